// Round 9
// baseline (1069.738 us; speedup 1.0000x reference)
//
#include <hip/hip_runtime.h>
#include <hip/hip_bf16.h>

// Problem constants (from reference)
#define N_NODES 50000
#define N_EDGES 200000
#define BGRAPHS 512
#define F0c 78
#define H1c 10
#define HC1 780     // H1*F0 (logical)
#define HSTR 800    // padded row stride: 10 head blocks of 80 (78 data + 2 pad)
#define C2c 128
#define SEQc 1000
#define VOCABc 26
#define NFc 32
#define KWc 8
#define LOUTc 121
#define EMBc 128
#define KX 96       // padded K for gemm1 (78 -> 96)
#define KXT 3872    // NF*LOUT = 32*121 -> 121 MFMA k-steps, split 11 x 11

typedef __attribute__((ext_vector_type(8))) short short8;
typedef __attribute__((ext_vector_type(4))) float f32x4;
typedef unsigned short u16;

static constexpr size_t alignup(size_t x) { return (x + 255) & ~size_t(255); }

// -------- workspace layout (bytes) --------
static constexpr size_t A_HBUF = 0;                                          // bf16 [N,800] = 80 MB
static constexpr size_t A_OUT1 = alignup(A_HBUF + size_t(N_NODES)*HSTR*2);   // bf16 [N,800] = 80 MB
static constexpr size_t A_H2   = alignup(A_OUT1 + size_t(N_NODES)*HSTR*2);   // f32  [N,128]
static constexpr size_t A_W2T  = alignup(A_H2   + size_t(N_NODES)*C2c*4);    // bf16 [128,800] padded-80 layout
static constexpr size_t A_ALS1 = alignup(A_W2T  + size_t(C2c)*HSTR*2);
static constexpr size_t A_ALD1 = alignup(A_ALS1 + size_t(N_NODES)*H1c*4);
static constexpr size_t A_ALS2 = alignup(A_ALD1 + size_t(N_NODES)*H1c*4);
static constexpr size_t A_ALD2 = alignup(A_ALS2 + size_t(N_NODES)*4);
static constexpr size_t A_DEG  = alignup(A_ALD2 + size_t(N_NODES)*4);
static constexpr size_t A_OFFS = alignup(A_DEG  + size_t(N_NODES)*4);
static constexpr size_t A_CUR  = alignup(A_OFFS + size_t(N_NODES+1)*4);
static constexpr size_t A_CSRC = alignup(A_CUR  + size_t(N_NODES)*4);
static constexpr size_t A_G    = alignup(A_CSRC + size_t(N_EDGES+N_NODES)*4);
static constexpr size_t A_XC   = alignup(A_G    + size_t(BGRAPHS)*C2c*4);
static constexpr size_t A_Y1   = alignup(A_XC   + size_t(BGRAPHS)*256*4);
static constexpr size_t A_Y2   = alignup(A_Y1   + size_t(BGRAPHS)*1024*4);
static constexpr size_t A_BOFF = alignup(A_Y2   + size_t(BGRAPHS)*256*4);
static constexpr size_t A_BPAD = alignup(A_BOFF + size_t(BGRAPHS)*(VOCABc+1)*4);
static constexpr size_t A_WXT  = alignup(A_BPAD + size_t(HSTR)*4);           // bf16 [128][3872]
static constexpr size_t A_END  = alignup(A_WXT  + size_t(C2c)*KXT*2);

// aliases inside hbuf region (valid after k_agg1 retires; hbuf dead then):
static constexpr size_t A_HFIN = A_HBUF;                                        // f32 [N,128]
static constexpr size_t A_ORD  = alignup(A_HFIN + size_t(N_NODES)*C2c*4);
static constexpr size_t A_AMAT = alignup(A_ORD  + size_t(BGRAPHS)*SEQc*4);
static constexpr size_t A_CVO  = alignup(A_AMAT + size_t(BGRAPHS)*NFc*VOCABc*KWc*4);  // bf16 [512][3872]
static_assert(A_CVO + size_t(BGRAPHS)*KXT*2 <= size_t(N_NODES)*HSTR*2, "alias A overflow");
// aliases inside out1 region (valid until k_agg1 writes out1):
static constexpr size_t A_XPAD = A_OUT1;                                        // bf16 [N,96]
static constexpr size_t A_W1T  = alignup(A_XPAD + size_t(N_NODES)*KX*2);        // bf16 [784,96]
static_assert(A_W1T + size_t(784)*KX*2 - A_OUT1 <= size_t(N_NODES)*HSTR*2, "alias B overflow");

// -------- helpers --------
__device__ __forceinline__ float bflo(unsigned u) { return __uint_as_float(u << 16); }
__device__ __forceinline__ float bfhi(unsigned u) { return __uint_as_float(u & 0xffff0000u); }
__device__ __forceinline__ u16 f2bf(float v) {
    __hip_bfloat16 b = __float2bfloat16(v);
    return *(u16*)&b;
}

// ---------------- prep: deg init + bf16 conversions + padded bias + xc bias init ----------------
__global__ void k_prep(const float* __restrict__ x, const float* __restrict__ W1,
                       const float* __restrict__ W2, const float* __restrict__ b1,
                       const float* __restrict__ fcxt_w, const float* __restrict__ fcxt_b,
                       __hip_bfloat16* __restrict__ xpad, __hip_bfloat16* __restrict__ w1t,
                       __hip_bfloat16* __restrict__ w2t, float* __restrict__ bpad,
                       __hip_bfloat16* __restrict__ wxt, float* __restrict__ xc,
                       int* __restrict__ deg) {
    int i = blockIdx.x*256 + threadIdx.x;
    const int R0 = N_NODES;
    const int R1 = R0 + N_NODES*KX;
    const int R2 = R1 + 784*KX;
    const int R3 = R2 + C2c*HSTR;
    const int R4 = R3 + HSTR;
    const int R5 = R4 + C2c*KXT;
    const int R6 = R5 + BGRAPHS*C2c;
    if (i < R0) {
        deg[i] = 1;   // self loop
    } else if (i < R1) {
        int t = i - R0; int n = t / KX, c = t - n*KX;
        xpad[t] = __float2bfloat16(c < F0c ? x[(size_t)n*F0c + c] : 0.f);
    } else if (i < R2) {
        int t = i - R1; int r = t / KX, k = t - r*KX;
        w1t[t] = __float2bfloat16((r < HC1 && k < F0c) ? W1[(size_t)k*HC1 + r] : 0.f);
    } else if (i < R3) {
        int t = i - R2; int c = t / HSTR, p = t - c*HSTR;
        int hh = p / 80, cc = p - hh*80;
        w2t[t] = __float2bfloat16(cc < F0c ? W2[(size_t)(hh*F0c + cc)*C2c + c] : 0.f);
    } else if (i < R4) {
        int p = i - R3; int hh = p / 80, cc = p - hh*80;
        bpad[p] = (cc < F0c) ? b1[hh*F0c + cc] : 0.f;
    } else if (i < R5) {
        int t = i - R4; int c = t / KXT, j = t - c*KXT;
        wxt[t] = __float2bfloat16(fcxt_w[(size_t)j*C2c + c]);
    } else if (i < R6) {
        int p = i - R5; int b = p / C2c, c = p - b*C2c;
        xc[b*256 + 128 + c] = fcxt_b[c];    // bias init; fcxt atomics accumulate on top
    }
}
#define PREP_TOTAL (N_NODES + N_NODES*KX + 784*KX + C2c*HSTR + HSTR + C2c*KXT + BGRAPHS*C2c)

// ---------------- CSR build ----------------
__global__ void k_count(const int* __restrict__ ei, int* deg) {
    int i = blockIdx.x*256 + threadIdx.x;
    if (i < N_EDGES) atomicAdd(&deg[ei[N_EDGES + i]], 1);
}
__global__ void k_scan(const int* __restrict__ deg, int* __restrict__ off,
                       int* __restrict__ cur, int n) {
    __shared__ int wsum[16];
    __shared__ int s_carry;
    int tid = threadIdx.x, lane = tid & 63, wid = tid >> 6;
    if (tid == 0) s_carry = 0;
    __syncthreads();
    for (int base = 0; base < n; base += 1024) {
        int i = base + tid;
        int v0 = (i < n) ? deg[i] : 0;
        int v = v0;
        for (int d = 1; d < 64; d <<= 1) { int t = __shfl_up(v, d, 64); if (lane >= d) v += t; }
        if (lane == 63) wsum[wid] = v;
        __syncthreads();
        if (wid == 0) {
            int w = (lane < 16) ? wsum[lane] : 0;
            for (int d = 1; d < 16; d <<= 1) { int t = __shfl_up(w, d, 64); if (lane >= d) w += t; }
            if (lane < 16) wsum[lane] = w;
        }
        __syncthreads();
        int wprev = (wid > 0) ? wsum[wid-1] : 0;
        int carry = s_carry;
        if (i < n) { int o = carry + wprev + (v - v0); off[i] = o; cur[i] = o; }
        __syncthreads();
        if (tid == 0) s_carry = carry + wsum[15];
        __syncthreads();
    }
    if (tid == 0) off[n] = s_carry;
}
__global__ void k_fill(const int* __restrict__ ei, int* cur, int* __restrict__ csrc) {
    int i = blockIdx.x*256 + threadIdx.x;
    if (i < N_EDGES) {
        int s = ei[i], d = ei[N_EDGES + i];
        int p = atomicAdd(&cur[d], 1);
        csrc[p] = s;
    } else if (i < N_EDGES + N_NODES) {
        int n = i - N_EDGES;
        int p = atomicAdd(&cur[n], 1);
        csrc[p] = n;
    }
}

// ---------------- GEMM1 (MFMA): xp[N,96] @ W1t[784,96]^T -> h[N,800] bf16 (padded-80) ----------------
__global__ void k_gemm1_mfma(const short* __restrict__ Xp, const short* __restrict__ W1t,
                             u16* __restrict__ Hout) {
    int wave = threadIdx.x >> 6, lane = threadIdx.x & 63;
    int m16 = lane & 15, quad = lane >> 4;
    int r0 = blockIdx.x*64 + wave*16;
    int c0 = blockIdx.y*112;               // 7 col tiles of 16
    int rowc = min(r0 + m16, N_NODES-1);
    const short8* arow = (const short8*)(Xp + (size_t)rowc*KX);
    f32x4 acc[7];
    #pragma unroll
    for (int ct = 0; ct < 7; ct++) acc[ct] = (f32x4){0.f,0.f,0.f,0.f};
    #pragma unroll
    for (int kt = 0; kt < 3; kt++) {
        short8 af = arow[kt*4 + quad];
        #pragma unroll
        for (int ct = 0; ct < 7; ct++) {
            const short8* brow = (const short8*)(W1t + (size_t)(c0 + ct*16 + m16)*KX);
            short8 bf = brow[kt*4 + quad];
            acc[ct] = __builtin_amdgcn_mfma_f32_16x16x32_bf16(af, bf, acc[ct], 0, 0, 0);
        }
    }
    #pragma unroll
    for (int ct = 0; ct < 7; ct++) {
        int col = c0 + ct*16 + m16;
        if (col >= HC1) continue;
        int pcol = col + 2*(col/78);       // padded-80 position
        #pragma unroll
        for (int r = 0; r < 4; r++) {
            int orow = r0 + quad*4 + r;
            if (orow < N_NODES) Hout[(size_t)orow*HSTR + pcol] = f2bf(acc[ct][r]);
        }
    }
}

// ---------------- GEMM2 (MFMA): out1[N,800] @ W2t[128,800]^T -> h2[N,128] f32 ----------------
__global__ void k_gemm2_mfma(const short* __restrict__ A, const short* __restrict__ Bt,
                             float* __restrict__ Cout) {
    int wave = threadIdx.x >> 6, lane = threadIdx.x & 63;
    int m16 = lane & 15, quad = lane >> 4;
    int r0 = blockIdx.x*64 + wave*16;
    int rowc = min(r0 + m16, N_NODES-1);
    const short8* arow = (const short8*)(A + (size_t)rowc*HSTR);
    f32x4 acc[8];
    #pragma unroll
    for (int ct = 0; ct < 8; ct++) acc[ct] = (f32x4){0.f,0.f,0.f,0.f};
    for (int kt = 0; kt < 25; kt++) {
        short8 af = arow[kt*4 + quad];
        #pragma unroll
        for (int ct = 0; ct < 8; ct++) {
            const short8* brow = (const short8*)(Bt + (size_t)(ct*16 + m16)*HSTR);
            short8 bf = brow[kt*4 + quad];
            acc[ct] = __builtin_amdgcn_mfma_f32_16x16x32_bf16(af, bf, acc[ct], 0, 0, 0);
        }
    }
    #pragma unroll
    for (int ct = 0; ct < 8; ct++) {
        #pragma unroll
        for (int r = 0; r < 4; r++) {
            int orow = r0 + quad*4 + r;
            if (orow < N_NODES) Cout[(size_t)orow*C2c + ct*16 + m16] = acc[ct][r];
        }
    }
}

// ---------------- attention logit precompute ----------------
__global__ void k_att1(const u16* __restrict__ h, const float* __restrict__ a_src,
                       const float* __restrict__ a_dst, float* __restrict__ als,
                       float* __restrict__ ald) {
    int i = blockIdx.x*256 + threadIdx.x;
    if (i >= N_NODES*H1c) return;
    int n = i / H1c, hh = i - n*H1c;
    const unsigned* hp = (const unsigned*)(h + (size_t)n*HSTR + hh*80);
    const float* asv = a_src + hh*F0c;
    const float* adv = a_dst + hh*F0c;
    float s1 = 0.f, s2 = 0.f;
    #pragma unroll
    for (int c2 = 0; c2 < F0c/2; c2++) {
        unsigned u = hp[c2];
        float v0 = bflo(u), v1 = bfhi(u);
        s1 += v0*asv[2*c2] + v1*asv[2*c2+1];
        s2 += v0*adv[2*c2] + v1*adv[2*c2+1];
    }
    als[i] = s1; ald[i] = s2;
}
__global__ void k_att2(const float* __restrict__ h, const float* __restrict__ a_src,
                       const float* __restrict__ a_dst, float* __restrict__ als,
                       float* __restrict__ ald) {
    int n = blockIdx.x*256 + threadIdx.x;
    if (n >= N_NODES) return;
    const float* hp = h + (size_t)n*C2c;
    float s1 = 0.f, s2 = 0.f;
    for (int c = 0; c < C2c; c++) { float v = hp[c]; s1 += v*a_src[c]; s2 += v*a_dst[c]; }
    als[n] = s1; ald[n] = s2;
}

// ---------------- GAT layer-1 aggregation: one wave per dst, vectorized row gather ----------------
// Fast path deg<=64 (P(deg>64) ~ 1e-15 for this graph; LDS 2.9 KB -> 32 waves/CU).
__global__ void k_agg1(const u16* __restrict__ hbuf, const float* __restrict__ als,
                       const float* __restrict__ ald, const int* __restrict__ offs,
                       const int* __restrict__ csrc, const float* __restrict__ bpad,
                       u16* __restrict__ out) {
    constexpr int H = H1c;
    int dn = blockIdx.x, lane = threadIdx.x;   // 64
    int s = offs[dn], e = offs[dn+1], deg = e - s;
    __shared__ float wexp[64*H];               // 2560 B
    __shared__ int   ssrc[64];
    __shared__ float ms[H], dinv_s[H];

    if (deg <= 64) {
        if (lane < deg) ssrc[lane] = csrc[s + lane];
        __syncthreads();
        for (int idx = lane; idx < deg*H; idx += 64) {
            int j = idx / H, hh = idx - j*H;
            float al = als[(size_t)ssrc[j]*H + hh] + ald[(size_t)dn*H + hh];
            wexp[idx] = (al >= 0.f) ? al : 0.2f*al;
        }
        __syncthreads();
        if (lane < H) {
            float m = -1e30f;
            for (int j = 0; j < deg; j++) m = fmaxf(m, wexp[j*H + lane]);
            float den = 0.f;
            for (int j = 0; j < deg; j++) den += __expf(wexp[j*H + lane] - m);
            ms[lane] = m; dinv_s[lane] = 1.f/(den + 1e-16f);
        }
        __syncthreads();
        for (int idx = lane; idx < deg*H; idx += 64) {
            int hh = idx % H;
            wexp[idx] = __expf(wexp[idx] - ms[hh]) * dinv_s[hh];
        }
        __syncthreads();
        // vector accumulate over full padded row: 100 chunks of 8 bf16 (16 B)
        int q0 = lane, q1 = 64 + lane;
        int hd0 = q0 / 10, hd1 = q1 / 10;          // chunk 8q..8q+7 lies in head q/10 (80%8==0)
        bool act1 = (q1 < 100);
        float acc0[8], acc1[8];
        #pragma unroll
        for (int t = 0; t < 8; t++) { acc0[t] = 0.f; acc1[t] = 0.f; }
        for (int j = 0; j < deg; j++) {
            const uint4* row = (const uint4*)(hbuf + (size_t)ssrc[j]*HSTR);
            float a0 = wexp[j*H + hd0];
            uint4 v = row[q0];
            acc0[0] += a0*bflo(v.x); acc0[1] += a0*bfhi(v.x);
            acc0[2] += a0*bflo(v.y); acc0[3] += a0*bfhi(v.y);
            acc0[4] += a0*bflo(v.z); acc0[5] += a0*bfhi(v.z);
            acc0[6] += a0*bflo(v.w); acc0[7] += a0*bfhi(v.w);
            if (act1) {
                float a1 = wexp[j*H + hd1];
                uint4 w = row[q1];
                acc1[0] += a1*bflo(w.x); acc1[1] += a1*bfhi(w.x);
                acc1[2] += a1*bflo(w.y); acc1[3] += a1*bfhi(w.y);
                acc1[4] += a1*bflo(w.z); acc1[5] += a1*bfhi(w.z);
                acc1[6] += a1*bflo(w.w); acc1[7] += a1*bfhi(w.w);
            }
        }
        {
            short8 pk;
            #pragma unroll
            for (int t = 0; t < 8; t++) {
                float v = acc0[t] + bpad[q0*8 + t];
                v = (v > 0.f) ? v : (__expf(v) - 1.f);
                pk[t] = (short)f2bf(v);
            }
            *((short8*)(out + (size_t)dn*HSTR + q0*8)) = pk;
        }
        if (act1) {
            short8 pk;
            #pragma unroll
            for (int t = 0; t < 8; t++) {
                float v = acc1[t] + bpad[q1*8 + t];
                v = (v > 0.f) ? v : (__expf(v) - 1.f);
                pk[t] = (short)f2bf(v);
            }
            *((short8*)(out + (size_t)dn*HSTR + q1*8)) = pk;
        }
    } else {
        // fallback deg>64: scalar, guaranteed correct
        if (lane < H) {
            float adv = ald[(size_t)dn*H + lane];
            float m = -1e30f;
            for (int j = s; j < e; j++) {
                float al = als[(size_t)csrc[j]*H + lane] + adv;
                al = (al >= 0.f) ? al : 0.2f*al;
                m = fmaxf(m, al);
            }
            float den = 0.f;
            for (int j = s; j < e; j++) {
                float al = als[(size_t)csrc[j]*H + lane] + adv;
                al = (al >= 0.f) ? al : 0.2f*al;
                den += __expf(al - m);
            }
            ms[lane] = m; dinv_s[lane] = 1.f/(den + 1e-16f);
        }
        __syncthreads();
        for (int hh = 0; hh < H; hh++) {
            float m = ms[hh], dinv = dinv_s[hh];
            float adv = ald[(size_t)dn*H + hh];
            for (int cb = 0; cb < F0c; cb += 64) {
                int c = cb + lane;
                if (c < F0c) {
                    float acc = 0.f;
                    for (int j = s; j < e; j++) {
                        int sj = csrc[j];
                        float al = als[(size_t)sj*H + hh] + adv;
                        al = (al >= 0.f) ? al : 0.2f*al;
                        float alpha = __expf(al - m) * dinv;
                        acc += alpha * __uint_as_float(((unsigned)hbuf[(size_t)sj*HSTR + hh*80 + c]) << 16);
                    }
                    float v = acc + bpad[hh*80 + c];
                    v = (v > 0.f) ? v : (__expf(v) - 1.f);
                    out[(size_t)dn*HSTR + hh*80 + c] = f2bf(v);
                }
            }
        }
        if (lane < 20) {
            int hh = lane >> 1, cc = 78 + (lane & 1);
            out[(size_t)dn*HSTR + hh*80 + cc] = 0;
        }
    }
}

// ---------------- GAT layer-2 aggregation (H=1, C=128 f32) ----------------
__global__ void k_agg2(const float* __restrict__ h2, const float* __restrict__ als,
                       const float* __restrict__ ald, const int* __restrict__ offs,
                       const int* __restrict__ csrc, const float* __restrict__ b2,
                       float* __restrict__ out) {
    int dn = blockIdx.x, lane = threadIdx.x;   // 64
    int s = offs[dn], e = offs[dn+1], deg = e - s;
    __shared__ float wexp[128];
    __shared__ int ssrc[128];

    if (deg <= 128) {
        float adv = ald[dn];
        for (int j = lane; j < deg; j += 64) {
            int sj = csrc[s + j];
            ssrc[j] = sj;
            float al = als[sj] + adv;
            wexp[j] = (al >= 0.f) ? al : 0.2f*al;
        }
        __syncthreads();
        float m = -1e30f;
        for (int j = lane; j < deg; j += 64) m = fmaxf(m, wexp[j]);
        #pragma unroll
        for (int d = 32; d > 0; d >>= 1) m = fmaxf(m, __shfl_xor(m, d, 64));
        __syncthreads();
        float den = 0.f;
        for (int j = lane; j < deg; j += 64) {
            float ex = __expf(wexp[j] - m);
            wexp[j] = ex;
            den += ex;
        }
        #pragma unroll
        for (int d = 32; d > 0; d >>= 1) den += __shfl_xor(den, d, 64);
        float dinv = 1.f/(den + 1e-16f);
        __syncthreads();
        float2 acc = {0.f, 0.f};
        for (int j = 0; j < deg; j++) {
            float alpha = wexp[j] * dinv;
            float2 v = ((const float2*)(h2 + (size_t)ssrc[j]*C2c))[lane];
            acc.x += alpha*v.x; acc.y += alpha*v.y;
        }
        float2 o;
        o.x = fmaxf(acc.x + b2[2*lane], 0.f);
        o.y = fmaxf(acc.y + b2[2*lane+1], 0.f);
        ((float2*)(out + (size_t)dn*C2c))[lane] = o;
    } else {
        __shared__ float sm[2];
        if (lane == 0) {
            float adv = ald[dn];
            float m = -1e30f;
            for (int j = s; j < e; j++) {
                float al = als[csrc[j]] + adv;
                al = (al >= 0.f) ? al : 0.2f*al;
                m = fmaxf(m, al);
            }
            float den = 0.f;
            for (int j = s; j < e; j++) {
                float al = als[csrc[j]] + adv;
                al = (al >= 0.f) ? al : 0.2f*al;
                den += __expf(al - m);
            }
            sm[0] = m; sm[1] = 1.f/(den + 1e-16f);
        }
        __syncthreads();
        float m = sm[0], dinv = sm[1], adv = ald[dn];
        float2 acc = {0.f, 0.f};
        for (int j = s; j < e; j++) {
            int sj = csrc[j];
            float al = als[sj] + adv;
            al = (al >= 0.f) ? al : 0.2f*al;
            float alpha = __expf(al - m) * dinv;
            float2 v = ((const float2*)(h2 + (size_t)sj*C2c))[lane];
            acc.x += alpha*v.x; acc.y += alpha*v.y;
        }
        float2 o;
        o.x = fmaxf(acc.x + b2[2*lane], 0.f);
        o.y = fmaxf(acc.y + b2[2*lane+1], 0.f);
        ((float2*)(out + (size_t)dn*C2c))[lane] = o;
    }
}

// ---------------- global max pool (batch sorted) ----------------
__global__ void k_pool(const float* __restrict__ hf, const int* __restrict__ batch,
                       float* __restrict__ g) {
    int b = blockIdx.x, tid = threadIdx.x;    // 128
    __shared__ int se[2];
    if (tid < 2) {
        int key = b + tid;
        int lo = 0, hi = N_NODES;
        while (lo < hi) { int mid = (lo+hi) >> 1; if (batch[mid] < key) lo = mid+1; else hi = mid; }
        se[tid] = lo;
    }
    __syncthreads();
    int s = se[0], e = se[1];
    float m = -1e30f;
    for (int n = s; n < e; n++) m = fmaxf(m, hf[(size_t)n*C2c + tid]);
    g[b*C2c + tid] = m;
}
__global__ void k_fcg(const float* __restrict__ g, const float* __restrict__ W,
                      const float* __restrict__ bias, float* __restrict__ xc) {
    int b = blockIdx.x, tid = threadIdx.x;    // 128
    __shared__ float gs[C2c];
    gs[tid] = g[b*C2c + tid];
    __syncthreads();
    float acc = bias[tid];
    for (int k = 0; k < C2c; k++) acc += gs[k] * W[k*C2c + tid];
    xc[b*256 + tid] = fmaxf(acc, 0.f);
}

// ---------------- conv path ----------------
__global__ void k_bucket(const int* __restrict__ target, int* __restrict__ ordered,
                         int* __restrict__ boff) {
    int b = blockIdx.x, tid = threadIdx.x;    // 256
    __shared__ int cnt[VOCABc];
    __shared__ int offs[VOCABc+1];
    __shared__ int cur[VOCABc];
    if (tid < VOCABc) cnt[tid] = 0;
    __syncthreads();
    for (int i = tid; i < SEQc; i += 256) atomicAdd(&cnt[target[(size_t)b*SEQc + i]], 1);
    __syncthreads();
    if (tid == 0) { offs[0] = 0; for (int v = 0; v < VOCABc; v++) offs[v+1] = offs[v] + cnt[v]; }
    __syncthreads();
    if (tid < VOCABc) cur[tid] = offs[tid];
    if (tid < VOCABc+1) boff[b*(VOCABc+1) + tid] = offs[tid];
    __syncthreads();
    for (int i = tid; i < SEQc; i += 256) {
        int t = target[(size_t)b*SEQc + i];
        int p = atomicAdd(&cur[t], 1);
        ordered[(size_t)b*SEQc + p] = i;
    }
}
__global__ void k_buildA(const float* __restrict__ convw, const int* __restrict__ ordered,
                         const int* __restrict__ boff, float* __restrict__ Amat) {
    int t = blockIdx.x, b = blockIdx.y;
    int tid = threadIdx.x;                // 256 = 32 o * 8 k
    int o = tid >> 3, k = tid & 7;
    int s = boff[b*(VOCABc+1) + t], e = boff[b*(VOCABc+1) + t + 1];
    const int* ord = ordered + (size_t)b*SEQc;
    float acc = 0.f;
    for (int j = s; j < e; j++) {
        int i = ord[j];
        acc += convw[((size_t)o*SEQc + i)*KWc + k];
    }
    Amat[(((size_t)b*NFc + o)*VOCABc + t)*KWc + k] = acc;
}
// conv -> bf16 output [B][3872]; grid (B, 4): 8 output channels per block for occupancy
__global__ void k_conv(const float* __restrict__ Amat, const float* __restrict__ emb,
                       const float* __restrict__ convb, u16* __restrict__ convout) {
    int b = blockIdx.x, og = blockIdx.y;      // og in 0..3 -> o base og*8
    int tid = threadIdx.x;                    // 128
    __shared__ float embs[VOCABc*EMBc];       // 13.3 KB
    __shared__ float arow[8*VOCABc*KWc];      // 6.6 KB
    for (int i = tid; i < VOCABc*EMBc; i += 128) embs[i] = emb[i];
    for (int i = tid; i < 8*VOCABc*KWc; i += 128)
        arow[i] = Amat[((size_t)b*NFc + og*8)*(VOCABc*KWc) + i];
    __syncthreads();
    if (tid < LOUTc) {
        #pragma unroll
        for (int oo = 0; oo < 8; oo++) {
            int o = og*8 + oo;
            float acc = convb[o];
            for (int t = 0; t < VOCABc; t++) {
                #pragma unroll
                for (int k = 0; k < KWc; k++)
                    acc += arow[oo*(VOCABc*KWc) + t*KWc + k] * embs[t*EMBc + tid + k];
            }
            convout[(size_t)b*KXT + o*LOUTc + tid] = f2bf(fmaxf(acc, 0.f));
        }
    }
}
// fcxt (MFMA, K-split): cvo[512,3872]bf16 @ wxt[128][3872]bf16 -> atomicAdd into xc[:,128:256]
__global__ void k_fcxt_mfma(const short* __restrict__ cvo, const short* __restrict__ wxt,
                            float* __restrict__ xc) {
    int wave = threadIdx.x >> 6, lane = threadIdx.x & 63;
    int m16 = lane & 15, quad = lane >> 4;
    int r0 = blockIdx.x*64 + wave*16;      // 512 rows = 8 blocks * 64
    int kt0 = blockIdx.y*11;               // 121 k-steps = 11 chunks * 11
    const short8* arow = (const short8*)(cvo + (size_t)(r0 + m16)*KXT);
    f32x4 acc[8];
    #pragma unroll
    for (int ct = 0; ct < 8; ct++) acc[ct] = (f32x4){0.f,0.f,0.f,0.f};
    for (int kt = kt0; kt < kt0 + 11; kt++) {
        short8 af = arow[kt*4 + quad];
        #pragma unroll
        for (int ct = 0; ct < 8; ct++) {
            const short8* brow = (const short8*)(wxt + (size_t)(ct*16 + m16)*KXT);
            short8 bf = brow[kt*4 + quad];
            acc[ct] = __builtin_amdgcn_mfma_f32_16x16x32_bf16(af, bf, acc[ct], 0, 0, 0);
        }
    }
    #pragma unroll
    for (int ct = 0; ct < 8; ct++) {
        int col = ct*16 + m16;
        #pragma unroll
        for (int r = 0; r < 4; r++) {
            int row = r0 + quad*4 + r;
            atomicAdd(&xc[(size_t)row*256 + 128 + col], acc[ct][r]);
        }
    }
}

// ---------------- head MLP (per-graph blocks, high occupancy) ----------------
__global__ void k_fc1(const float* __restrict__ xc, const float* __restrict__ W,
                      const float* __restrict__ bias, float* __restrict__ y1) {
    int b = blockIdx.x, tid = threadIdx.x;    // 256
    __shared__ float xs[256];
    xs[tid] = xc[b*256 + tid];
    __syncthreads();
    float a0 = bias[tid], a1 = bias[tid+256], a2 = bias[tid+512], a3 = bias[tid+768];
    for (int k = 0; k < 256; k++) {
        float xk = xs[k];
        const float* wr = W + (size_t)k*1024;
        a0 += xk*wr[tid]; a1 += xk*wr[tid+256]; a2 += xk*wr[tid+512]; a3 += xk*wr[tid+768];
    }
    y1[(size_t)b*1024 + tid      ] = fmaxf(a0, 0.f);
    y1[(size_t)b*1024 + tid + 256] = fmaxf(a1, 0.f);
    y1[(size_t)b*1024 + tid + 512] = fmaxf(a2, 0.f);
    y1[(size_t)b*1024 + tid + 768] = fmaxf(a3, 0.f);
}
__global__ void k_fc2(const float* __restrict__ y1, const float* __restrict__ W,
                      const float* __restrict__ bias, float* __restrict__ y2) {
    int b = blockIdx.x, tid = threadIdx.x;    // 256
    __shared__ float ys[1024];
    for (int i = tid; i < 1024; i += 256) ys[i] = y1[(size_t)b*1024 + i];
    __syncthreads();
    float acc = bias[tid];
    for (int k = 0; k < 1024; k++) acc += ys[k] * W[(size_t)k*256 + tid];
    y2[b*256 + tid] = fmaxf(acc, 0.f);
}
__global__ void k_out(const float* __restrict__ y2, const float* __restrict__ ow,
                      const float* __restrict__ ob, float* __restrict__ out) {
    int b = blockIdx.x, lane = threadIdx.x;   // 64
    float p = 0.f;
    for (int c = lane; c < 256; c += 64) p += y2[b*256 + c] * ow[c];
    for (int d = 32; d > 0; d >>= 1) p += __shfl_xor(p, d, 64);
    if (lane == 0) out[b] = p + ob[0];
}

extern "C" void kernel_launch(void* const* d_in, const int* in_sizes, int n_in,
                              void* d_out, int out_size, void* d_ws, size_t ws_size,
                              hipStream_t stream) {
    (void)in_sizes; (void)n_in; (void)out_size;
    if (ws_size < A_END) return;   // guard: clean numeric-fail if ws too small

    const float* x       = (const float*)d_in[0];
    const int*   ei      = (const int*)  d_in[1];
    const int*   batch   = (const int*)  d_in[2];
    const int*   target  = (const int*)  d_in[3];
    const float* W1      = (const float*)d_in[4];
    const float* a_src1  = (const float*)d_in[5];
    const float* a_dst1  = (const float*)d_in[6];
    const float* b1      = (const float*)d_in[7];
    const float* W2      = (const float*)d_in[8];
    const float* a_src2  = (const float*)d_in[9];
    const float* a_dst2  = (const float*)d_in[10];
    const float* b2      = (const float*)d_in[11];
    const float* fcg_w   = (const float*)d_in[12];
    const float* fcg_b   = (const float*)d_in[13];
    const float* emb     = (const float*)d_in[14];
    const float* conv_w  = (const float*)d_in[15];
    const float* conv_b  = (const float*)d_in[16];
    const float* fcxt_w  = (const float*)d_in[17];
    const float* fcxt_b  = (const float*)d_in[18];
    const float* fc1_w   = (const float*)d_in[19];
    const float* fc1_b   = (const float*)d_in[20];
    const float* fc2_w   = (const float*)d_in[21];
    const float* fc2_b   = (const float*)d_in[22];
    const float* out_w   = (const float*)d_in[23];
    const float* out_b   = (const float*)d_in[24];

    char* wsb = (char*)d_ws;
    u16*   hbuf  = (u16*)  (wsb + A_HBUF);
    u16*   out1  = (u16*)  (wsb + A_OUT1);
    float* h2    = (float*)(wsb + A_H2);
    __hip_bfloat16* w2t = (__hip_bfloat16*)(wsb + A_W2T);
    float* als1  = (float*)(wsb + A_ALS1);
    float* ald1  = (float*)(wsb + A_ALD1);
    float* als2  = (float*)(wsb + A_ALS2);
    float* ald2  = (float*)(wsb + A_ALD2);
    int*   deg   = (int*)  (wsb + A_DEG);
    int*   offs  = (int*)  (wsb + A_OFFS);
    int*   cur   = (int*)  (wsb + A_CUR);
    int*   csrc  = (int*)  (wsb + A_CSRC);
    float* g     = (float*)(wsb + A_G);
    float* xc    = (float*)(wsb + A_XC);
    float* y1    = (float*)(wsb + A_Y1);
    float* y2    = (float*)(wsb + A_Y2);
    int*   boff  = (int*)  (wsb + A_BOFF);
    float* bpad  = (float*)(wsb + A_BPAD);
    __hip_bfloat16* wxt = (__hip_bfloat16*)(wsb + A_WXT);
    // aliases:
    float* hfin  = (float*)(wsb + A_HFIN);
    int*   ord   = (int*)  (wsb + A_ORD);
    float* Amat  = (float*)(wsb + A_AMAT);
    u16*   cvo   = (u16*)  (wsb + A_CVO);
    __hip_bfloat16* xpad = (__hip_bfloat16*)(wsb + A_XPAD);
    __hip_bfloat16* w1t  = (__hip_bfloat16*)(wsb + A_W1T);

    // prep: deg init + conversions + padded bias + xc bias init
    k_prep<<<(PREP_TOTAL+255)/256, 256, 0, stream>>>(x, W1, W2, b1, fcxt_w, fcxt_b,
                                                     xpad, w1t, w2t, bpad, wxt, xc, deg);
    // CSR build
    k_count<<<(N_EDGES+255)/256, 256, 0, stream>>>(ei, deg);
    k_scan <<<1, 1024, 0, stream>>>(deg, offs, cur, N_NODES);
    k_fill <<<(N_EDGES+N_NODES+255)/256, 256, 0, stream>>>(ei, cur, csrc);

    // GAT layer 1
    k_gemm1_mfma<<<dim3((N_NODES+63)/64, 7), 256, 0, stream>>>((const short*)xpad, (const short*)w1t, hbuf);
    k_att1<<<(N_NODES*H1c+255)/256, 256, 0, stream>>>(hbuf, a_src1, a_dst1, als1, ald1);
    k_agg1<<<N_NODES, 64, 0, stream>>>(hbuf, als1, ald1, offs, csrc, bpad, out1);
    // ---- hbuf dead; xpad/w1t dead (out1 region now live) ----

    // GAT layer 2
    k_gemm2_mfma<<<(N_NODES+63)/64, 256, 0, stream>>>((const short*)out1, (const short*)w2t, h2);
    k_att2<<<(N_NODES+255)/256, 256, 0, stream>>>(h2, a_src2, a_dst2, als2, ald2);
    k_agg2<<<N_NODES, 64, 0, stream>>>(h2, als2, ald2, offs, csrc, b2, hfin);

    // pool + fc_g1 -> xc[:, 0:128]
    k_pool<<<BGRAPHS, 128, 0, stream>>>(hfin, batch, g);
    k_fcg <<<BGRAPHS, 128, 0, stream>>>(g, fcg_w, fcg_b, xc);

    // conv path -> xc[:, 128:256] (bias pre-initialized in k_prep)
    k_bucket<<<BGRAPHS, 256, 0, stream>>>(target, ord, boff);
    k_buildA<<<dim3(VOCABc, BGRAPHS), 256, 0, stream>>>(conv_w, ord, boff, Amat);
    k_conv  <<<dim3(BGRAPHS, 4), 128, 0, stream>>>(Amat, emb, conv_b, cvo);
    k_fcxt_mfma<<<dim3(BGRAPHS/64, 11), 256, 0, stream>>>((const short*)cvo, (const short*)wxt, xc);

    // head MLP
    k_fc1<<<BGRAPHS, 256, 0, stream>>>(xc, fc1_w, fc1_b, y1);
    k_fc2<<<BGRAPHS, 256, 0, stream>>>(y1, fc2_w, fc2_b, y2);
    k_out<<<BGRAPHS, 64, 0, stream>>>(y2, out_w, out_b, (float*)d_out);
}

// Round 11
// 762.626 us; speedup vs baseline: 1.4027x; 1.4027x over previous
//
#include <hip/hip_runtime.h>
#include <hip/hip_bf16.h>

// Problem constants (from reference)
#define N_NODES 50000
#define N_EDGES 200000
#define BGRAPHS 512
#define F0c 78
#define H1c 10
#define HC1 780     // H1*F0 (logical)
#define HSTR 800    // padded row stride: 10 head blocks of 80 (78 data + 2 pad)
#define C2c 128
#define SEQc 1000
#define VOCABc 26
#define NFc 32
#define KWc 8
#define LOUTc 121
#define EMBc 128
#define KX 96       // padded K for gemm1 (78 -> 96)
#define KXT 3872    // NF*LOUT = 32*121 -> 121 MFMA k-steps, split 11 x 11

typedef __attribute__((ext_vector_type(8))) short short8;
typedef __attribute__((ext_vector_type(4))) float f32x4;
typedef unsigned short u16;

static constexpr size_t alignup(size_t x) { return (x + 255) & ~size_t(255); }

// -------- workspace layout (bytes) --------
static constexpr size_t A_HBUF = 0;                                          // bf16 [N,800] = 80 MB
static constexpr size_t A_OUT1 = alignup(A_HBUF + size_t(N_NODES)*HSTR*2);   // bf16 [N,800] = 80 MB
static constexpr size_t A_H2   = alignup(A_OUT1 + size_t(N_NODES)*HSTR*2);   // f32  [N,128]
static constexpr size_t A_W2T  = alignup(A_H2   + size_t(N_NODES)*C2c*4);    // bf16 [128,800] padded-80 layout
static constexpr size_t A_ALS1 = alignup(A_W2T  + size_t(C2c)*HSTR*2);
static constexpr size_t A_ALD1 = alignup(A_ALS1 + size_t(N_NODES)*H1c*4);
static constexpr size_t A_ALS2 = alignup(A_ALD1 + size_t(N_NODES)*H1c*4);
static constexpr size_t A_ALD2 = alignup(A_ALS2 + size_t(N_NODES)*4);
static constexpr size_t A_DEG  = alignup(A_ALD2 + size_t(N_NODES)*4);
static constexpr size_t A_OFFS = alignup(A_DEG  + size_t(N_NODES)*4);
static constexpr size_t A_CUR  = alignup(A_OFFS + size_t(N_NODES+1)*4);
static constexpr size_t A_CSRC = alignup(A_CUR  + size_t(N_NODES)*4);
static constexpr size_t A_G    = alignup(A_CSRC + size_t(N_EDGES+N_NODES)*4);
static constexpr size_t A_XC   = alignup(A_G    + size_t(BGRAPHS)*C2c*4);
static constexpr size_t A_Y1   = alignup(A_XC   + size_t(BGRAPHS)*256*4);
static constexpr size_t A_Y2   = alignup(A_Y1   + size_t(BGRAPHS)*1024*4);
static constexpr size_t A_BOFF = alignup(A_Y2   + size_t(BGRAPHS)*256*4);
static constexpr size_t A_BPAD = alignup(A_BOFF + size_t(BGRAPHS)*(VOCABc+1)*4);
static constexpr size_t A_WXT  = alignup(A_BPAD + size_t(HSTR)*4);           // bf16 [128][3872]
static constexpr size_t A_FXP  = alignup(A_WXT  + size_t(C2c)*KXT*2);        // f32 [11][512][128] fcxt partials
static constexpr size_t A_END  = alignup(A_FXP  + size_t(11)*BGRAPHS*C2c*4);

// aliases inside hbuf region (valid after k_agg1 retires; hbuf dead then):
static constexpr size_t A_HFIN = A_HBUF;                                        // f32 [N,128]
static constexpr size_t A_ORD  = alignup(A_HFIN + size_t(N_NODES)*C2c*4);
static constexpr size_t A_AMAT = alignup(A_ORD  + size_t(BGRAPHS)*SEQc*4);
static constexpr size_t A_CVO  = alignup(A_AMAT + size_t(BGRAPHS)*NFc*VOCABc*KWc*4);  // bf16 [512][3872]
static_assert(A_CVO + size_t(BGRAPHS)*KXT*2 <= size_t(N_NODES)*HSTR*2, "alias A overflow");
// aliases inside out1 region (valid until k_agg1 writes out1):
static constexpr size_t A_XPAD = A_OUT1;                                        // bf16 [N,96]
static constexpr size_t A_W1T  = alignup(A_XPAD + size_t(N_NODES)*KX*2);        // bf16 [784,96]
static_assert(A_W1T + size_t(784)*KX*2 - A_OUT1 <= size_t(N_NODES)*HSTR*2, "alias B overflow");

// -------- helpers --------
__device__ __forceinline__ float bflo(unsigned u) { return __uint_as_float(u << 16); }
__device__ __forceinline__ float bfhi(unsigned u) { return __uint_as_float(u & 0xffff0000u); }
__device__ __forceinline__ u16 f2bf(float v) {
    __hip_bfloat16 b = __float2bfloat16(v);
    return *(u16*)&b;
}

// ---------------- prep: deg init + bf16 conversions + padded bias ----------------
__global__ void k_prep(const float* __restrict__ x, const float* __restrict__ W1,
                       const float* __restrict__ W2, const float* __restrict__ b1,
                       const float* __restrict__ fcxt_w,
                       __hip_bfloat16* __restrict__ xpad, __hip_bfloat16* __restrict__ w1t,
                       __hip_bfloat16* __restrict__ w2t, float* __restrict__ bpad,
                       __hip_bfloat16* __restrict__ wxt, int* __restrict__ deg) {
    int i = blockIdx.x*256 + threadIdx.x;
    const int R0 = N_NODES;
    const int R1 = R0 + N_NODES*KX;
    const int R2 = R1 + 784*KX;
    const int R3 = R2 + C2c*HSTR;
    const int R4 = R3 + HSTR;
    const int R5 = R4 + C2c*KXT;
    if (i < R0) {
        deg[i] = 1;   // self loop
    } else if (i < R1) {
        int t = i - R0; int n = t / KX, c = t - n*KX;
        xpad[t] = __float2bfloat16(c < F0c ? x[(size_t)n*F0c + c] : 0.f);
    } else if (i < R2) {
        int t = i - R1; int r = t / KX, k = t - r*KX;
        w1t[t] = __float2bfloat16((r < HC1 && k < F0c) ? W1[(size_t)k*HC1 + r] : 0.f);
    } else if (i < R3) {
        int t = i - R2; int c = t / HSTR, p = t - c*HSTR;
        int hh = p / 80, cc = p - hh*80;
        w2t[t] = __float2bfloat16(cc < F0c ? W2[(size_t)(hh*F0c + cc)*C2c + c] : 0.f);
    } else if (i < R4) {
        int p = i - R3; int hh = p / 80, cc = p - hh*80;
        bpad[p] = (cc < F0c) ? b1[hh*F0c + cc] : 0.f;
    } else if (i < R5) {
        int t = i - R4; int c = t / KXT, j = t - c*KXT;
        wxt[t] = __float2bfloat16(fcxt_w[(size_t)j*C2c + c]);
    }
}
#define PREP_TOTAL (N_NODES + N_NODES*KX + 784*KX + C2c*HSTR + HSTR + C2c*KXT)

// ---------------- CSR build ----------------
__global__ void k_count(const int* __restrict__ ei, int* deg) {
    int i = blockIdx.x*256 + threadIdx.x;
    if (i < N_EDGES) atomicAdd(&deg[ei[N_EDGES + i]], 1);
}
__global__ void k_scan(const int* __restrict__ deg, int* __restrict__ off,
                       int* __restrict__ cur, int n) {
    __shared__ int wsum[16];
    __shared__ int s_carry;
    int tid = threadIdx.x, lane = tid & 63, wid = tid >> 6;
    if (tid == 0) s_carry = 0;
    __syncthreads();
    for (int base = 0; base < n; base += 1024) {
        int i = base + tid;
        int v0 = (i < n) ? deg[i] : 0;
        int v = v0;
        for (int d = 1; d < 64; d <<= 1) { int t = __shfl_up(v, d, 64); if (lane >= d) v += t; }
        if (lane == 63) wsum[wid] = v;
        __syncthreads();
        if (wid == 0) {
            int w = (lane < 16) ? wsum[lane] : 0;
            for (int d = 1; d < 16; d <<= 1) { int t = __shfl_up(w, d, 64); if (lane >= d) w += t; }
            if (lane < 16) wsum[lane] = w;
        }
        __syncthreads();
        int wprev = (wid > 0) ? wsum[wid-1] : 0;
        int carry = s_carry;
        if (i < n) { int o = carry + wprev + (v - v0); off[i] = o; cur[i] = o; }
        __syncthreads();
        if (tid == 0) s_carry = carry + wsum[15];
        __syncthreads();
    }
    if (tid == 0) off[n] = s_carry;
}
__global__ void k_fill(const int* __restrict__ ei, int* cur, int* __restrict__ csrc) {
    int i = blockIdx.x*256 + threadIdx.x;
    if (i < N_EDGES) {
        int s = ei[i], d = ei[N_EDGES + i];
        int p = atomicAdd(&cur[d], 1);
        csrc[p] = s;
    } else if (i < N_EDGES + N_NODES) {
        int n = i - N_EDGES;
        int p = atomicAdd(&cur[n], 1);
        csrc[p] = n;
    }
}
// determinize: sort each CSR segment (deg ~5; atomic fill order varies run-to-run,
// which permutes bf16 summation order in agg kernels -> round-10 replay divergence)
__global__ void k_sortcsr(const int* __restrict__ offs, int* __restrict__ csrc) {
    int n = blockIdx.x*256 + threadIdx.x;
    if (n >= N_NODES) return;
    int s = offs[n], e = offs[n+1];
    for (int i = s + 1; i < e; i++) {
        int v = csrc[i];
        int j = i - 1;
        while (j >= s && csrc[j] > v) { csrc[j+1] = csrc[j]; j--; }
        csrc[j+1] = v;
    }
}

// ---------------- GEMM1 (MFMA): xp[N,96] @ W1t[784,96]^T -> h[N,800] bf16 (padded-80) ----------------
__global__ void k_gemm1_mfma(const short* __restrict__ Xp, const short* __restrict__ W1t,
                             u16* __restrict__ Hout) {
    int wave = threadIdx.x >> 6, lane = threadIdx.x & 63;
    int m16 = lane & 15, quad = lane >> 4;
    int r0 = blockIdx.x*64 + wave*16;
    int c0 = blockIdx.y*112;               // 7 col tiles of 16
    int rowc = min(r0 + m16, N_NODES-1);
    const short8* arow = (const short8*)(Xp + (size_t)rowc*KX);
    f32x4 acc[7];
    #pragma unroll
    for (int ct = 0; ct < 7; ct++) acc[ct] = (f32x4){0.f,0.f,0.f,0.f};
    #pragma unroll
    for (int kt = 0; kt < 3; kt++) {
        short8 af = arow[kt*4 + quad];
        #pragma unroll
        for (int ct = 0; ct < 7; ct++) {
            const short8* brow = (const short8*)(W1t + (size_t)(c0 + ct*16 + m16)*KX);
            short8 bf = brow[kt*4 + quad];
            acc[ct] = __builtin_amdgcn_mfma_f32_16x16x32_bf16(af, bf, acc[ct], 0, 0, 0);
        }
    }
    #pragma unroll
    for (int ct = 0; ct < 7; ct++) {
        int col = c0 + ct*16 + m16;
        if (col >= HC1) continue;
        int pcol = col + 2*(col/78);       // padded-80 position
        #pragma unroll
        for (int r = 0; r < 4; r++) {
            int orow = r0 + quad*4 + r;
            if (orow < N_NODES) Hout[(size_t)orow*HSTR + pcol] = f2bf(acc[ct][r]);
        }
    }
}

// ---------------- GEMM2 (MFMA): out1[N,800] @ W2t[128,800]^T -> h2[N,128] f32 ----------------
__global__ void k_gemm2_mfma(const short* __restrict__ A, const short* __restrict__ Bt,
                             float* __restrict__ Cout) {
    int wave = threadIdx.x >> 6, lane = threadIdx.x & 63;
    int m16 = lane & 15, quad = lane >> 4;
    int r0 = blockIdx.x*64 + wave*16;
    int rowc = min(r0 + m16, N_NODES-1);
    const short8* arow = (const short8*)(A + (size_t)rowc*HSTR);
    f32x4 acc[8];
    #pragma unroll
    for (int ct = 0; ct < 8; ct++) acc[ct] = (f32x4){0.f,0.f,0.f,0.f};
    for (int kt = 0; kt < 25; kt++) {
        short8 af = arow[kt*4 + quad];
        #pragma unroll
        for (int ct = 0; ct < 8; ct++) {
            const short8* brow = (const short8*)(Bt + (size_t)(ct*16 + m16)*HSTR);
            short8 bf = brow[kt*4 + quad];
            acc[ct] = __builtin_amdgcn_mfma_f32_16x16x32_bf16(af, bf, acc[ct], 0, 0, 0);
        }
    }
    #pragma unroll
    for (int ct = 0; ct < 8; ct++) {
        #pragma unroll
        for (int r = 0; r < 4; r++) {
            int orow = r0 + quad*4 + r;
            if (orow < N_NODES) Cout[(size_t)orow*C2c + ct*16 + m16] = acc[ct][r];
        }
    }
}

// ---------------- attention logit precompute ----------------
__global__ void k_att1(const u16* __restrict__ h, const float* __restrict__ a_src,
                       const float* __restrict__ a_dst, float* __restrict__ als,
                       float* __restrict__ ald) {
    int i = blockIdx.x*256 + threadIdx.x;
    if (i >= N_NODES*H1c) return;
    int n = i / H1c, hh = i - n*H1c;
    const unsigned* hp = (const unsigned*)(h + (size_t)n*HSTR + hh*80);
    const float* asv = a_src + hh*F0c;
    const float* adv = a_dst + hh*F0c;
    float s1 = 0.f, s2 = 0.f;
    #pragma unroll
    for (int c2 = 0; c2 < F0c/2; c2++) {
        unsigned u = hp[c2];
        float v0 = bflo(u), v1 = bfhi(u);
        s1 += v0*asv[2*c2] + v1*asv[2*c2+1];
        s2 += v0*adv[2*c2] + v1*adv[2*c2+1];
    }
    als[i] = s1; ald[i] = s2;
}
__global__ void k_att2(const float* __restrict__ h, const float* __restrict__ a_src,
                       const float* __restrict__ a_dst, float* __restrict__ als,
                       float* __restrict__ ald) {
    int n = blockIdx.x*256 + threadIdx.x;
    if (n >= N_NODES) return;
    const float* hp = h + (size_t)n*C2c;
    float s1 = 0.f, s2 = 0.f;
    for (int c = 0; c < C2c; c++) { float v = hp[c]; s1 += v*a_src[c]; s2 += v*a_dst[c]; }
    als[n] = s1; ald[n] = s2;
}

// ---------------- GAT layer-1 aggregation: one wave per dst, vectorized row gather ----------------
// Fast path deg<=64 (P(deg>64) ~ 1e-15 for this graph; LDS 2.9 KB -> 32 waves/CU).
__global__ void k_agg1(const u16* __restrict__ hbuf, const float* __restrict__ als,
                       const float* __restrict__ ald, const int* __restrict__ offs,
                       const int* __restrict__ csrc, const float* __restrict__ bpad,
                       u16* __restrict__ out) {
    constexpr int H = H1c;
    int dn = blockIdx.x, lane = threadIdx.x;   // 64
    int s = offs[dn], e = offs[dn+1], deg = e - s;
    __shared__ float wexp[64*H];               // 2560 B
    __shared__ int   ssrc[64];
    __shared__ float ms[H], dinv_s[H];

    if (deg <= 64) {
        if (lane < deg) ssrc[lane] = csrc[s + lane];
        __syncthreads();
        for (int idx = lane; idx < deg*H; idx += 64) {
            int j = idx / H, hh = idx - j*H;
            float al = als[(size_t)ssrc[j]*H + hh] + ald[(size_t)dn*H + hh];
            wexp[idx] = (al >= 0.f) ? al : 0.2f*al;
        }
        __syncthreads();
        if (lane < H) {
            float m = -1e30f;
            for (int j = 0; j < deg; j++) m = fmaxf(m, wexp[j*H + lane]);
            float den = 0.f;
            for (int j = 0; j < deg; j++) den += __expf(wexp[j*H + lane] - m);
            ms[lane] = m; dinv_s[lane] = 1.f/(den + 1e-16f);
        }
        __syncthreads();
        for (int idx = lane; idx < deg*H; idx += 64) {
            int hh = idx % H;
            wexp[idx] = __expf(wexp[idx] - ms[hh]) * dinv_s[hh];
        }
        __syncthreads();
        // vector accumulate over full padded row: 100 chunks of 8 bf16 (16 B)
        int q0 = lane, q1 = 64 + lane;
        int hd0 = q0 / 10, hd1 = q1 / 10;          // chunk 8q..8q+7 lies in head q/10 (80%8==0)
        bool act1 = (q1 < 100);
        float acc0[8], acc1[8];
        #pragma unroll
        for (int t = 0; t < 8; t++) { acc0[t] = 0.f; acc1[t] = 0.f; }
        for (int j = 0; j < deg; j++) {
            const uint4* row = (const uint4*)(hbuf + (size_t)ssrc[j]*HSTR);
            float a0 = wexp[j*H + hd0];
            uint4 v = row[q0];
            acc0[0] += a0*bflo(v.x); acc0[1] += a0*bfhi(v.x);
            acc0[2] += a0*bflo(v.y); acc0[3] += a0*bfhi(v.y);
            acc0[4] += a0*bflo(v.z); acc0[5] += a0*bfhi(v.z);
            acc0[6] += a0*bflo(v.w); acc0[7] += a0*bfhi(v.w);
            if (act1) {
                float a1 = wexp[j*H + hd1];
                uint4 w = row[q1];
                acc1[0] += a1*bflo(w.x); acc1[1] += a1*bfhi(w.x);
                acc1[2] += a1*bflo(w.y); acc1[3] += a1*bfhi(w.y);
                acc1[4] += a1*bflo(w.z); acc1[5] += a1*bfhi(w.z);
                acc1[6] += a1*bflo(w.w); acc1[7] += a1*bfhi(w.w);
            }
        }
        {
            short8 pk;
            #pragma unroll
            for (int t = 0; t < 8; t++) {
                float v = acc0[t] + bpad[q0*8 + t];
                v = (v > 0.f) ? v : (__expf(v) - 1.f);
                pk[t] = (short)f2bf(v);
            }
            *((short8*)(out + (size_t)dn*HSTR + q0*8)) = pk;
        }
        if (act1) {
            short8 pk;
            #pragma unroll
            for (int t = 0; t < 8; t++) {
                float v = acc1[t] + bpad[q1*8 + t];
                v = (v > 0.f) ? v : (__expf(v) - 1.f);
                pk[t] = (short)f2bf(v);
            }
            *((short8*)(out + (size_t)dn*HSTR + q1*8)) = pk;
        }
    } else {
        // fallback deg>64: scalar, guaranteed correct
        if (lane < H) {
            float adv = ald[(size_t)dn*H + lane];
            float m = -1e30f;
            for (int j = s; j < e; j++) {
                float al = als[(size_t)csrc[j]*H + lane] + adv;
                al = (al >= 0.f) ? al : 0.2f*al;
                m = fmaxf(m, al);
            }
            float den = 0.f;
            for (int j = s; j < e; j++) {
                float al = als[(size_t)csrc[j]*H + lane] + adv;
                al = (al >= 0.f) ? al : 0.2f*al;
                den += __expf(al - m);
            }
            ms[lane] = m; dinv_s[lane] = 1.f/(den + 1e-16f);
        }
        __syncthreads();
        for (int hh = 0; hh < H; hh++) {
            float m = ms[hh], dinv = dinv_s[hh];
            float adv = ald[(size_t)dn*H + hh];
            for (int cb = 0; cb < F0c; cb += 64) {
                int c = cb + lane;
                if (c < F0c) {
                    float acc = 0.f;
                    for (int j = s; j < e; j++) {
                        int sj = csrc[j];
                        float al = als[(size_t)sj*H + hh] + adv;
                        al = (al >= 0.f) ? al : 0.2f*al;
                        float alpha = __expf(al - m) * dinv;
                        acc += alpha * __uint_as_float(((unsigned)hbuf[(size_t)sj*HSTR + hh*80 + c]) << 16);
                    }
                    float v = acc + bpad[hh*80 + c];
                    v = (v > 0.f) ? v : (__expf(v) - 1.f);
                    out[(size_t)dn*HSTR + hh*80 + c] = f2bf(v);
                }
            }
        }
        if (lane < 20) {
            int hh = lane >> 1, cc = 78 + (lane & 1);
            out[(size_t)dn*HSTR + hh*80 + cc] = 0;
        }
    }
}

// ---------------- GAT layer-2 aggregation (H=1, C=128 f32) ----------------
__global__ void k_agg2(const float* __restrict__ h2, const float* __restrict__ als,
                       const float* __restrict__ ald, const int* __restrict__ offs,
                       const int* __restrict__ csrc, const float* __restrict__ b2,
                       float* __restrict__ out) {
    int dn = blockIdx.x, lane = threadIdx.x;   // 64
    int s = offs[dn], e = offs[dn+1], deg = e - s;
    __shared__ float wexp[128];
    __shared__ int ssrc[128];

    if (deg <= 128) {
        float adv = ald[dn];
        for (int j = lane; j < deg; j += 64) {
            int sj = csrc[s + j];
            ssrc[j] = sj;
            float al = als[sj] + adv;
            wexp[j] = (al >= 0.f) ? al : 0.2f*al;
        }
        __syncthreads();
        float m = -1e30f;
        for (int j = lane; j < deg; j += 64) m = fmaxf(m, wexp[j]);
        #pragma unroll
        for (int d = 32; d > 0; d >>= 1) m = fmaxf(m, __shfl_xor(m, d, 64));
        __syncthreads();
        float den = 0.f;
        for (int j = lane; j < deg; j += 64) {
            float ex = __expf(wexp[j] - m);
            wexp[j] = ex;
            den += ex;
        }
        #pragma unroll
        for (int d = 32; d > 0; d >>= 1) den += __shfl_xor(den, d, 64);
        float dinv = 1.f/(den + 1e-16f);
        __syncthreads();
        float2 acc = {0.f, 0.f};
        for (int j = 0; j < deg; j++) {
            float alpha = wexp[j] * dinv;
            float2 v = ((const float2*)(h2 + (size_t)ssrc[j]*C2c))[lane];
            acc.x += alpha*v.x; acc.y += alpha*v.y;
        }
        float2 o;
        o.x = fmaxf(acc.x + b2[2*lane], 0.f);
        o.y = fmaxf(acc.y + b2[2*lane+1], 0.f);
        ((float2*)(out + (size_t)dn*C2c))[lane] = o;
    } else {
        __shared__ float sm[2];
        if (lane == 0) {
            float adv = ald[dn];
            float m = -1e30f;
            for (int j = s; j < e; j++) {
                float al = als[csrc[j]] + adv;
                al = (al >= 0.f) ? al : 0.2f*al;
                m = fmaxf(m, al);
            }
            float den = 0.f;
            for (int j = s; j < e; j++) {
                float al = als[csrc[j]] + adv;
                al = (al >= 0.f) ? al : 0.2f*al;
                den += __expf(al - m);
            }
            sm[0] = m; sm[1] = 1.f/(den + 1e-16f);
        }
        __syncthreads();
        float m = sm[0], dinv = sm[1], adv = ald[dn];
        float2 acc = {0.f, 0.f};
        for (int j = s; j < e; j++) {
            int sj = csrc[j];
            float al = als[sj] + adv;
            al = (al >= 0.f) ? al : 0.2f*al;
            float alpha = __expf(al - m) * dinv;
            float2 v = ((const float2*)(h2 + (size_t)sj*C2c))[lane];
            acc.x += alpha*v.x; acc.y += alpha*v.y;
        }
        float2 o;
        o.x = fmaxf(acc.x + b2[2*lane], 0.f);
        o.y = fmaxf(acc.y + b2[2*lane+1], 0.f);
        ((float2*)(out + (size_t)dn*C2c))[lane] = o;
    }
}

// ---------------- global max pool (batch sorted) ----------------
__global__ void k_pool(const float* __restrict__ hf, const int* __restrict__ batch,
                       float* __restrict__ g) {
    int b = blockIdx.x, tid = threadIdx.x;    // 128
    __shared__ int se[2];
    if (tid < 2) {
        int key = b + tid;
        int lo = 0, hi = N_NODES;
        while (lo < hi) { int mid = (lo+hi) >> 1; if (batch[mid] < key) lo = mid+1; else hi = mid; }
        se[tid] = lo;
    }
    __syncthreads();
    int s = se[0], e = se[1];
    float m = -1e30f;
    for (int n = s; n < e; n++) m = fmaxf(m, hf[(size_t)n*C2c + tid]);
    g[b*C2c + tid] = m;
}
__global__ void k_fcg(const float* __restrict__ g, const float* __restrict__ W,
                      const float* __restrict__ bias, float* __restrict__ xc) {
    int b = blockIdx.x, tid = threadIdx.x;    // 128
    __shared__ float gs[C2c];
    gs[tid] = g[b*C2c + tid];
    __syncthreads();
    float acc = bias[tid];
    for (int k = 0; k < C2c; k++) acc += gs[k] * W[k*C2c + tid];
    xc[b*256 + tid] = fmaxf(acc, 0.f);
}

// ---------------- conv path ----------------
// deterministic bucket: stable rank via LDS scan (no atomic placement order)
__global__ void k_bucket(const int* __restrict__ target, int* __restrict__ ordered,
                         int* __restrict__ boff) {
    int b = blockIdx.x, tid = threadIdx.x;    // 256
    __shared__ unsigned char tg[SEQc];
    __shared__ int cnt[VOCABc];
    __shared__ int offs_s[VOCABc+1];
    if (tid < VOCABc) cnt[tid] = 0;
    __syncthreads();
    for (int i = tid; i < SEQc; i += 256) {
        int t = target[(size_t)b*SEQc + i];
        tg[i] = (unsigned char)t;
        atomicAdd(&cnt[t], 1);                // integer counts: order-independent
    }
    __syncthreads();
    if (tid == 0) { offs_s[0] = 0; for (int v = 0; v < VOCABc; v++) offs_s[v+1] = offs_s[v] + cnt[v]; }
    __syncthreads();
    if (tid < VOCABc+1) boff[b*(VOCABc+1) + tid] = offs_s[tid];
    // stable rank: rank(i) = #{j<i : tg[j]==tg[i]}  -> fully deterministic ordered[]
    for (int i = tid; i < SEQc; i += 256) {
        int t = tg[i], r = 0;
        for (int j = 0; j < i; j++) r += (tg[j] == t) ? 1 : 0;
        ordered[(size_t)b*SEQc + offs_s[t] + r] = i;
    }
}
__global__ void k_buildA(const float* __restrict__ convw, const int* __restrict__ ordered,
                         const int* __restrict__ boff, float* __restrict__ Amat) {
    int t = blockIdx.x, b = blockIdx.y;
    int tid = threadIdx.x;                // 256 = 32 o * 8 k
    int o = tid >> 3, k = tid & 7;
    int s = boff[b*(VOCABc+1) + t], e = boff[b*(VOCABc+1) + t + 1];
    const int* ord = ordered + (size_t)b*SEQc;
    float acc = 0.f;
    for (int j = s; j < e; j++) {
        int i = ord[j];
        acc += convw[((size_t)o*SEQc + i)*KWc + k];
    }
    Amat[(((size_t)b*NFc + o)*VOCABc + t)*KWc + k] = acc;
}
// conv -> bf16 [B][3872]; grid (B, 8): 4 channels/block.
// __launch_bounds__(128,4): VGPR cap 128 (no spill for 4 accs), 16 waves/CU.
__global__ void __launch_bounds__(128, 4)
k_conv(const float* __restrict__ Amat, const float* __restrict__ emb,
       const float* __restrict__ convb, u16* __restrict__ convout) {
    int b = blockIdx.x, og = blockIdx.y;      // og in 0..7 -> o base og*4
    int tid = threadIdx.x;                    // 128
    __shared__ float embs[VOCABc*EMBc];       // 13.3 KB
    __shared__ float arow[4*VOCABc*KWc];      // 3.3 KB
    for (int i = tid; i < VOCABc*EMBc; i += 128) embs[i] = emb[i];
    for (int i = tid; i < 4*VOCABc*KWc; i += 128)
        arow[i] = Amat[((size_t)b*NFc + og*4)*(VOCABc*KWc) + i];
    __syncthreads();
    if (tid < LOUTc) {
        float a0 = convb[og*4+0], a1 = convb[og*4+1], a2 = convb[og*4+2], a3 = convb[og*4+3];
        for (int t = 0; t < VOCABc; t++) {
            #pragma unroll
            for (int k = 0; k < KWc; k++) {
                float ev = embs[t*EMBc + tid + k];
                a0 += arow[0*(VOCABc*KWc) + t*KWc + k] * ev;
                a1 += arow[1*(VOCABc*KWc) + t*KWc + k] * ev;
                a2 += arow[2*(VOCABc*KWc) + t*KWc + k] * ev;
                a3 += arow[3*(VOCABc*KWc) + t*KWc + k] * ev;
            }
        }
        size_t base = (size_t)b*KXT + (og*4)*LOUTc + tid;
        convout[base            ] = f2bf(fmaxf(a0, 0.f));
        convout[base +   LOUTc  ] = f2bf(fmaxf(a1, 0.f));
        convout[base + 2*LOUTc  ] = f2bf(fmaxf(a2, 0.f));
        convout[base + 3*LOUTc  ] = f2bf(fmaxf(a3, 0.f));
    }
}
// fcxt (MFMA, K-split): partials -> fxp[11][512][128] (plain stores, deterministic)
__global__ void k_fcxt_mfma(const short* __restrict__ cvo, const short* __restrict__ wxt,
                            float* __restrict__ fxp) {
    int wave = threadIdx.x >> 6, lane = threadIdx.x & 63;
    int m16 = lane & 15, quad = lane >> 4;
    int r0 = blockIdx.x*64 + wave*16;      // 512 rows = 8 blocks * 64
    int kt0 = blockIdx.y*11;               // 121 k-steps = 11 chunks * 11
    const short8* arow = (const short8*)(cvo + (size_t)(r0 + m16)*KXT);
    f32x4 acc[8];
    #pragma unroll
    for (int ct = 0; ct < 8; ct++) acc[ct] = (f32x4){0.f,0.f,0.f,0.f};
    for (int kt = kt0; kt < kt0 + 11; kt++) {
        short8 af = arow[kt*4 + quad];
        #pragma unroll
        for (int ct = 0; ct < 8; ct++) {
            const short8* brow = (const short8*)(wxt + (size_t)(ct*16 + m16)*KXT);
            short8 bf = brow[kt*4 + quad];
            acc[ct] = __builtin_amdgcn_mfma_f32_16x16x32_bf16(af, bf, acc[ct], 0, 0, 0);
        }
    }
    #pragma unroll
    for (int ct = 0; ct < 8; ct++) {
        int col = ct*16 + m16;
        #pragma unroll
        for (int r = 0; r < 4; r++) {
            int row = r0 + quad*4 + r;
            fxp[((size_t)blockIdx.y*BGRAPHS + row)*C2c + col] = acc[ct][r];
        }
    }
}
// fixed-order reduction of the 11 K-chunk partials (+bias) -> xc[:,128:256]
__global__ void k_fcxt_red(const float* __restrict__ fxp, const float* __restrict__ bias,
                           float* __restrict__ xc) {
    int idx = blockIdx.x*256 + threadIdx.x;   // 0..65535
    if (idx >= BGRAPHS*C2c) return;
    int row = idx >> 7, col = idx & 127;
    float s = bias[col];
    #pragma unroll
    for (int q = 0; q < 11; q++) s += fxp[((size_t)q*BGRAPHS + row)*C2c + col];
    xc[(size_t)row*256 + 128 + col] = s;
}

// ---------------- head MLP (per-graph blocks, high occupancy) ----------------
__global__ void k_fc1(const float* __restrict__ xc, const float* __restrict__ W,
                      const float* __restrict__ bias, float* __restrict__ y1) {
    int b = blockIdx.x, tid = threadIdx.x;    // 256
    __shared__ float xs[256];
    xs[tid] = xc[b*256 + tid];
    __syncthreads();
    float a0 = bias[tid], a1 = bias[tid+256], a2 = bias[tid+512], a3 = bias[tid+768];
    for (int k = 0; k < 256; k++) {
        float xk = xs[k];
        const float* wr = W + (size_t)k*1024;
        a0 += xk*wr[tid]; a1 += xk*wr[tid+256]; a2 += xk*wr[tid+512]; a3 += xk*wr[tid+768];
    }
    y1[(size_t)b*1024 + tid      ] = fmaxf(a0, 0.f);
    y1[(size_t)b*1024 + tid + 256] = fmaxf(a1, 0.f);
    y1[(size_t)b*1024 + tid + 512] = fmaxf(a2, 0.f);
    y1[(size_t)b*1024 + tid + 768] = fmaxf(a3, 0.f);
}
__global__ void k_fc2(const float* __restrict__ y1, const float* __restrict__ W,
                      const float* __restrict__ bias, float* __restrict__ y2) {
    int b = blockIdx.x, tid = threadIdx.x;    // 256
    __shared__ float ys[1024];
    for (int i = tid; i < 1024; i += 256) ys[i] = y1[(size_t)b*1024 + i];
    __syncthreads();
    float acc = bias[tid];
    for (int k = 0; k < 1024; k++) acc += ys[k] * W[(size_t)k*256 + tid];
    y2[b*256 + tid] = fmaxf(acc, 0.f);
}
__global__ void k_out(const float* __restrict__ y2, const float* __restrict__ ow,
                      const float* __restrict__ ob, float* __restrict__ out) {
    int b = blockIdx.x, lane = threadIdx.x;   // 64
    float p = 0.f;
    for (int c = lane; c < 256; c += 64) p += y2[b*256 + c] * ow[c];
    for (int d = 32; d > 0; d >>= 1) p += __shfl_xor(p, d, 64);
    if (lane == 0) out[b] = p + ob[0];
}

extern "C" void kernel_launch(void* const* d_in, const int* in_sizes, int n_in,
                              void* d_out, int out_size, void* d_ws, size_t ws_size,
                              hipStream_t stream) {
    (void)in_sizes; (void)n_in; (void)out_size;
    if (ws_size < A_END) return;   // guard: clean numeric-fail if ws too small

    const float* x       = (const float*)d_in[0];
    const int*   ei      = (const int*)  d_in[1];
    const int*   batch   = (const int*)  d_in[2];
    const int*   target  = (const int*)  d_in[3];
    const float* W1      = (const float*)d_in[4];
    const float* a_src1  = (const float*)d_in[5];
    const float* a_dst1  = (const float*)d_in[6];
    const float* b1      = (const float*)d_in[7];
    const float* W2      = (const float*)d_in[8];
    const float* a_src2  = (const float*)d_in[9];
    const float* a_dst2  = (const float*)d_in[10];
    const float* b2      = (const float*)d_in[11];
    const float* fcg_w   = (const float*)d_in[12];
    const float* fcg_b   = (const float*)d_in[13];
    const float* emb     = (const float*)d_in[14];
    const float* conv_w  = (const float*)d_in[15];
    const float* conv_b  = (const float*)d_in[16];
    const float* fcxt_w  = (const float*)d_in[17];
    const float* fcxt_b  = (const float*)d_in[18];
    const float* fc1_w   = (const float*)d_in[19];
    const float* fc1_b   = (const float*)d_in[20];
    const float* fc2_w   = (const float*)d_in[21];
    const float* fc2_b   = (const float*)d_in[22];
    const float* out_w   = (const float*)d_in[23];
    const float* out_b   = (const float*)d_in[24];

    char* wsb = (char*)d_ws;
    u16*   hbuf  = (u16*)  (wsb + A_HBUF);
    u16*   out1  = (u16*)  (wsb + A_OUT1);
    float* h2    = (float*)(wsb + A_H2);
    __hip_bfloat16* w2t = (__hip_bfloat16*)(wsb + A_W2T);
    float* als1  = (float*)(wsb + A_ALS1);
    float* ald1  = (float*)(wsb + A_ALD1);
    float* als2  = (float*)(wsb + A_ALS2);
    float* ald2  = (float*)(wsb + A_ALD2);
    int*   deg   = (int*)  (wsb + A_DEG);
    int*   offs  = (int*)  (wsb + A_OFFS);
    int*   cur   = (int*)  (wsb + A_CUR);
    int*   csrc  = (int*)  (wsb + A_CSRC);
    float* g     = (float*)(wsb + A_G);
    float* xc    = (float*)(wsb + A_XC);
    float* y1    = (float*)(wsb + A_Y1);
    float* y2    = (float*)(wsb + A_Y2);
    int*   boff  = (int*)  (wsb + A_BOFF);
    float* bpad  = (float*)(wsb + A_BPAD);
    __hip_bfloat16* wxt = (__hip_bfloat16*)(wsb + A_WXT);
    float* fxp   = (float*)(wsb + A_FXP);
    // aliases:
    float* hfin  = (float*)(wsb + A_HFIN);
    int*   ord   = (int*)  (wsb + A_ORD);
    float* Amat  = (float*)(wsb + A_AMAT);
    u16*   cvo   = (u16*)  (wsb + A_CVO);
    __hip_bfloat16* xpad = (__hip_bfloat16*)(wsb + A_XPAD);
    __hip_bfloat16* w1t  = (__hip_bfloat16*)(wsb + A_W1T);

    // prep: deg init + conversions + padded bias
    k_prep<<<(PREP_TOTAL+255)/256, 256, 0, stream>>>(x, W1, W2, b1, fcxt_w,
                                                     xpad, w1t, w2t, bpad, wxt, deg);
    // CSR build (+ deterministic segment sort)
    k_count  <<<(N_EDGES+255)/256, 256, 0, stream>>>(ei, deg);
    k_scan   <<<1, 1024, 0, stream>>>(deg, offs, cur, N_NODES);
    k_fill   <<<(N_EDGES+N_NODES+255)/256, 256, 0, stream>>>(ei, cur, csrc);
    k_sortcsr<<<(N_NODES+255)/256, 256, 0, stream>>>(offs, csrc);

    // GAT layer 1
    k_gemm1_mfma<<<dim3((N_NODES+63)/64, 7), 256, 0, stream>>>((const short*)xpad, (const short*)w1t, hbuf);
    k_att1<<<(N_NODES*H1c+255)/256, 256, 0, stream>>>(hbuf, a_src1, a_dst1, als1, ald1);
    k_agg1<<<N_NODES, 64, 0, stream>>>(hbuf, als1, ald1, offs, csrc, bpad, out1);
    // ---- hbuf dead; xpad/w1t dead (out1 region now live) ----

    // GAT layer 2
    k_gemm2_mfma<<<(N_NODES+63)/64, 256, 0, stream>>>((const short*)out1, (const short*)w2t, h2);
    k_att2<<<(N_NODES+255)/256, 256, 0, stream>>>(h2, a_src2, a_dst2, als2, ald2);
    k_agg2<<<N_NODES, 64, 0, stream>>>(h2, als2, ald2, offs, csrc, b2, hfin);

    // pool + fc_g1 -> xc[:, 0:128]
    k_pool<<<BGRAPHS, 128, 0, stream>>>(hfin, batch, g);
    k_fcg <<<BGRAPHS, 128, 0, stream>>>(g, fcg_w, fcg_b, xc);

    // conv path -> xc[:, 128:256]
    k_bucket<<<BGRAPHS, 256, 0, stream>>>(target, ord, boff);
    k_buildA<<<dim3(VOCABc, BGRAPHS), 256, 0, stream>>>(conv_w, ord, boff, Amat);
    k_conv  <<<dim3(BGRAPHS, 8), 128, 0, stream>>>(Amat, emb, conv_b, cvo);
    k_fcxt_mfma<<<dim3(BGRAPHS/64, 11), 256, 0, stream>>>((const short*)cvo, (const short*)wxt, fxp);
    k_fcxt_red <<<(BGRAPHS*C2c+255)/256, 256, 0, stream>>>(fxp, fcxt_b, xc);

    // head MLP
    k_fc1<<<BGRAPHS, 256, 0, stream>>>(xc, fc1_w, fc1_b, y1);
    k_fc2<<<BGRAPHS, 256, 0, stream>>>(y1, fc2_w, fc2_b, y2);
    k_out<<<BGRAPHS, 64, 0, stream>>>(y2, out_w, out_b, (float*)d_out);
}

// Round 12
// 691.361 us; speedup vs baseline: 1.5473x; 1.1031x over previous
//
#include <hip/hip_runtime.h>
#include <hip/hip_bf16.h>

// Problem constants (from reference)
#define N_NODES 50000
#define N_EDGES 200000
#define BGRAPHS 512
#define F0c 78
#define H1c 10
#define HC1 780     // H1*F0 (logical)
#define HSTR 800    // padded row stride: 10 head blocks of 80 (78 data + 2 pad)
#define C2c 128
#define SEQc 1000
#define VOCABc 26
#define NFc 32
#define KWc 8
#define LOUTc 121
#define EMBc 128
#define KX 96       // padded K for gemm1 (78 -> 96)
#define KXT 3872    // NF*LOUT = 32*121 -> 121 MFMA k-steps, split 11 x 11

typedef __attribute__((ext_vector_type(8))) short short8;
typedef __attribute__((ext_vector_type(4))) float f32x4;
typedef unsigned short u16;

static constexpr size_t alignup(size_t x) { return (x + 255) & ~size_t(255); }

// -------- workspace layout (bytes) --------
static constexpr size_t A_HBUF = 0;                                          // bf16 [N,800] = 80 MB
static constexpr size_t A_OUT1 = alignup(A_HBUF + size_t(N_NODES)*HSTR*2);   // bf16 [N,800] = 80 MB
static constexpr size_t A_H2   = alignup(A_OUT1 + size_t(N_NODES)*HSTR*2);   // f32  [N,128]
static constexpr size_t A_W2T  = alignup(A_H2   + size_t(N_NODES)*C2c*4);    // bf16 [128,800] padded-80 layout
static constexpr size_t A_ALS1 = alignup(A_W2T  + size_t(C2c)*HSTR*2);
static constexpr size_t A_ALD1 = alignup(A_ALS1 + size_t(N_NODES)*H1c*4);
static constexpr size_t A_ALS2 = alignup(A_ALD1 + size_t(N_NODES)*H1c*4);
static constexpr size_t A_ALD2 = alignup(A_ALS2 + size_t(N_NODES)*4);
static constexpr size_t A_DEG  = alignup(A_ALD2 + size_t(N_NODES)*4);
static constexpr size_t A_OFFS = alignup(A_DEG  + size_t(N_NODES)*4);
static constexpr size_t A_CUR  = alignup(A_OFFS + size_t(N_NODES+1)*4);
static constexpr size_t A_CSRC = alignup(A_CUR  + size_t(N_NODES)*4);
static constexpr size_t A_G    = alignup(A_CSRC + size_t(N_EDGES+N_NODES)*4);
static constexpr size_t A_XC   = alignup(A_G    + size_t(BGRAPHS)*C2c*4);
static constexpr size_t A_Y1   = alignup(A_XC   + size_t(BGRAPHS)*256*4);
static constexpr size_t A_Y2   = alignup(A_Y1   + size_t(BGRAPHS)*1024*4);
static constexpr size_t A_BOFF = alignup(A_Y2   + size_t(BGRAPHS)*256*4);
static constexpr size_t A_BPAD = alignup(A_BOFF + size_t(BGRAPHS)*(VOCABc+1)*4);
static constexpr size_t A_WXT  = alignup(A_BPAD + size_t(HSTR)*4);           // bf16 [128][3872]
static constexpr size_t A_FXP  = alignup(A_WXT  + size_t(C2c)*KXT*2);        // f32 [11][512][128] fcxt partials
static constexpr size_t A_END  = alignup(A_FXP  + size_t(11)*BGRAPHS*C2c*4);

// aliases inside hbuf region (valid after k_agg1 retires; hbuf dead then):
static constexpr size_t A_HFIN = A_HBUF;                                        // f32 [N,128]
static constexpr size_t A_ORD  = alignup(A_HFIN + size_t(N_NODES)*C2c*4);
static constexpr size_t A_AMAT = alignup(A_ORD  + size_t(BGRAPHS)*SEQc*4);
static constexpr size_t A_CVO  = alignup(A_AMAT + size_t(BGRAPHS)*NFc*VOCABc*KWc*4);  // bf16 [512][3872]
static_assert(A_CVO + size_t(BGRAPHS)*KXT*2 <= size_t(N_NODES)*HSTR*2, "alias A overflow");
// aliases inside out1 region (valid until k_agg1 writes out1):
static constexpr size_t A_XPAD = A_OUT1;                                        // bf16 [N,96]
static constexpr size_t A_W1T  = alignup(A_XPAD + size_t(N_NODES)*KX*2);        // bf16 [784,96]
static_assert(A_W1T + size_t(784)*KX*2 - A_OUT1 <= size_t(N_NODES)*HSTR*2, "alias B overflow");

// -------- helpers --------
__device__ __forceinline__ float bflo(unsigned u) { return __uint_as_float(u << 16); }
__device__ __forceinline__ float bfhi(unsigned u) { return __uint_as_float(u & 0xffff0000u); }
__device__ __forceinline__ u16 f2bf(float v) {
    __hip_bfloat16 b = __float2bfloat16(v);
    return *(u16*)&b;
}

// ---------------- prep: deg init + bf16 conversions + padded bias ----------------
__global__ void k_prep(const float* __restrict__ x, const float* __restrict__ W1,
                       const float* __restrict__ W2, const float* __restrict__ b1,
                       const float* __restrict__ fcxt_w,
                       __hip_bfloat16* __restrict__ xpad, __hip_bfloat16* __restrict__ w1t,
                       __hip_bfloat16* __restrict__ w2t, float* __restrict__ bpad,
                       __hip_bfloat16* __restrict__ wxt, int* __restrict__ deg) {
    int i = blockIdx.x*256 + threadIdx.x;
    const int R0 = N_NODES;
    const int R1 = R0 + N_NODES*KX;
    const int R2 = R1 + 784*KX;
    const int R3 = R2 + C2c*HSTR;
    const int R4 = R3 + HSTR;
    const int R5 = R4 + C2c*KXT;
    if (i < R0) {
        deg[i] = 1;   // self loop
    } else if (i < R1) {
        int t = i - R0; int n = t / KX, c = t - n*KX;
        xpad[t] = __float2bfloat16(c < F0c ? x[(size_t)n*F0c + c] : 0.f);
    } else if (i < R2) {
        int t = i - R1; int r = t / KX, k = t - r*KX;
        w1t[t] = __float2bfloat16((r < HC1 && k < F0c) ? W1[(size_t)k*HC1 + r] : 0.f);
    } else if (i < R3) {
        int t = i - R2; int c = t / HSTR, p = t - c*HSTR;
        int hh = p / 80, cc = p - hh*80;
        w2t[t] = __float2bfloat16(cc < F0c ? W2[(size_t)(hh*F0c + cc)*C2c + c] : 0.f);
    } else if (i < R4) {
        int p = i - R3; int hh = p / 80, cc = p - hh*80;
        bpad[p] = (cc < F0c) ? b1[hh*F0c + cc] : 0.f;
    } else if (i < R5) {
        int t = i - R4; int c = t / KXT, j = t - c*KXT;
        wxt[t] = __float2bfloat16(fcxt_w[(size_t)j*C2c + c]);
    }
}
#define PREP_TOTAL (N_NODES + N_NODES*KX + 784*KX + C2c*HSTR + HSTR + C2c*KXT)

// ---------------- CSR build ----------------
__global__ void k_count(const int* __restrict__ ei, int* deg) {
    int i = blockIdx.x*256 + threadIdx.x;
    if (i < N_EDGES) atomicAdd(&deg[ei[N_EDGES + i]], 1);
}
__global__ void k_scan(const int* __restrict__ deg, int* __restrict__ off,
                       int* __restrict__ cur, int n) {
    __shared__ int wsum[16];
    __shared__ int s_carry;
    int tid = threadIdx.x, lane = tid & 63, wid = tid >> 6;
    if (tid == 0) s_carry = 0;
    __syncthreads();
    for (int base = 0; base < n; base += 1024) {
        int i = base + tid;
        int v0 = (i < n) ? deg[i] : 0;
        int v = v0;
        for (int d = 1; d < 64; d <<= 1) { int t = __shfl_up(v, d, 64); if (lane >= d) v += t; }
        if (lane == 63) wsum[wid] = v;
        __syncthreads();
        if (wid == 0) {
            int w = (lane < 16) ? wsum[lane] : 0;
            for (int d = 1; d < 16; d <<= 1) { int t = __shfl_up(w, d, 64); if (lane >= d) w += t; }
            if (lane < 16) wsum[lane] = w;
        }
        __syncthreads();
        int wprev = (wid > 0) ? wsum[wid-1] : 0;
        int carry = s_carry;
        if (i < n) { int o = carry + wprev + (v - v0); off[i] = o; cur[i] = o; }
        __syncthreads();
        if (tid == 0) s_carry = carry + wsum[15];
        __syncthreads();
    }
    if (tid == 0) off[n] = s_carry;
}
__global__ void k_fill(const int* __restrict__ ei, int* cur, int* __restrict__ csrc) {
    int i = blockIdx.x*256 + threadIdx.x;
    if (i < N_EDGES) {
        int s = ei[i], d = ei[N_EDGES + i];
        int p = atomicAdd(&cur[d], 1);
        csrc[p] = s;
    } else if (i < N_EDGES + N_NODES) {
        int n = i - N_EDGES;
        int p = atomicAdd(&cur[n], 1);
        csrc[p] = n;
    }
}
// determinize: sort each CSR segment (deg ~5; atomic fill order varies run-to-run,
// which permutes bf16 summation order in agg kernels -> round-10 replay divergence)
__global__ void k_sortcsr(const int* __restrict__ offs, int* __restrict__ csrc) {
    int n = blockIdx.x*256 + threadIdx.x;
    if (n >= N_NODES) return;
    int s = offs[n], e = offs[n+1];
    for (int i = s + 1; i < e; i++) {
        int v = csrc[i];
        int j = i - 1;
        while (j >= s && csrc[j] > v) { csrc[j+1] = csrc[j]; j--; }
        csrc[j+1] = v;
    }
}

// ---------------- GEMM1 (MFMA): xp[N,96] @ W1t[784,96]^T -> h[N,800] bf16 (padded-80) ----------------
__global__ void k_gemm1_mfma(const short* __restrict__ Xp, const short* __restrict__ W1t,
                             u16* __restrict__ Hout) {
    int wave = threadIdx.x >> 6, lane = threadIdx.x & 63;
    int m16 = lane & 15, quad = lane >> 4;
    int r0 = blockIdx.x*64 + wave*16;
    int c0 = blockIdx.y*112;               // 7 col tiles of 16
    int rowc = min(r0 + m16, N_NODES-1);
    const short8* arow = (const short8*)(Xp + (size_t)rowc*KX);
    f32x4 acc[7];
    #pragma unroll
    for (int ct = 0; ct < 7; ct++) acc[ct] = (f32x4){0.f,0.f,0.f,0.f};
    #pragma unroll
    for (int kt = 0; kt < 3; kt++) {
        short8 af = arow[kt*4 + quad];
        #pragma unroll
        for (int ct = 0; ct < 7; ct++) {
            const short8* brow = (const short8*)(W1t + (size_t)(c0 + ct*16 + m16)*KX);
            short8 bf = brow[kt*4 + quad];
            acc[ct] = __builtin_amdgcn_mfma_f32_16x16x32_bf16(af, bf, acc[ct], 0, 0, 0);
        }
    }
    #pragma unroll
    for (int ct = 0; ct < 7; ct++) {
        int col = c0 + ct*16 + m16;
        if (col >= HC1) continue;
        int pcol = col + 2*(col/78);       // padded-80 position
        #pragma unroll
        for (int r = 0; r < 4; r++) {
            int orow = r0 + quad*4 + r;
            if (orow < N_NODES) Hout[(size_t)orow*HSTR + pcol] = f2bf(acc[ct][r]);
        }
    }
}

// ---------------- GEMM2 (MFMA): out1[N,800] @ W2t[128,800]^T -> h2[N,128] f32 ----------------
__global__ void k_gemm2_mfma(const short* __restrict__ A, const short* __restrict__ Bt,
                             float* __restrict__ Cout) {
    int wave = threadIdx.x >> 6, lane = threadIdx.x & 63;
    int m16 = lane & 15, quad = lane >> 4;
    int r0 = blockIdx.x*64 + wave*16;
    int rowc = min(r0 + m16, N_NODES-1);
    const short8* arow = (const short8*)(A + (size_t)rowc*HSTR);
    f32x4 acc[8];
    #pragma unroll
    for (int ct = 0; ct < 8; ct++) acc[ct] = (f32x4){0.f,0.f,0.f,0.f};
    for (int kt = 0; kt < 25; kt++) {
        short8 af = arow[kt*4 + quad];
        #pragma unroll
        for (int ct = 0; ct < 8; ct++) {
            const short8* brow = (const short8*)(Bt + (size_t)(ct*16 + m16)*HSTR);
            short8 bf = brow[kt*4 + quad];
            acc[ct] = __builtin_amdgcn_mfma_f32_16x16x32_bf16(af, bf, acc[ct], 0, 0, 0);
        }
    }
    #pragma unroll
    for (int ct = 0; ct < 8; ct++) {
        #pragma unroll
        for (int r = 0; r < 4; r++) {
            int orow = r0 + quad*4 + r;
            if (orow < N_NODES) Cout[(size_t)orow*C2c + ct*16 + m16] = acc[ct][r];
        }
    }
}

// ---------------- attention logit precompute ----------------
__global__ void k_att1(const u16* __restrict__ h, const float* __restrict__ a_src,
                       const float* __restrict__ a_dst, float* __restrict__ als,
                       float* __restrict__ ald) {
    int i = blockIdx.x*256 + threadIdx.x;
    if (i >= N_NODES*H1c) return;
    int n = i / H1c, hh = i - n*H1c;
    const unsigned* hp = (const unsigned*)(h + (size_t)n*HSTR + hh*80);
    const float* asv = a_src + hh*F0c;
    const float* adv = a_dst + hh*F0c;
    float s1 = 0.f, s2 = 0.f;
    #pragma unroll
    for (int c2 = 0; c2 < F0c/2; c2++) {
        unsigned u = hp[c2];
        float v0 = bflo(u), v1 = bfhi(u);
        s1 += v0*asv[2*c2] + v1*asv[2*c2+1];
        s2 += v0*adv[2*c2] + v1*adv[2*c2+1];
    }
    als[i] = s1; ald[i] = s2;
}
__global__ void k_att2(const float* __restrict__ h, const float* __restrict__ a_src,
                       const float* __restrict__ a_dst, float* __restrict__ als,
                       float* __restrict__ ald) {
    int n = blockIdx.x*256 + threadIdx.x;
    if (n >= N_NODES) return;
    const float* hp = h + (size_t)n*C2c;
    float s1 = 0.f, s2 = 0.f;
    for (int c = 0; c < C2c; c++) { float v = hp[c]; s1 += v*a_src[c]; s2 += v*a_dst[c]; }
    als[n] = s1; ald[n] = s2;
}

// ---------------- GAT layer-1 aggregation: one wave per dst, vectorized row gather ----------------
// Fast path deg<=64 (P(deg>64) ~ 1e-15 for this graph; LDS 2.9 KB -> 32 waves/CU).
__global__ void k_agg1(const u16* __restrict__ hbuf, const float* __restrict__ als,
                       const float* __restrict__ ald, const int* __restrict__ offs,
                       const int* __restrict__ csrc, const float* __restrict__ bpad,
                       u16* __restrict__ out) {
    constexpr int H = H1c;
    int dn = blockIdx.x, lane = threadIdx.x;   // 64
    int s = offs[dn], e = offs[dn+1], deg = e - s;
    __shared__ float wexp[64*H];               // 2560 B
    __shared__ int   ssrc[64];
    __shared__ float ms[H], dinv_s[H];

    if (deg <= 64) {
        if (lane < deg) ssrc[lane] = csrc[s + lane];
        __syncthreads();
        for (int idx = lane; idx < deg*H; idx += 64) {
            int j = idx / H, hh = idx - j*H;
            float al = als[(size_t)ssrc[j]*H + hh] + ald[(size_t)dn*H + hh];
            wexp[idx] = (al >= 0.f) ? al : 0.2f*al;
        }
        __syncthreads();
        if (lane < H) {
            float m = -1e30f;
            for (int j = 0; j < deg; j++) m = fmaxf(m, wexp[j*H + lane]);
            float den = 0.f;
            for (int j = 0; j < deg; j++) den += __expf(wexp[j*H + lane] - m);
            ms[lane] = m; dinv_s[lane] = 1.f/(den + 1e-16f);
        }
        __syncthreads();
        for (int idx = lane; idx < deg*H; idx += 64) {
            int hh = idx % H;
            wexp[idx] = __expf(wexp[idx] - ms[hh]) * dinv_s[hh];
        }
        __syncthreads();
        // vector accumulate over full padded row: 100 chunks of 8 bf16 (16 B)
        int q0 = lane, q1 = 64 + lane;
        int hd0 = q0 / 10, hd1 = q1 / 10;          // chunk 8q..8q+7 lies in head q/10 (80%8==0)
        bool act1 = (q1 < 100);
        float acc0[8], acc1[8];
        #pragma unroll
        for (int t = 0; t < 8; t++) { acc0[t] = 0.f; acc1[t] = 0.f; }
        for (int j = 0; j < deg; j++) {
            const uint4* row = (const uint4*)(hbuf + (size_t)ssrc[j]*HSTR);
            float a0 = wexp[j*H + hd0];
            uint4 v = row[q0];
            acc0[0] += a0*bflo(v.x); acc0[1] += a0*bfhi(v.x);
            acc0[2] += a0*bflo(v.y); acc0[3] += a0*bfhi(v.y);
            acc0[4] += a0*bflo(v.z); acc0[5] += a0*bfhi(v.z);
            acc0[6] += a0*bflo(v.w); acc0[7] += a0*bfhi(v.w);
            if (act1) {
                float a1 = wexp[j*H + hd1];
                uint4 w = row[q1];
                acc1[0] += a1*bflo(w.x); acc1[1] += a1*bfhi(w.x);
                acc1[2] += a1*bflo(w.y); acc1[3] += a1*bfhi(w.y);
                acc1[4] += a1*bflo(w.z); acc1[5] += a1*bfhi(w.z);
                acc1[6] += a1*bflo(w.w); acc1[7] += a1*bfhi(w.w);
            }
        }
        {
            short8 pk;
            #pragma unroll
            for (int t = 0; t < 8; t++) {
                float v = acc0[t] + bpad[q0*8 + t];
                v = (v > 0.f) ? v : (__expf(v) - 1.f);
                pk[t] = (short)f2bf(v);
            }
            *((short8*)(out + (size_t)dn*HSTR + q0*8)) = pk;
        }
        if (act1) {
            short8 pk;
            #pragma unroll
            for (int t = 0; t < 8; t++) {
                float v = acc1[t] + bpad[q1*8 + t];
                v = (v > 0.f) ? v : (__expf(v) - 1.f);
                pk[t] = (short)f2bf(v);
            }
            *((short8*)(out + (size_t)dn*HSTR + q1*8)) = pk;
        }
    } else {
        // fallback deg>64: scalar, guaranteed correct
        if (lane < H) {
            float adv = ald[(size_t)dn*H + lane];
            float m = -1e30f;
            for (int j = s; j < e; j++) {
                float al = als[(size_t)csrc[j]*H + lane] + adv;
                al = (al >= 0.f) ? al : 0.2f*al;
                m = fmaxf(m, al);
            }
            float den = 0.f;
            for (int j = s; j < e; j++) {
                float al = als[(size_t)csrc[j]*H + lane] + adv;
                al = (al >= 0.f) ? al : 0.2f*al;
                den += __expf(al - m);
            }
            ms[lane] = m; dinv_s[lane] = 1.f/(den + 1e-16f);
        }
        __syncthreads();
        for (int hh = 0; hh < H; hh++) {
            float m = ms[hh], dinv = dinv_s[hh];
            float adv = ald[(size_t)dn*H + hh];
            for (int cb = 0; cb < F0c; cb += 64) {
                int c = cb + lane;
                if (c < F0c) {
                    float acc = 0.f;
                    for (int j = s; j < e; j++) {
                        int sj = csrc[j];
                        float al = als[(size_t)sj*H + hh] + adv;
                        al = (al >= 0.f) ? al : 0.2f*al;
                        float alpha = __expf(al - m) * dinv;
                        acc += alpha * __uint_as_float(((unsigned)hbuf[(size_t)sj*HSTR + hh*80 + c]) << 16);
                    }
                    float v = acc + bpad[hh*80 + c];
                    v = (v > 0.f) ? v : (__expf(v) - 1.f);
                    out[(size_t)dn*HSTR + hh*80 + c] = f2bf(v);
                }
            }
        }
        if (lane < 20) {
            int hh = lane >> 1, cc = 78 + (lane & 1);
            out[(size_t)dn*HSTR + hh*80 + cc] = 0;
        }
    }
}

// ---------------- GAT layer-2 aggregation (H=1, C=128 f32) ----------------
__global__ void k_agg2(const float* __restrict__ h2, const float* __restrict__ als,
                       const float* __restrict__ ald, const int* __restrict__ offs,
                       const int* __restrict__ csrc, const float* __restrict__ b2,
                       float* __restrict__ out) {
    int dn = blockIdx.x, lane = threadIdx.x;   // 64
    int s = offs[dn], e = offs[dn+1], deg = e - s;
    __shared__ float wexp[128];
    __shared__ int ssrc[128];

    if (deg <= 128) {
        float adv = ald[dn];
        for (int j = lane; j < deg; j += 64) {
            int sj = csrc[s + j];
            ssrc[j] = sj;
            float al = als[sj] + adv;
            wexp[j] = (al >= 0.f) ? al : 0.2f*al;
        }
        __syncthreads();
        float m = -1e30f;
        for (int j = lane; j < deg; j += 64) m = fmaxf(m, wexp[j]);
        #pragma unroll
        for (int d = 32; d > 0; d >>= 1) m = fmaxf(m, __shfl_xor(m, d, 64));
        __syncthreads();
        float den = 0.f;
        for (int j = lane; j < deg; j += 64) {
            float ex = __expf(wexp[j] - m);
            wexp[j] = ex;
            den += ex;
        }
        #pragma unroll
        for (int d = 32; d > 0; d >>= 1) den += __shfl_xor(den, d, 64);
        float dinv = 1.f/(den + 1e-16f);
        __syncthreads();
        float2 acc = {0.f, 0.f};
        for (int j = 0; j < deg; j++) {
            float alpha = wexp[j] * dinv;
            float2 v = ((const float2*)(h2 + (size_t)ssrc[j]*C2c))[lane];
            acc.x += alpha*v.x; acc.y += alpha*v.y;
        }
        float2 o;
        o.x = fmaxf(acc.x + b2[2*lane], 0.f);
        o.y = fmaxf(acc.y + b2[2*lane+1], 0.f);
        ((float2*)(out + (size_t)dn*C2c))[lane] = o;
    } else {
        __shared__ float sm[2];
        if (lane == 0) {
            float adv = ald[dn];
            float m = -1e30f;
            for (int j = s; j < e; j++) {
                float al = als[csrc[j]] + adv;
                al = (al >= 0.f) ? al : 0.2f*al;
                m = fmaxf(m, al);
            }
            float den = 0.f;
            for (int j = s; j < e; j++) {
                float al = als[csrc[j]] + adv;
                al = (al >= 0.f) ? al : 0.2f*al;
                den += __expf(al - m);
            }
            sm[0] = m; sm[1] = 1.f/(den + 1e-16f);
        }
        __syncthreads();
        float m = sm[0], dinv = sm[1], adv = ald[dn];
        float2 acc = {0.f, 0.f};
        for (int j = s; j < e; j++) {
            int sj = csrc[j];
            float al = als[sj] + adv;
            al = (al >= 0.f) ? al : 0.2f*al;
            float alpha = __expf(al - m) * dinv;
            float2 v = ((const float2*)(h2 + (size_t)sj*C2c))[lane];
            acc.x += alpha*v.x; acc.y += alpha*v.y;
        }
        float2 o;
        o.x = fmaxf(acc.x + b2[2*lane], 0.f);
        o.y = fmaxf(acc.y + b2[2*lane+1], 0.f);
        ((float2*)(out + (size_t)dn*C2c))[lane] = o;
    }
}

// ---------------- global max pool (batch sorted) ----------------
__global__ void k_pool(const float* __restrict__ hf, const int* __restrict__ batch,
                       float* __restrict__ g) {
    int b = blockIdx.x, tid = threadIdx.x;    // 128
    __shared__ int se[2];
    if (tid < 2) {
        int key = b + tid;
        int lo = 0, hi = N_NODES;
        while (lo < hi) { int mid = (lo+hi) >> 1; if (batch[mid] < key) lo = mid+1; else hi = mid; }
        se[tid] = lo;
    }
    __syncthreads();
    int s = se[0], e = se[1];
    float m = -1e30f;
    for (int n = s; n < e; n++) m = fmaxf(m, hf[(size_t)n*C2c + tid]);
    g[b*C2c + tid] = m;
}
__global__ void k_fcg(const float* __restrict__ g, const float* __restrict__ W,
                      const float* __restrict__ bias, float* __restrict__ xc) {
    int b = blockIdx.x, tid = threadIdx.x;    // 128
    __shared__ float gs[C2c];
    gs[tid] = g[b*C2c + tid];
    __syncthreads();
    float acc = bias[tid];
    for (int k = 0; k < C2c; k++) acc += gs[k] * W[k*C2c + tid];
    xc[b*256 + tid] = fmaxf(acc, 0.f);
}

// ---------------- conv path ----------------
// deterministic O(SEQ) counting sort: thread-private LDS columns, no atomics.
// Chunk t = items [4t, 4t+4); cnt[v][t] private to thread t (no races, stable).
__global__ void k_bucket(const int* __restrict__ target, int* __restrict__ ordered,
                         int* __restrict__ boff) {
    int b = blockIdx.x, tid = threadIdx.x;    // 256
    __shared__ unsigned char tg[SEQc];
    __shared__ u16 cnt[VOCABc][256];          // 13.3 KB, [v][chunk]
    __shared__ int offs_s[VOCABc+1];
    __shared__ int tot[VOCABc];
    for (int i = tid; i < VOCABc*256; i += 256) ((u16*)cnt)[i] = 0;
    __syncthreads();
    int i0 = tid*4;
    #pragma unroll
    for (int k = 0; k < 4; k++) {
        int i = i0 + k;
        if (i < SEQc) {
            int t = target[(size_t)b*SEQc + i];
            tg[i] = (unsigned char)t;
            cnt[t][tid]++;                    // column tid private
        }
    }
    __syncthreads();
    // exclusive prefix over chunks for each vocab (threads 0..25, serial 256 — cheap)
    if (tid < VOCABc) {
        int run = 0;
        for (int c = 0; c < 256; c++) {
            int v = cnt[tid][c];
            cnt[tid][c] = (u16)run;
            run += v;
        }
        tot[tid] = run;
    }
    __syncthreads();
    if (tid == 0) {
        offs_s[0] = 0;
        for (int v = 0; v < VOCABc; v++) offs_s[v+1] = offs_s[v] + tot[v];
    }
    __syncthreads();
    if (tid < VOCABc+1) boff[b*(VOCABc+1) + tid] = offs_s[tid];
    // place items in order using private running cursor cnt[v][tid]
    #pragma unroll
    for (int k = 0; k < 4; k++) {
        int i = i0 + k;
        if (i < SEQc) {
            int t = tg[i];
            int r = cnt[t][tid]++;
            ordered[(size_t)b*SEQc + offs_s[t] + r] = i;
        }
    }
}
__global__ void k_buildA(const float* __restrict__ convw, const int* __restrict__ ordered,
                         const int* __restrict__ boff, float* __restrict__ Amat) {
    int t = blockIdx.x, b = blockIdx.y;
    int tid = threadIdx.x;                // 256 = 32 o * 8 k
    int o = tid >> 3, k = tid & 7;
    int s = boff[b*(VOCABc+1) + t], e = boff[b*(VOCABc+1) + t + 1];
    const int* ord = ordered + (size_t)b*SEQc;
    float acc = 0.f;
    for (int j = s; j < e; j++) {
        int i = ord[j];
        acc += convw[((size_t)o*SEQc + i)*KWc + k];
    }
    Amat[(((size_t)b*NFc + o)*VOCABc + t)*KWc + k] = acc;
}
// conv -> bf16 [B][3872]; grid (B, 8): 4 channels/block.
// __launch_bounds__(128,4): VGPR cap 128 (no spill for 4 accs), 16 waves/CU.
__global__ void __launch_bounds__(128, 4)
k_conv(const float* __restrict__ Amat, const float* __restrict__ emb,
       const float* __restrict__ convb, u16* __restrict__ convout) {
    int b = blockIdx.x, og = blockIdx.y;      // og in 0..7 -> o base og*4
    int tid = threadIdx.x;                    // 128
    __shared__ float embs[VOCABc*EMBc];       // 13.3 KB
    __shared__ float arow[4*VOCABc*KWc];      // 3.3 KB
    for (int i = tid; i < VOCABc*EMBc; i += 128) embs[i] = emb[i];
    for (int i = tid; i < 4*VOCABc*KWc; i += 128)
        arow[i] = Amat[((size_t)b*NFc + og*4)*(VOCABc*KWc) + i];
    __syncthreads();
    if (tid < LOUTc) {
        float a0 = convb[og*4+0], a1 = convb[og*4+1], a2 = convb[og*4+2], a3 = convb[og*4+3];
        for (int t = 0; t < VOCABc; t++) {
            #pragma unroll
            for (int k = 0; k < KWc; k++) {
                float ev = embs[t*EMBc + tid + k];
                a0 += arow[0*(VOCABc*KWc) + t*KWc + k] * ev;
                a1 += arow[1*(VOCABc*KWc) + t*KWc + k] * ev;
                a2 += arow[2*(VOCABc*KWc) + t*KWc + k] * ev;
                a3 += arow[3*(VOCABc*KWc) + t*KWc + k] * ev;
            }
        }
        size_t base = (size_t)b*KXT + (og*4)*LOUTc + tid;
        convout[base            ] = f2bf(fmaxf(a0, 0.f));
        convout[base +   LOUTc  ] = f2bf(fmaxf(a1, 0.f));
        convout[base + 2*LOUTc  ] = f2bf(fmaxf(a2, 0.f));
        convout[base + 3*LOUTc  ] = f2bf(fmaxf(a3, 0.f));
    }
}
// fcxt (MFMA, K-split): partials -> fxp[11][512][128] (plain stores, deterministic)
__global__ void k_fcxt_mfma(const short* __restrict__ cvo, const short* __restrict__ wxt,
                            float* __restrict__ fxp) {
    int wave = threadIdx.x >> 6, lane = threadIdx.x & 63;
    int m16 = lane & 15, quad = lane >> 4;
    int r0 = blockIdx.x*64 + wave*16;      // 512 rows = 8 blocks * 64
    int kt0 = blockIdx.y*11;               // 121 k-steps = 11 chunks * 11
    const short8* arow = (const short8*)(cvo + (size_t)(r0 + m16)*KXT);
    f32x4 acc[8];
    #pragma unroll
    for (int ct = 0; ct < 8; ct++) acc[ct] = (f32x4){0.f,0.f,0.f,0.f};
    for (int kt = kt0; kt < kt0 + 11; kt++) {
        short8 af = arow[kt*4 + quad];
        #pragma unroll
        for (int ct = 0; ct < 8; ct++) {
            const short8* brow = (const short8*)(wxt + (size_t)(ct*16 + m16)*KXT);
            short8 bf = brow[kt*4 + quad];
            acc[ct] = __builtin_amdgcn_mfma_f32_16x16x32_bf16(af, bf, acc[ct], 0, 0, 0);
        }
    }
    #pragma unroll
    for (int ct = 0; ct < 8; ct++) {
        int col = ct*16 + m16;
        #pragma unroll
        for (int r = 0; r < 4; r++) {
            int row = r0 + quad*4 + r;
            fxp[((size_t)blockIdx.y*BGRAPHS + row)*C2c + col] = acc[ct][r];
        }
    }
}
// fixed-order reduction of the 11 K-chunk partials (+bias) -> xc[:,128:256]
__global__ void k_fcxt_red(const float* __restrict__ fxp, const float* __restrict__ bias,
                           float* __restrict__ xc) {
    int idx = blockIdx.x*256 + threadIdx.x;   // 0..65535
    if (idx >= BGRAPHS*C2c) return;
    int row = idx >> 7, col = idx & 127;
    float s = bias[col];
    #pragma unroll
    for (int q = 0; q < 11; q++) s += fxp[((size_t)q*BGRAPHS + row)*C2c + col];
    xc[(size_t)row*256 + 128 + col] = s;
}

// ---------------- head MLP (per-graph blocks, high occupancy) ----------------
__global__ void k_fc1(const float* __restrict__ xc, const float* __restrict__ W,
                      const float* __restrict__ bias, float* __restrict__ y1) {
    int b = blockIdx.x, tid = threadIdx.x;    // 256
    __shared__ float xs[256];
    xs[tid] = xc[b*256 + tid];
    __syncthreads();
    float a0 = bias[tid], a1 = bias[tid+256], a2 = bias[tid+512], a3 = bias[tid+768];
    for (int k = 0; k < 256; k++) {
        float xk = xs[k];
        const float* wr = W + (size_t)k*1024;
        a0 += xk*wr[tid]; a1 += xk*wr[tid+256]; a2 += xk*wr[tid+512]; a3 += xk*wr[tid+768];
    }
    y1[(size_t)b*1024 + tid      ] = fmaxf(a0, 0.f);
    y1[(size_t)b*1024 + tid + 256] = fmaxf(a1, 0.f);
    y1[(size_t)b*1024 + tid + 512] = fmaxf(a2, 0.f);
    y1[(size_t)b*1024 + tid + 768] = fmaxf(a3, 0.f);
}
__global__ void k_fc2(const float* __restrict__ y1, const float* __restrict__ W,
                      const float* __restrict__ bias, float* __restrict__ y2) {
    int b = blockIdx.x, tid = threadIdx.x;    // 256
    __shared__ float ys[1024];
    for (int i = tid; i < 1024; i += 256) ys[i] = y1[(size_t)b*1024 + i];
    __syncthreads();
    float acc = bias[tid];
    for (int k = 0; k < 1024; k++) acc += ys[k] * W[(size_t)k*256 + tid];
    y2[b*256 + tid] = fmaxf(acc, 0.f);
}
__global__ void k_out(const float* __restrict__ y2, const float* __restrict__ ow,
                      const float* __restrict__ ob, float* __restrict__ out) {
    int b = blockIdx.x, lane = threadIdx.x;   // 64
    float p = 0.f;
    for (int c = lane; c < 256; c += 64) p += y2[b*256 + c] * ow[c];
    for (int d = 32; d > 0; d >>= 1) p += __shfl_xor(p, d, 64);
    if (lane == 0) out[b] = p + ob[0];
}

extern "C" void kernel_launch(void* const* d_in, const int* in_sizes, int n_in,
                              void* d_out, int out_size, void* d_ws, size_t ws_size,
                              hipStream_t stream) {
    (void)in_sizes; (void)n_in; (void)out_size;
    if (ws_size < A_END) return;   // guard: clean numeric-fail if ws too small

    const float* x       = (const float*)d_in[0];
    const int*   ei      = (const int*)  d_in[1];
    const int*   batch   = (const int*)  d_in[2];
    const int*   target  = (const int*)  d_in[3];
    const float* W1      = (const float*)d_in[4];
    const float* a_src1  = (const float*)d_in[5];
    const float* a_dst1  = (const float*)d_in[6];
    const float* b1      = (const float*)d_in[7];
    const float* W2      = (const float*)d_in[8];
    const float* a_src2  = (const float*)d_in[9];
    const float* a_dst2  = (const float*)d_in[10];
    const float* b2      = (const float*)d_in[11];
    const float* fcg_w   = (const float*)d_in[12];
    const float* fcg_b   = (const float*)d_in[13];
    const float* emb     = (const float*)d_in[14];
    const float* conv_w  = (const float*)d_in[15];
    const float* conv_b  = (const float*)d_in[16];
    const float* fcxt_w  = (const float*)d_in[17];
    const float* fcxt_b  = (const float*)d_in[18];
    const float* fc1_w   = (const float*)d_in[19];
    const float* fc1_b   = (const float*)d_in[20];
    const float* fc2_w   = (const float*)d_in[21];
    const float* fc2_b   = (const float*)d_in[22];
    const float* out_w   = (const float*)d_in[23];
    const float* out_b   = (const float*)d_in[24];

    char* wsb = (char*)d_ws;
    u16*   hbuf  = (u16*)  (wsb + A_HBUF);
    u16*   out1  = (u16*)  (wsb + A_OUT1);
    float* h2    = (float*)(wsb + A_H2);
    __hip_bfloat16* w2t = (__hip_bfloat16*)(wsb + A_W2T);
    float* als1  = (float*)(wsb + A_ALS1);
    float* ald1  = (float*)(wsb + A_ALD1);
    float* als2  = (float*)(wsb + A_ALS2);
    float* ald2  = (float*)(wsb + A_ALD2);
    int*   deg   = (int*)  (wsb + A_DEG);
    int*   offs  = (int*)  (wsb + A_OFFS);
    int*   cur   = (int*)  (wsb + A_CUR);
    int*   csrc  = (int*)  (wsb + A_CSRC);
    float* g     = (float*)(wsb + A_G);
    float* xc    = (float*)(wsb + A_XC);
    float* y1    = (float*)(wsb + A_Y1);
    float* y2    = (float*)(wsb + A_Y2);
    int*   boff  = (int*)  (wsb + A_BOFF);
    float* bpad  = (float*)(wsb + A_BPAD);
    __hip_bfloat16* wxt = (__hip_bfloat16*)(wsb + A_WXT);
    float* fxp   = (float*)(wsb + A_FXP);
    // aliases:
    float* hfin  = (float*)(wsb + A_HFIN);
    int*   ord   = (int*)  (wsb + A_ORD);
    float* Amat  = (float*)(wsb + A_AMAT);
    u16*   cvo   = (u16*)  (wsb + A_CVO);
    __hip_bfloat16* xpad = (__hip_bfloat16*)(wsb + A_XPAD);
    __hip_bfloat16* w1t  = (__hip_bfloat16*)(wsb + A_W1T);

    // prep: deg init + conversions + padded bias
    k_prep<<<(PREP_TOTAL+255)/256, 256, 0, stream>>>(x, W1, W2, b1, fcxt_w,
                                                     xpad, w1t, w2t, bpad, wxt, deg);
    // CSR build (+ deterministic segment sort)
    k_count  <<<(N_EDGES+255)/256, 256, 0, stream>>>(ei, deg);
    k_scan   <<<1, 1024, 0, stream>>>(deg, offs, cur, N_NODES);
    k_fill   <<<(N_EDGES+N_NODES+255)/256, 256, 0, stream>>>(ei, cur, csrc);
    k_sortcsr<<<(N_NODES+255)/256, 256, 0, stream>>>(offs, csrc);

    // GAT layer 1
    k_gemm1_mfma<<<dim3((N_NODES+63)/64, 7), 256, 0, stream>>>((const short*)xpad, (const short*)w1t, hbuf);
    k_att1<<<(N_NODES*H1c+255)/256, 256, 0, stream>>>(hbuf, a_src1, a_dst1, als1, ald1);
    k_agg1<<<N_NODES, 64, 0, stream>>>(hbuf, als1, ald1, offs, csrc, bpad, out1);
    // ---- hbuf dead; xpad/w1t dead (out1 region now live) ----

    // GAT layer 2
    k_gemm2_mfma<<<(N_NODES+63)/64, 256, 0, stream>>>((const short*)out1, (const short*)w2t, h2);
    k_att2<<<(N_NODES+255)/256, 256, 0, stream>>>(h2, a_src2, a_dst2, als2, ald2);
    k_agg2<<<N_NODES, 64, 0, stream>>>(h2, als2, ald2, offs, csrc, b2, hfin);

    // pool + fc_g1 -> xc[:, 0:128]
    k_pool<<<BGRAPHS, 128, 0, stream>>>(hfin, batch, g);
    k_fcg <<<BGRAPHS, 128, 0, stream>>>(g, fcg_w, fcg_b, xc);

    // conv path -> xc[:, 128:256]
    k_bucket<<<BGRAPHS, 256, 0, stream>>>(target, ord, boff);
    k_buildA<<<dim3(VOCABc, BGRAPHS), 256, 0, stream>>>(conv_w, ord, boff, Amat);
    k_conv  <<<dim3(BGRAPHS, 8), 128, 0, stream>>>(Amat, emb, conv_b, cvo);
    k_fcxt_mfma<<<dim3(BGRAPHS/64, 11), 256, 0, stream>>>((const short*)cvo, (const short*)wxt, fxp);
    k_fcxt_red <<<(BGRAPHS*C2c+255)/256, 256, 0, stream>>>(fxp, fcxt_b, xc);

    // head MLP
    k_fc1<<<BGRAPHS, 256, 0, stream>>>(xc, fc1_w, fc1_b, y1);
    k_fc2<<<BGRAPHS, 256, 0, stream>>>(y1, fc2_w, fc2_b, y2);
    k_out<<<BGRAPHS, 64, 0, stream>>>(y2, out_w, out_b, (float*)d_out);
}

// Round 13
// 674.554 us; speedup vs baseline: 1.5858x; 1.0249x over previous
//
#include <hip/hip_runtime.h>
#include <hip/hip_bf16.h>

// Problem constants (from reference)
#define N_NODES 50000
#define N_EDGES 200000
#define BGRAPHS 512
#define F0c 78
#define H1c 10
#define HC1 780     // H1*F0 (logical)
#define HSTR 800    // padded row stride: 10 head blocks of 80 (78 data + 2 pad)
#define C2c 128
#define SEQc 1000
#define VOCABc 26
#define NFc 32
#define KWc 8
#define LOUTc 121
#define EMBc 128
#define KX 96       // padded K for gemm1 (78 -> 96)
#define KXT 3872    // NF*LOUT = 32*121 -> 121 MFMA k-steps, split 11 x 11

typedef __attribute__((ext_vector_type(8))) short short8;
typedef __attribute__((ext_vector_type(4))) float f32x4;
typedef unsigned short u16;

static constexpr size_t alignup(size_t x) { return (x + 255) & ~size_t(255); }

// -------- workspace layout (bytes) --------
static constexpr size_t A_HBUF = 0;                                          // bf16 [N,800] = 80 MB
static constexpr size_t A_OUT1 = alignup(A_HBUF + size_t(N_NODES)*HSTR*2);   // bf16 [N,800] = 80 MB
static constexpr size_t A_H2   = alignup(A_OUT1 + size_t(N_NODES)*HSTR*2);   // f32  [N,128]
static constexpr size_t A_W2T  = alignup(A_H2   + size_t(N_NODES)*C2c*4);    // bf16 [128,800] padded-80 layout
static constexpr size_t A_ALS1 = alignup(A_W2T  + size_t(C2c)*HSTR*2);
static constexpr size_t A_ALD1 = alignup(A_ALS1 + size_t(N_NODES)*H1c*4);
static constexpr size_t A_ALS2 = alignup(A_ALD1 + size_t(N_NODES)*H1c*4);
static constexpr size_t A_ALD2 = alignup(A_ALS2 + size_t(N_NODES)*4);
static constexpr size_t A_DEG  = alignup(A_ALD2 + size_t(N_NODES)*4);
static constexpr size_t A_OFFS = alignup(A_DEG  + size_t(N_NODES)*4);
static constexpr size_t A_CUR  = alignup(A_OFFS + size_t(N_NODES+1)*4);
static constexpr size_t A_CSRC = alignup(A_CUR  + size_t(N_NODES)*4);
static constexpr size_t A_XC   = alignup(A_CSRC + size_t(N_EDGES+N_NODES)*4);
static constexpr size_t A_Y1   = alignup(A_XC   + size_t(BGRAPHS)*256*4);
static constexpr size_t A_BOFF = alignup(A_Y1   + size_t(BGRAPHS)*1024*4);
static constexpr size_t A_BPAD = alignup(A_BOFF + size_t(BGRAPHS)*(VOCABc+1)*4);
static constexpr size_t A_WXT  = alignup(A_BPAD + size_t(HSTR)*4);           // bf16 [128][3872]
static constexpr size_t A_FXP  = alignup(A_WXT  + size_t(C2c)*KXT*2);        // f32 [11][512][128] fcxt partials
static constexpr size_t A_END  = alignup(A_FXP  + size_t(11)*BGRAPHS*C2c*4);

// aliases inside hbuf region (valid after k_agg1 retires; hbuf dead then):
static constexpr size_t A_HFIN = A_HBUF;                                        // f32 [N,128]
static constexpr size_t A_ORD  = alignup(A_HFIN + size_t(N_NODES)*C2c*4);
static constexpr size_t A_AMAT = alignup(A_ORD  + size_t(BGRAPHS)*SEQc*4);
static constexpr size_t A_CVO  = alignup(A_AMAT + size_t(BGRAPHS)*NFc*VOCABc*KWc*4);  // bf16 [512][3872]
static_assert(A_CVO + size_t(BGRAPHS)*KXT*2 <= size_t(N_NODES)*HSTR*2, "alias A overflow");
// aliases inside out1 region (valid until k_agg1 writes out1):
static constexpr size_t A_XPAD = A_OUT1;                                        // bf16 [N,96]
static constexpr size_t A_W1T  = alignup(A_XPAD + size_t(N_NODES)*KX*2);        // bf16 [784,96]
static_assert(A_W1T + size_t(784)*KX*2 - A_OUT1 <= size_t(N_NODES)*HSTR*2, "alias B overflow");

// -------- helpers --------
__device__ __forceinline__ float bflo(unsigned u) { return __uint_as_float(u << 16); }
__device__ __forceinline__ float bfhi(unsigned u) { return __uint_as_float(u & 0xffff0000u); }
__device__ __forceinline__ u16 f2bf(float v) {
    __hip_bfloat16 b = __float2bfloat16(v);
    return *(u16*)&b;
}

// ---------------- prep: deg init + bf16 conversions + padded bias ----------------
__global__ void k_prep(const float* __restrict__ x, const float* __restrict__ W1,
                       const float* __restrict__ W2, const float* __restrict__ b1,
                       const float* __restrict__ fcxt_w,
                       __hip_bfloat16* __restrict__ xpad, __hip_bfloat16* __restrict__ w1t,
                       __hip_bfloat16* __restrict__ w2t, float* __restrict__ bpad,
                       __hip_bfloat16* __restrict__ wxt, int* __restrict__ deg) {
    int i = blockIdx.x*256 + threadIdx.x;
    const int R0 = N_NODES;
    const int R1 = R0 + N_NODES*KX;
    const int R2 = R1 + 784*KX;
    const int R3 = R2 + C2c*HSTR;
    const int R4 = R3 + HSTR;
    const int R5 = R4 + C2c*KXT;
    if (i < R0) {
        deg[i] = 1;   // self loop
    } else if (i < R1) {
        int t = i - R0; int n = t / KX, c = t - n*KX;
        xpad[t] = __float2bfloat16(c < F0c ? x[(size_t)n*F0c + c] : 0.f);
    } else if (i < R2) {
        int t = i - R1; int r = t / KX, k = t - r*KX;
        w1t[t] = __float2bfloat16((r < HC1 && k < F0c) ? W1[(size_t)k*HC1 + r] : 0.f);
    } else if (i < R3) {
        int t = i - R2; int c = t / HSTR, p = t - c*HSTR;
        int hh = p / 80, cc = p - hh*80;
        w2t[t] = __float2bfloat16(cc < F0c ? W2[(size_t)(hh*F0c + cc)*C2c + c] : 0.f);
    } else if (i < R4) {
        int p = i - R3; int hh = p / 80, cc = p - hh*80;
        bpad[p] = (cc < F0c) ? b1[hh*F0c + cc] : 0.f;
    } else if (i < R5) {
        int t = i - R4; int c = t / KXT, j = t - c*KXT;
        wxt[t] = __float2bfloat16(fcxt_w[(size_t)j*C2c + c]);
    }
}
#define PREP_TOTAL (N_NODES + N_NODES*KX + 784*KX + C2c*HSTR + HSTR + C2c*KXT)

// ---------------- CSR build ----------------
__global__ void k_count(const int* __restrict__ ei, int* deg) {
    int i = blockIdx.x*256 + threadIdx.x;
    if (i < N_EDGES) atomicAdd(&deg[ei[N_EDGES + i]], 1);
}
__global__ void k_scan(const int* __restrict__ deg, int* __restrict__ off,
                       int* __restrict__ cur, int n) {
    __shared__ int wsum[16];
    __shared__ int s_carry;
    int tid = threadIdx.x, lane = tid & 63, wid = tid >> 6;
    if (tid == 0) s_carry = 0;
    __syncthreads();
    for (int base = 0; base < n; base += 1024) {
        int i = base + tid;
        int v0 = (i < n) ? deg[i] : 0;
        int v = v0;
        for (int d = 1; d < 64; d <<= 1) { int t = __shfl_up(v, d, 64); if (lane >= d) v += t; }
        if (lane == 63) wsum[wid] = v;
        __syncthreads();
        if (wid == 0) {
            int w = (lane < 16) ? wsum[lane] : 0;
            for (int d = 1; d < 16; d <<= 1) { int t = __shfl_up(w, d, 64); if (lane >= d) w += t; }
            if (lane < 16) wsum[lane] = w;
        }
        __syncthreads();
        int wprev = (wid > 0) ? wsum[wid-1] : 0;
        int carry = s_carry;
        if (i < n) { int o = carry + wprev + (v - v0); off[i] = o; cur[i] = o; }
        __syncthreads();
        if (tid == 0) s_carry = carry + wsum[15];
        __syncthreads();
    }
    if (tid == 0) off[n] = s_carry;
}
__global__ void k_fill(const int* __restrict__ ei, int* cur, int* __restrict__ csrc) {
    int i = blockIdx.x*256 + threadIdx.x;
    if (i < N_EDGES) {
        int s = ei[i], d = ei[N_EDGES + i];
        int p = atomicAdd(&cur[d], 1);
        csrc[p] = s;
    } else if (i < N_EDGES + N_NODES) {
        int n = i - N_EDGES;
        int p = atomicAdd(&cur[n], 1);
        csrc[p] = n;
    }
}
// determinize: sort each CSR segment (atomic fill order varies run-to-run)
__global__ void k_sortcsr(const int* __restrict__ offs, int* __restrict__ csrc) {
    int n = blockIdx.x*256 + threadIdx.x;
    if (n >= N_NODES) return;
    int s = offs[n], e = offs[n+1];
    for (int i = s + 1; i < e; i++) {
        int v = csrc[i];
        int j = i - 1;
        while (j >= s && csrc[j] > v) { csrc[j+1] = csrc[j]; j--; }
        csrc[j+1] = v;
    }
}

// ---------------- GEMM1 (MFMA): xp[N,96] @ W1t[784,96]^T -> h[N,800] bf16 (padded-80) ----------------
__global__ void k_gemm1_mfma(const short* __restrict__ Xp, const short* __restrict__ W1t,
                             u16* __restrict__ Hout) {
    int wave = threadIdx.x >> 6, lane = threadIdx.x & 63;
    int m16 = lane & 15, quad = lane >> 4;
    int r0 = blockIdx.x*64 + wave*16;
    int c0 = blockIdx.y*112;               // 7 col tiles of 16
    int rowc = min(r0 + m16, N_NODES-1);
    const short8* arow = (const short8*)(Xp + (size_t)rowc*KX);
    f32x4 acc[7];
    #pragma unroll
    for (int ct = 0; ct < 7; ct++) acc[ct] = (f32x4){0.f,0.f,0.f,0.f};
    #pragma unroll
    for (int kt = 0; kt < 3; kt++) {
        short8 af = arow[kt*4 + quad];
        #pragma unroll
        for (int ct = 0; ct < 7; ct++) {
            const short8* brow = (const short8*)(W1t + (size_t)(c0 + ct*16 + m16)*KX);
            short8 bf = brow[kt*4 + quad];
            acc[ct] = __builtin_amdgcn_mfma_f32_16x16x32_bf16(af, bf, acc[ct], 0, 0, 0);
        }
    }
    #pragma unroll
    for (int ct = 0; ct < 7; ct++) {
        int col = c0 + ct*16 + m16;
        if (col >= HC1) continue;
        int pcol = col + 2*(col/78);       // padded-80 position
        #pragma unroll
        for (int r = 0; r < 4; r++) {
            int orow = r0 + quad*4 + r;
            if (orow < N_NODES) Hout[(size_t)orow*HSTR + pcol] = f2bf(acc[ct][r]);
        }
    }
}

// ---------------- GEMM2 (MFMA) + att2 fold: out1 @ W2t^T -> h2, als2, ald2 ----------------
__global__ void k_gemm2_mfma(const short* __restrict__ A, const short* __restrict__ Bt,
                             const float* __restrict__ a_src2, const float* __restrict__ a_dst2,
                             float* __restrict__ Cout, float* __restrict__ als2,
                             float* __restrict__ ald2) {
    int wave = threadIdx.x >> 6, lane = threadIdx.x & 63;
    int m16 = lane & 15, quad = lane >> 4;
    int r0 = blockIdx.x*64 + wave*16;
    int rowc = min(r0 + m16, N_NODES-1);
    const short8* arow = (const short8*)(A + (size_t)rowc*HSTR);
    f32x4 acc[8];
    #pragma unroll
    for (int ct = 0; ct < 8; ct++) acc[ct] = (f32x4){0.f,0.f,0.f,0.f};
    for (int kt = 0; kt < 25; kt++) {
        short8 af = arow[kt*4 + quad];
        #pragma unroll
        for (int ct = 0; ct < 8; ct++) {
            const short8* brow = (const short8*)(Bt + (size_t)(ct*16 + m16)*HSTR);
            short8 bf = brow[kt*4 + quad];
            acc[ct] = __builtin_amdgcn_mfma_f32_16x16x32_bf16(af, bf, acc[ct], 0, 0, 0);
        }
    }
    #pragma unroll
    for (int ct = 0; ct < 8; ct++) {
        #pragma unroll
        for (int r = 0; r < 4; r++) {
            int orow = r0 + quad*4 + r;
            if (orow < N_NODES) Cout[(size_t)orow*C2c + ct*16 + m16] = acc[ct][r];
        }
    }
    // att2 fold: per-row dots vs a_src2/a_dst2, reduced across the 16-lane m16 group
    float asv[8], adv[8];
    #pragma unroll
    for (int ct = 0; ct < 8; ct++) { asv[ct] = a_src2[ct*16 + m16]; adv[ct] = a_dst2[ct*16 + m16]; }
    #pragma unroll
    for (int r = 0; r < 4; r++) {
        float s1 = 0.f, s2 = 0.f;
        #pragma unroll
        for (int ct = 0; ct < 8; ct++) { s1 += acc[ct][r]*asv[ct]; s2 += acc[ct][r]*adv[ct]; }
        #pragma unroll
        for (int d = 1; d < 16; d <<= 1) { s1 += __shfl_xor(s1, d, 64); s2 += __shfl_xor(s2, d, 64); }
        int orow = r0 + quad*4 + r;
        if (m16 == 0 && orow < N_NODES) { als2[orow] = s1; ald2[orow] = s2; }
    }
}

// ---------------- attention logit precompute (layer 1) ----------------
__global__ void k_att1(const u16* __restrict__ h, const float* __restrict__ a_src,
                       const float* __restrict__ a_dst, float* __restrict__ als,
                       float* __restrict__ ald) {
    int i = blockIdx.x*256 + threadIdx.x;
    if (i >= N_NODES*H1c) return;
    int n = i / H1c, hh = i - n*H1c;
    const unsigned* hp = (const unsigned*)(h + (size_t)n*HSTR + hh*80);
    const float* asv = a_src + hh*F0c;
    const float* adv = a_dst + hh*F0c;
    float s1 = 0.f, s2 = 0.f;
    #pragma unroll
    for (int c2 = 0; c2 < F0c/2; c2++) {
        unsigned u = hp[c2];
        float v0 = bflo(u), v1 = bfhi(u);
        s1 += v0*asv[2*c2] + v1*asv[2*c2+1];
        s2 += v0*adv[2*c2] + v1*adv[2*c2+1];
    }
    als[i] = s1; ald[i] = s2;
}

// ---------------- GAT layer-1 aggregation: one wave per dst, 2x-unrolled gather ----------------
__global__ void k_agg1(const u16* __restrict__ hbuf, const float* __restrict__ als,
                       const float* __restrict__ ald, const int* __restrict__ offs,
                       const int* __restrict__ csrc, const float* __restrict__ bpad,
                       u16* __restrict__ out) {
    constexpr int H = H1c;
    int dn = blockIdx.x, lane = threadIdx.x;   // 64
    int s = offs[dn], e = offs[dn+1], deg = e - s;
    __shared__ float wexp[64*H];               // 2560 B
    __shared__ int   ssrc[64];
    __shared__ float ms[H], dinv_s[H];

    if (deg <= 64) {
        if (lane < deg) ssrc[lane] = csrc[s + lane];
        __syncthreads();
        for (int idx = lane; idx < deg*H; idx += 64) {
            int j = idx / H, hh = idx - j*H;
            float al = als[(size_t)ssrc[j]*H + hh] + ald[(size_t)dn*H + hh];
            wexp[idx] = (al >= 0.f) ? al : 0.2f*al;
        }
        __syncthreads();
        if (lane < H) {
            float m = -1e30f;
            for (int j = 0; j < deg; j++) m = fmaxf(m, wexp[j*H + lane]);
            float den = 0.f;
            for (int j = 0; j < deg; j++) den += __expf(wexp[j*H + lane] - m);
            ms[lane] = m; dinv_s[lane] = 1.f/(den + 1e-16f);
        }
        __syncthreads();
        for (int idx = lane; idx < deg*H; idx += 64) {
            int hh = idx % H;
            wexp[idx] = __expf(wexp[idx] - ms[hh]) * dinv_s[hh];
        }
        __syncthreads();
        // vector accumulate, 2 edges per iteration (4 gathers in flight)
        int q0 = lane, q1 = 64 + lane;
        int hd0 = q0 / 10, hd1 = q1 / 10;
        bool act1 = (q1 < 100);
        float acc0[8], acc1[8];
        #pragma unroll
        for (int t = 0; t < 8; t++) { acc0[t] = 0.f; acc1[t] = 0.f; }
        int j = 0;
        for (; j + 1 < deg; j += 2) {
            const uint4* rowA = (const uint4*)(hbuf + (size_t)ssrc[j]*HSTR);
            const uint4* rowB = (const uint4*)(hbuf + (size_t)ssrc[j+1]*HSTR);
            float aA = wexp[j*H + hd0], aB = wexp[(j+1)*H + hd0];
            uint4 va = rowA[q0], vb = rowB[q0];
            acc0[0] += aA*bflo(va.x) + aB*bflo(vb.x);
            acc0[1] += aA*bfhi(va.x) + aB*bfhi(vb.x);
            acc0[2] += aA*bflo(va.y) + aB*bflo(vb.y);
            acc0[3] += aA*bfhi(va.y) + aB*bfhi(vb.y);
            acc0[4] += aA*bflo(va.z) + aB*bflo(vb.z);
            acc0[5] += aA*bfhi(va.z) + aB*bfhi(vb.z);
            acc0[6] += aA*bflo(va.w) + aB*bflo(vb.w);
            acc0[7] += aA*bfhi(va.w) + aB*bfhi(vb.w);
            if (act1) {
                float cA = wexp[j*H + hd1], cB = wexp[(j+1)*H + hd1];
                uint4 wa = rowA[q1], wb = rowB[q1];
                acc1[0] += cA*bflo(wa.x) + cB*bflo(wb.x);
                acc1[1] += cA*bfhi(wa.x) + cB*bfhi(wb.x);
                acc1[2] += cA*bflo(wa.y) + cB*bflo(wb.y);
                acc1[3] += cA*bfhi(wa.y) + cB*bfhi(wb.y);
                acc1[4] += cA*bflo(wa.z) + cB*bflo(wb.z);
                acc1[5] += cA*bfhi(wa.z) + cB*bfhi(wb.z);
                acc1[6] += cA*bflo(wa.w) + cB*bflo(wb.w);
                acc1[7] += cA*bfhi(wa.w) + cB*bfhi(wb.w);
            }
        }
        if (j < deg) {
            const uint4* row = (const uint4*)(hbuf + (size_t)ssrc[j]*HSTR);
            float a0 = wexp[j*H + hd0];
            uint4 v = row[q0];
            acc0[0] += a0*bflo(v.x); acc0[1] += a0*bfhi(v.x);
            acc0[2] += a0*bflo(v.y); acc0[3] += a0*bfhi(v.y);
            acc0[4] += a0*bflo(v.z); acc0[5] += a0*bfhi(v.z);
            acc0[6] += a0*bflo(v.w); acc0[7] += a0*bfhi(v.w);
            if (act1) {
                float a1 = wexp[j*H + hd1];
                uint4 w = row[q1];
                acc1[0] += a1*bflo(w.x); acc1[1] += a1*bfhi(w.x);
                acc1[2] += a1*bflo(w.y); acc1[3] += a1*bfhi(w.y);
                acc1[4] += a1*bflo(w.z); acc1[5] += a1*bfhi(w.z);
                acc1[6] += a1*bflo(w.w); acc1[7] += a1*bfhi(w.w);
            }
        }
        {
            short8 pk;
            #pragma unroll
            for (int t = 0; t < 8; t++) {
                float v = acc0[t] + bpad[q0*8 + t];
                v = (v > 0.f) ? v : (__expf(v) - 1.f);
                pk[t] = (short)f2bf(v);
            }
            *((short8*)(out + (size_t)dn*HSTR + q0*8)) = pk;
        }
        if (act1) {
            short8 pk;
            #pragma unroll
            for (int t = 0; t < 8; t++) {
                float v = acc1[t] + bpad[q1*8 + t];
                v = (v > 0.f) ? v : (__expf(v) - 1.f);
                pk[t] = (short)f2bf(v);
            }
            *((short8*)(out + (size_t)dn*HSTR + q1*8)) = pk;
        }
    } else {
        // fallback deg>64: scalar, guaranteed correct
        if (lane < H) {
            float adv = ald[(size_t)dn*H + lane];
            float m = -1e30f;
            for (int j = s; j < e; j++) {
                float al = als[(size_t)csrc[j]*H + lane] + adv;
                al = (al >= 0.f) ? al : 0.2f*al;
                m = fmaxf(m, al);
            }
            float den = 0.f;
            for (int j = s; j < e; j++) {
                float al = als[(size_t)csrc[j]*H + lane] + adv;
                al = (al >= 0.f) ? al : 0.2f*al;
                den += __expf(al - m);
            }
            ms[lane] = m; dinv_s[lane] = 1.f/(den + 1e-16f);
        }
        __syncthreads();
        for (int hh = 0; hh < H; hh++) {
            float m = ms[hh], dinv = dinv_s[hh];
            float adv = ald[(size_t)dn*H + hh];
            for (int cb = 0; cb < F0c; cb += 64) {
                int c = cb + lane;
                if (c < F0c) {
                    float acc = 0.f;
                    for (int j = s; j < e; j++) {
                        int sj = csrc[j];
                        float al = als[(size_t)sj*H + hh] + adv;
                        al = (al >= 0.f) ? al : 0.2f*al;
                        float alpha = __expf(al - m) * dinv;
                        acc += alpha * __uint_as_float(((unsigned)hbuf[(size_t)sj*HSTR + hh*80 + c]) << 16);
                    }
                    float v = acc + bpad[hh*80 + c];
                    v = (v > 0.f) ? v : (__expf(v) - 1.f);
                    out[(size_t)dn*HSTR + hh*80 + c] = f2bf(v);
                }
            }
        }
        if (lane < 20) {
            int hh = lane >> 1, cc = 78 + (lane & 1);
            out[(size_t)dn*HSTR + hh*80 + cc] = 0;
        }
    }
}

// ---------------- GAT layer-2 aggregation (H=1, C=128 f32) ----------------
__global__ void k_agg2(const float* __restrict__ h2, const float* __restrict__ als,
                       const float* __restrict__ ald, const int* __restrict__ offs,
                       const int* __restrict__ csrc, const float* __restrict__ b2,
                       float* __restrict__ out) {
    int dn = blockIdx.x, lane = threadIdx.x;   // 64
    int s = offs[dn], e = offs[dn+1], deg = e - s;
    __shared__ float wexp[128];
    __shared__ int ssrc[128];

    if (deg <= 128) {
        float adv = ald[dn];
        for (int j = lane; j < deg; j += 64) {
            int sj = csrc[s + j];
            ssrc[j] = sj;
            float al = als[sj] + adv;
            wexp[j] = (al >= 0.f) ? al : 0.2f*al;
        }
        __syncthreads();
        float m = -1e30f;
        for (int j = lane; j < deg; j += 64) m = fmaxf(m, wexp[j]);
        #pragma unroll
        for (int d = 32; d > 0; d >>= 1) m = fmaxf(m, __shfl_xor(m, d, 64));
        __syncthreads();
        float den = 0.f;
        for (int j = lane; j < deg; j += 64) {
            float ex = __expf(wexp[j] - m);
            wexp[j] = ex;
            den += ex;
        }
        #pragma unroll
        for (int d = 32; d > 0; d >>= 1) den += __shfl_xor(den, d, 64);
        float dinv = 1.f/(den + 1e-16f);
        __syncthreads();
        float2 acc = {0.f, 0.f};
        for (int j = 0; j < deg; j++) {
            float alpha = wexp[j] * dinv;
            float2 v = ((const float2*)(h2 + (size_t)ssrc[j]*C2c))[lane];
            acc.x += alpha*v.x; acc.y += alpha*v.y;
        }
        float2 o;
        o.x = fmaxf(acc.x + b2[2*lane], 0.f);
        o.y = fmaxf(acc.y + b2[2*lane+1], 0.f);
        ((float2*)(out + (size_t)dn*C2c))[lane] = o;
    } else {
        __shared__ float sm[2];
        if (lane == 0) {
            float adv = ald[dn];
            float m = -1e30f;
            for (int j = s; j < e; j++) {
                float al = als[csrc[j]] + adv;
                al = (al >= 0.f) ? al : 0.2f*al;
                m = fmaxf(m, al);
            }
            float den = 0.f;
            for (int j = s; j < e; j++) {
                float al = als[csrc[j]] + adv;
                al = (al >= 0.f) ? al : 0.2f*al;
                den += __expf(al - m);
            }
            sm[0] = m; sm[1] = 1.f/(den + 1e-16f);
        }
        __syncthreads();
        float m = sm[0], dinv = sm[1], adv = ald[dn];
        float2 acc = {0.f, 0.f};
        for (int j = s; j < e; j++) {
            int sj = csrc[j];
            float al = als[sj] + adv;
            al = (al >= 0.f) ? al : 0.2f*al;
            float alpha = __expf(al - m) * dinv;
            float2 v = ((const float2*)(h2 + (size_t)sj*C2c))[lane];
            acc.x += alpha*v.x; acc.y += alpha*v.y;
        }
        float2 o;
        o.x = fmaxf(acc.x + b2[2*lane], 0.f);
        o.y = fmaxf(acc.y + b2[2*lane+1], 0.f);
        ((float2*)(out + (size_t)dn*C2c))[lane] = o;
    }
}

// ---------------- pool + fc_g1 merged (g stays in LDS) ----------------
__global__ void k_poolfcg(const float* __restrict__ hf, const int* __restrict__ batch,
                          const float* __restrict__ W, const float* __restrict__ bias,
                          float* __restrict__ xc) {
    int b = blockIdx.x, tid = threadIdx.x;    // 128
    __shared__ int se[2];
    __shared__ float gs[C2c];
    if (tid < 2) {
        int key = b + tid;
        int lo = 0, hi = N_NODES;
        while (lo < hi) { int mid = (lo+hi) >> 1; if (batch[mid] < key) lo = mid+1; else hi = mid; }
        se[tid] = lo;
    }
    __syncthreads();
    int s = se[0], e = se[1];
    float m = -1e30f;
    for (int n = s; n < e; n++) m = fmaxf(m, hf[(size_t)n*C2c + tid]);
    gs[tid] = m;
    __syncthreads();
    float acc = bias[tid];
    for (int k = 0; k < C2c; k++) acc += gs[k] * W[k*C2c + tid];
    xc[b*256 + tid] = fmaxf(acc, 0.f);
}

// ---------------- conv path ----------------
// deterministic O(SEQ) counting sort: thread-private LDS columns, no atomics.
__global__ void k_bucket(const int* __restrict__ target, int* __restrict__ ordered,
                         int* __restrict__ boff) {
    int b = blockIdx.x, tid = threadIdx.x;    // 256
    __shared__ unsigned char tg[SEQc];
    __shared__ u16 cnt[VOCABc][256];          // 13.3 KB, [v][chunk]
    __shared__ int offs_s[VOCABc+1];
    __shared__ int tot[VOCABc];
    for (int i = tid; i < VOCABc*256; i += 256) ((u16*)cnt)[i] = 0;
    __syncthreads();
    int i0 = tid*4;
    #pragma unroll
    for (int k = 0; k < 4; k++) {
        int i = i0 + k;
        if (i < SEQc) {
            int t = target[(size_t)b*SEQc + i];
            tg[i] = (unsigned char)t;
            cnt[t][tid]++;
        }
    }
    __syncthreads();
    if (tid < VOCABc) {
        int run = 0;
        for (int c = 0; c < 256; c++) {
            int v = cnt[tid][c];
            cnt[tid][c] = (u16)run;
            run += v;
        }
        tot[tid] = run;
    }
    __syncthreads();
    if (tid == 0) {
        offs_s[0] = 0;
        for (int v = 0; v < VOCABc; v++) offs_s[v+1] = offs_s[v] + tot[v];
    }
    __syncthreads();
    if (tid < VOCABc+1) boff[b*(VOCABc+1) + tid] = offs_s[tid];
    #pragma unroll
    for (int k = 0; k < 4; k++) {
        int i = i0 + k;
        if (i < SEQc) {
            int t = tg[i];
            int r = cnt[t][tid]++;
            ordered[(size_t)b*SEQc + offs_s[t] + r] = i;
        }
    }
}
__global__ void k_buildA(const float* __restrict__ convw, const int* __restrict__ ordered,
                         const int* __restrict__ boff, float* __restrict__ Amat) {
    int t = blockIdx.x, b = blockIdx.y;
    int tid = threadIdx.x;                // 256 = 32 o * 8 k
    int o = tid >> 3, k = tid & 7;
    int s = boff[b*(VOCABc+1) + t], e = boff[b*(VOCABc+1) + t + 1];
    const int* ord = ordered + (size_t)b*SEQc;
    float acc = 0.f;
    for (int j = s; j < e; j++) {
        int i = ord[j];
        acc += convw[((size_t)o*SEQc + i)*KWc + k];
    }
    Amat[(((size_t)b*NFc + o)*VOCABc + t)*KWc + k] = acc;
}
// conv -> bf16 [B][3872]; grid (B, 8): 4 channels/block, __launch_bounds__(128,4)
__global__ void __launch_bounds__(128, 4)
k_conv(const float* __restrict__ Amat, const float* __restrict__ emb,
       const float* __restrict__ convb, u16* __restrict__ convout) {
    int b = blockIdx.x, og = blockIdx.y;      // og in 0..7 -> o base og*4
    int tid = threadIdx.x;                    // 128
    __shared__ float embs[VOCABc*EMBc];       // 13.3 KB
    __shared__ float arow[4*VOCABc*KWc];      // 3.3 KB
    for (int i = tid; i < VOCABc*EMBc; i += 128) embs[i] = emb[i];
    for (int i = tid; i < 4*VOCABc*KWc; i += 128)
        arow[i] = Amat[((size_t)b*NFc + og*4)*(VOCABc*KWc) + i];
    __syncthreads();
    if (tid < LOUTc) {
        float a0 = convb[og*4+0], a1 = convb[og*4+1], a2 = convb[og*4+2], a3 = convb[og*4+3];
        for (int t = 0; t < VOCABc; t++) {
            #pragma unroll
            for (int k = 0; k < KWc; k++) {
                float ev = embs[t*EMBc + tid + k];
                a0 += arow[0*(VOCABc*KWc) + t*KWc + k] * ev;
                a1 += arow[1*(VOCABc*KWc) + t*KWc + k] * ev;
                a2 += arow[2*(VOCABc*KWc) + t*KWc + k] * ev;
                a3 += arow[3*(VOCABc*KWc) + t*KWc + k] * ev;
            }
        }
        size_t base = (size_t)b*KXT + (og*4)*LOUTc + tid;
        convout[base            ] = f2bf(fmaxf(a0, 0.f));
        convout[base +   LOUTc  ] = f2bf(fmaxf(a1, 0.f));
        convout[base + 2*LOUTc  ] = f2bf(fmaxf(a2, 0.f));
        convout[base + 3*LOUTc  ] = f2bf(fmaxf(a3, 0.f));
    }
}
// fcxt (MFMA, K-split): partials -> fxp[11][512][128] (plain stores, deterministic)
__global__ void k_fcxt_mfma(const short* __restrict__ cvo, const short* __restrict__ wxt,
                            float* __restrict__ fxp) {
    int wave = threadIdx.x >> 6, lane = threadIdx.x & 63;
    int m16 = lane & 15, quad = lane >> 4;
    int r0 = blockIdx.x*64 + wave*16;      // 512 rows = 8 blocks * 64
    int kt0 = blockIdx.y*11;               // 121 k-steps = 11 chunks * 11
    const short8* arow = (const short8*)(cvo + (size_t)(r0 + m16)*KXT);
    f32x4 acc[8];
    #pragma unroll
    for (int ct = 0; ct < 8; ct++) acc[ct] = (f32x4){0.f,0.f,0.f,0.f};
    for (int kt = kt0; kt < kt0 + 11; kt++) {
        short8 af = arow[kt*4 + quad];
        #pragma unroll
        for (int ct = 0; ct < 8; ct++) {
            const short8* brow = (const short8*)(wxt + (size_t)(ct*16 + m16)*KXT);
            short8 bf = brow[kt*4 + quad];
            acc[ct] = __builtin_amdgcn_mfma_f32_16x16x32_bf16(af, bf, acc[ct], 0, 0, 0);
        }
    }
    #pragma unroll
    for (int ct = 0; ct < 8; ct++) {
        int col = ct*16 + m16;
        #pragma unroll
        for (int r = 0; r < 4; r++) {
            int row = r0 + quad*4 + r;
            fxp[((size_t)blockIdx.y*BGRAPHS + row)*C2c + col] = acc[ct][r];
        }
    }
}

// ---------------- head MLP ----------------
// fc1 absorbs the fcxt partial reduction when loading xs[128:256]
__global__ void k_fc1(const float* __restrict__ xc, const float* __restrict__ fxp,
                      const float* __restrict__ fcxt_b, const float* __restrict__ W,
                      const float* __restrict__ bias, float* __restrict__ y1) {
    int b = blockIdx.x, tid = threadIdx.x;    // 256
    __shared__ float xs[256];
    if (tid < 128) {
        xs[tid] = xc[b*256 + tid];
    } else {
        int col = tid - 128;
        float s = fcxt_b[col];
        #pragma unroll
        for (int q = 0; q < 11; q++) s += fxp[((size_t)q*BGRAPHS + b)*C2c + col];
        xs[tid] = s;
    }
    __syncthreads();
    float a0 = bias[tid], a1 = bias[tid+256], a2 = bias[tid+512], a3 = bias[tid+768];
    for (int k = 0; k < 256; k++) {
        float xk = xs[k];
        const float* wr = W + (size_t)k*1024;
        a0 += xk*wr[tid]; a1 += xk*wr[tid+256]; a2 += xk*wr[tid+512]; a3 += xk*wr[tid+768];
    }
    y1[(size_t)b*1024 + tid      ] = fmaxf(a0, 0.f);
    y1[(size_t)b*1024 + tid + 256] = fmaxf(a1, 0.f);
    y1[(size_t)b*1024 + tid + 512] = fmaxf(a2, 0.f);
    y1[(size_t)b*1024 + tid + 768] = fmaxf(a3, 0.f);
}
// fc2 + out merged: y2 never materialized
__global__ void k_fc2out(const float* __restrict__ y1, const float* __restrict__ W,
                         const float* __restrict__ bias, const float* __restrict__ ow,
                         const float* __restrict__ ob, float* __restrict__ out) {
    int b = blockIdx.x, tid = threadIdx.x;    // 256
    int lane = tid & 63, wid = tid >> 6;
    __shared__ float ys[1024];
    __shared__ float wsum[4];
    for (int i = tid; i < 1024; i += 256) ys[i] = y1[(size_t)b*1024 + i];
    __syncthreads();
    float acc = bias[tid];
    for (int k = 0; k < 1024; k++) acc += ys[k] * W[(size_t)k*256 + tid];
    float v = fmaxf(acc, 0.f) * ow[tid];
    #pragma unroll
    for (int d = 32; d > 0; d >>= 1) v += __shfl_xor(v, d, 64);
    if (lane == 0) wsum[wid] = v;
    __syncthreads();
    if (tid == 0) out[b] = wsum[0] + wsum[1] + wsum[2] + wsum[3] + ob[0];
}

extern "C" void kernel_launch(void* const* d_in, const int* in_sizes, int n_in,
                              void* d_out, int out_size, void* d_ws, size_t ws_size,
                              hipStream_t stream) {
    (void)in_sizes; (void)n_in; (void)out_size;
    if (ws_size < A_END) return;   // guard: clean numeric-fail if ws too small

    const float* x       = (const float*)d_in[0];
    const int*   ei      = (const int*)  d_in[1];
    const int*   batch   = (const int*)  d_in[2];
    const int*   target  = (const int*)  d_in[3];
    const float* W1      = (const float*)d_in[4];
    const float* a_src1  = (const float*)d_in[5];
    const float* a_dst1  = (const float*)d_in[6];
    const float* b1      = (const float*)d_in[7];
    const float* W2      = (const float*)d_in[8];
    const float* a_src2  = (const float*)d_in[9];
    const float* a_dst2  = (const float*)d_in[10];
    const float* b2      = (const float*)d_in[11];
    const float* fcg_w   = (const float*)d_in[12];
    const float* fcg_b   = (const float*)d_in[13];
    const float* emb     = (const float*)d_in[14];
    const float* conv_w  = (const float*)d_in[15];
    const float* conv_b  = (const float*)d_in[16];
    const float* fcxt_w  = (const float*)d_in[17];
    const float* fcxt_b  = (const float*)d_in[18];
    const float* fc1_w   = (const float*)d_in[19];
    const float* fc1_b   = (const float*)d_in[20];
    const float* fc2_w   = (const float*)d_in[21];
    const float* fc2_b   = (const float*)d_in[22];
    const float* out_w   = (const float*)d_in[23];
    const float* out_b   = (const float*)d_in[24];

    char* wsb = (char*)d_ws;
    u16*   hbuf  = (u16*)  (wsb + A_HBUF);
    u16*   out1  = (u16*)  (wsb + A_OUT1);
    float* h2    = (float*)(wsb + A_H2);
    __hip_bfloat16* w2t = (__hip_bfloat16*)(wsb + A_W2T);
    float* als1  = (float*)(wsb + A_ALS1);
    float* ald1  = (float*)(wsb + A_ALD1);
    float* als2  = (float*)(wsb + A_ALS2);
    float* ald2  = (float*)(wsb + A_ALD2);
    int*   deg   = (int*)  (wsb + A_DEG);
    int*   offs  = (int*)  (wsb + A_OFFS);
    int*   cur   = (int*)  (wsb + A_CUR);
    int*   csrc  = (int*)  (wsb + A_CSRC);
    float* xc    = (float*)(wsb + A_XC);
    float* y1    = (float*)(wsb + A_Y1);
    int*   boff  = (int*)  (wsb + A_BOFF);
    float* bpad  = (float*)(wsb + A_BPAD);
    __hip_bfloat16* wxt = (__hip_bfloat16*)(wsb + A_WXT);
    float* fxp   = (float*)(wsb + A_FXP);
    // aliases:
    float* hfin  = (float*)(wsb + A_HFIN);
    int*   ord   = (int*)  (wsb + A_ORD);
    float* Amat  = (float*)(wsb + A_AMAT);
    u16*   cvo   = (u16*)  (wsb + A_CVO);
    __hip_bfloat16* xpad = (__hip_bfloat16*)(wsb + A_XPAD);
    __hip_bfloat16* w1t  = (__hip_bfloat16*)(wsb + A_W1T);

    // prep: deg init + conversions + padded bias
    k_prep<<<(PREP_TOTAL+255)/256, 256, 0, stream>>>(x, W1, W2, b1, fcxt_w,
                                                     xpad, w1t, w2t, bpad, wxt, deg);
    // CSR build (+ deterministic segment sort)
    k_count  <<<(N_EDGES+255)/256, 256, 0, stream>>>(ei, deg);
    k_scan   <<<1, 1024, 0, stream>>>(deg, offs, cur, N_NODES);
    k_fill   <<<(N_EDGES+N_NODES+255)/256, 256, 0, stream>>>(ei, cur, csrc);
    k_sortcsr<<<(N_NODES+255)/256, 256, 0, stream>>>(offs, csrc);

    // GAT layer 1
    k_gemm1_mfma<<<dim3((N_NODES+63)/64, 7), 256, 0, stream>>>((const short*)xpad, (const short*)w1t, hbuf);
    k_att1<<<(N_NODES*H1c+255)/256, 256, 0, stream>>>(hbuf, a_src1, a_dst1, als1, ald1);
    k_agg1<<<N_NODES, 64, 0, stream>>>(hbuf, als1, ald1, offs, csrc, bpad, out1);
    // ---- hbuf dead; xpad/w1t dead (out1 region now live) ----

    // GAT layer 2 (gemm2 also emits als2/ald2)
    k_gemm2_mfma<<<(N_NODES+63)/64, 256, 0, stream>>>((const short*)out1, (const short*)w2t,
                                                      a_src2, a_dst2, h2, als2, ald2);
    k_agg2<<<N_NODES, 64, 0, stream>>>(h2, als2, ald2, offs, csrc, b2, hfin);

    // pool + fc_g1 -> xc[:, 0:128]
    k_poolfcg<<<BGRAPHS, 128, 0, stream>>>(hfin, batch, fcg_w, fcg_b, xc);

    // conv path -> fxp partials
    k_bucket<<<BGRAPHS, 256, 0, stream>>>(target, ord, boff);
    k_buildA<<<dim3(VOCABc, BGRAPHS), 256, 0, stream>>>(conv_w, ord, boff, Amat);
    k_conv  <<<dim3(BGRAPHS, 8), 128, 0, stream>>>(Amat, emb, conv_b, cvo);
    k_fcxt_mfma<<<dim3(BGRAPHS/64, 11), 256, 0, stream>>>((const short*)cvo, (const short*)wxt, fxp);

    // head MLP (fc1 reduces fxp inline; fc2 folds the output dot)
    k_fc1<<<BGRAPHS, 256, 0, stream>>>(xc, fxp, fcxt_b, fc1_w, fc1_b, y1);
    k_fc2out<<<BGRAPHS, 256, 0, stream>>>(y1, fc2_w, fc2_b, out_w, out_b, (float*)d_out);
}

// Round 14
// 649.786 us; speedup vs baseline: 1.6463x; 1.0381x over previous
//
#include <hip/hip_runtime.h>
#include <hip/hip_bf16.h>

// Problem constants (from reference)
#define N_NODES 50000
#define N_EDGES 200000
#define BGRAPHS 512
#define F0c 78
#define H1c 10
#define HC1 780     // H1*F0 (logical)
#define HSTR 800    // padded row stride: 10 head blocks of 80 (78 data + 2 pad)
#define C2c 128
#define SEQc 1000
#define VOCABc 26
#define NFc 32
#define KWc 8
#define LOUTc 121
#define EMBc 128
#define KX 96       // padded cols for xpad (78 -> 96)
#define KXT 3872    // NF*LOUT = 32*121 -> 121 MFMA k-steps, split 11 x 11

typedef __attribute__((ext_vector_type(8))) short short8;
typedef __attribute__((ext_vector_type(4))) float f32x4;
typedef unsigned short u16;

static constexpr size_t alignup(size_t x) { return (x + 255) & ~size_t(255); }

// -------- workspace layout (bytes) --------
// A_HBUF region now holds xagg bf16 [N][10][80] = 80,000,000 B (same size as old hbuf).
static constexpr size_t A_HBUF = 0;
static constexpr size_t A_OUT1 = alignup(A_HBUF + size_t(N_NODES)*HSTR*2);   // bf16 [N,800] = 80 MB
static constexpr size_t A_H2   = alignup(A_OUT1 + size_t(N_NODES)*HSTR*2);   // f32  [N,128]
static constexpr size_t A_W2T  = alignup(A_H2   + size_t(N_NODES)*C2c*4);    // bf16 [128,800] padded-80 layout
static constexpr size_t A_ALS1 = alignup(A_W2T  + size_t(C2c)*HSTR*2);
static constexpr size_t A_ALD1 = alignup(A_ALS1 + size_t(N_NODES)*H1c*4);
static constexpr size_t A_ALS2 = alignup(A_ALD1 + size_t(N_NODES)*H1c*4);
static constexpr size_t A_ALD2 = alignup(A_ALS2 + size_t(N_NODES)*4);
static constexpr size_t A_DEG  = alignup(A_ALD2 + size_t(N_NODES)*4);
static constexpr size_t A_OFFS = alignup(A_DEG  + size_t(N_NODES)*4);
static constexpr size_t A_CUR  = alignup(A_OFFS + size_t(N_NODES+1)*4);
static constexpr size_t A_CSRC = alignup(A_CUR  + size_t(N_NODES)*4);
static constexpr size_t A_XC   = alignup(A_CSRC + size_t(N_EDGES+N_NODES)*4);
static constexpr size_t A_Y1   = alignup(A_XC   + size_t(BGRAPHS)*256*4);
static constexpr size_t A_BOFF = alignup(A_Y1   + size_t(BGRAPHS)*1024*4);
static constexpr size_t A_BPAD = alignup(A_BOFF + size_t(BGRAPHS)*(VOCABc+1)*4);
static constexpr size_t A_WXT  = alignup(A_BPAD + size_t(HSTR)*4);           // bf16 [128][3872]
static constexpr size_t A_FXP  = alignup(A_WXT  + size_t(C2c)*KXT*2);        // f32 [11][512][128]
static constexpr size_t A_W1HP = alignup(A_FXP  + size_t(11)*BGRAPHS*C2c*4); // bf16 [10][80][96]
static constexpr size_t A_WSD  = alignup(A_W1HP + size_t(10)*80*96*2);       // f32 [2][10][78]
static constexpr size_t A_END  = alignup(A_WSD  + size_t(2)*H1c*F0c*4);

// aliases inside xagg region (valid after k_gemm1h retires; xagg dead then):
static constexpr size_t A_HFIN = A_HBUF;                                        // f32 [N,128]
static constexpr size_t A_ORD  = alignup(A_HFIN + size_t(N_NODES)*C2c*4);
static constexpr size_t A_AMAT = alignup(A_ORD  + size_t(BGRAPHS)*SEQc*4);
static constexpr size_t A_CVO  = alignup(A_AMAT + size_t(BGRAPHS)*NFc*VOCABc*KWc*4);  // bf16 [512][3872]
static_assert(A_CVO + size_t(BGRAPHS)*KXT*2 <= size_t(N_NODES)*HSTR*2, "alias A overflow");
// alias inside out1 region (xpad dead before gemm1h writes out1):
static constexpr size_t A_XPAD = A_OUT1;                                        // bf16 [N,96]
static_assert(size_t(N_NODES)*KX*2 <= size_t(N_NODES)*HSTR*2, "alias B overflow");

// -------- helpers --------
__device__ __forceinline__ float bflo(unsigned u) { return __uint_as_float(u << 16); }
__device__ __forceinline__ float bfhi(unsigned u) { return __uint_as_float(u & 0xffff0000u); }
__device__ __forceinline__ u16 f2bf(float v) {
    __hip_bfloat16 b = __float2bfloat16(v);
    return *(u16*)&b;
}

// ---------------- prep: deg init + conversions + folded attention vectors ----------------
__global__ void k_prep(const float* __restrict__ x, const float* __restrict__ W1,
                       const float* __restrict__ W2, const float* __restrict__ b1,
                       const float* __restrict__ fcxt_w,
                       const float* __restrict__ a_src1, const float* __restrict__ a_dst1,
                       __hip_bfloat16* __restrict__ xpad, __hip_bfloat16* __restrict__ w1hp,
                       __hip_bfloat16* __restrict__ w2t, float* __restrict__ bpad,
                       __hip_bfloat16* __restrict__ wxt, float* __restrict__ wsd,
                       int* __restrict__ deg) {
    int i = blockIdx.x*256 + threadIdx.x;
    const int R0 = N_NODES;
    const int R1 = R0 + N_NODES*KX;
    const int R2 = R1 + 10*80*96;
    const int R3 = R2 + C2c*HSTR;
    const int R4 = R3 + HSTR;
    const int R5 = R4 + C2c*KXT;
    const int R6 = R5 + 2*H1c*F0c;
    if (i < R0) {
        deg[i] = 1;   // self loop
    } else if (i < R1) {
        int t = i - R0; int n = t / KX, c = t - n*KX;
        xpad[t] = __float2bfloat16(c < F0c ? x[(size_t)n*F0c + c] : 0.f);
    } else if (i < R2) {
        int t = i - R1; int hh = t / 7680, rem = t - hh*7680;
        int j = rem / 96, k = rem - j*96;
        w1hp[t] = __float2bfloat16((j < F0c && k < F0c) ? W1[(size_t)k*HC1 + hh*F0c + j] : 0.f);
    } else if (i < R3) {
        int t = i - R2; int c = t / HSTR, p = t - c*HSTR;
        int hh = p / 80, cc = p - hh*80;
        w2t[t] = __float2bfloat16(cc < F0c ? W2[(size_t)(hh*F0c + cc)*C2c + c] : 0.f);
    } else if (i < R4) {
        int p = i - R3; int hh = p / 80, cc = p - hh*80;
        bpad[p] = (cc < F0c) ? b1[hh*F0c + cc] : 0.f;
    } else if (i < R5) {
        int t = i - R4; int c = t / KXT, j = t - c*KXT;
        wxt[t] = __float2bfloat16(fcxt_w[(size_t)j*C2c + c]);
    } else if (i < R6) {
        int t = i - R5; int sd = t / (H1c*F0c), rem = t - sd*(H1c*F0c);
        int hh = rem / F0c, c = rem - hh*F0c;
        const float* a = sd ? a_dst1 : a_src1;
        float v = 0.f;
        for (int j = 0; j < F0c; j++) v += W1[(size_t)c*HC1 + hh*F0c + j] * a[hh*F0c + j];
        wsd[t] = v;
    }
}
#define PREP_TOTAL (N_NODES + N_NODES*KX + 10*80*96 + C2c*HSTR + HSTR + C2c*KXT + 2*H1c*F0c)

// ---------------- CSR build ----------------
__global__ void k_count(const int* __restrict__ ei, int* deg) {
    int i = blockIdx.x*256 + threadIdx.x;
    if (i < N_EDGES) atomicAdd(&deg[ei[N_EDGES + i]], 1);
}
__global__ void k_scan(const int* __restrict__ deg, int* __restrict__ off,
                       int* __restrict__ cur, int n) {
    __shared__ int wsum[16];
    __shared__ int s_carry;
    int tid = threadIdx.x, lane = tid & 63, wid = tid >> 6;
    if (tid == 0) s_carry = 0;
    __syncthreads();
    for (int base = 0; base < n; base += 1024) {
        int i = base + tid;
        int v0 = (i < n) ? deg[i] : 0;
        int v = v0;
        for (int d = 1; d < 64; d <<= 1) { int t = __shfl_up(v, d, 64); if (lane >= d) v += t; }
        if (lane == 63) wsum[wid] = v;
        __syncthreads();
        if (wid == 0) {
            int w = (lane < 16) ? wsum[lane] : 0;
            for (int d = 1; d < 16; d <<= 1) { int t = __shfl_up(w, d, 64); if (lane >= d) w += t; }
            if (lane < 16) wsum[lane] = w;
        }
        __syncthreads();
        int wprev = (wid > 0) ? wsum[wid-1] : 0;
        int carry = s_carry;
        if (i < n) { int o = carry + wprev + (v - v0); off[i] = o; cur[i] = o; }
        __syncthreads();
        if (tid == 0) s_carry = carry + wsum[15];
        __syncthreads();
    }
    if (tid == 0) off[n] = s_carry;
}
__global__ void k_fill(const int* __restrict__ ei, int* cur, int* __restrict__ csrc) {
    int i = blockIdx.x*256 + threadIdx.x;
    if (i < N_EDGES) {
        int s = ei[i], d = ei[N_EDGES + i];
        int p = atomicAdd(&cur[d], 1);
        csrc[p] = s;
    } else if (i < N_EDGES + N_NODES) {
        int n = i - N_EDGES;
        int p = atomicAdd(&cur[n], 1);
        csrc[p] = n;
    }
}
// determinize: sort each CSR segment (atomic fill order varies run-to-run)
__global__ void k_sortcsr(const int* __restrict__ offs, int* __restrict__ csrc) {
    int n = blockIdx.x*256 + threadIdx.x;
    if (n >= N_NODES) return;
    int s = offs[n], e = offs[n+1];
    for (int i = s + 1; i < e; i++) {
        int v = csrc[i];
        int j = i - 1;
        while (j >= s && csrc[j] > v) { csrc[j+1] = csrc[j]; j--; }
        csrc[j+1] = v;
    }
}

// ---------------- layer-1 attention logits, direct from x: als = x @ (W1_h a_h) ----------------
__global__ void k_att1x(const float* __restrict__ x, const float* __restrict__ wsd,
                        float* __restrict__ als, float* __restrict__ ald) {
    int i = blockIdx.x*256 + threadIdx.x;
    if (i >= N_NODES*H1c) return;
    int n = i / H1c, hh = i - n*H1c;
    const float* xr = x + (size_t)n*F0c;
    const float* ws = wsd + hh*F0c;
    const float* wd = wsd + H1c*F0c + hh*F0c;
    float s1 = 0.f, s2 = 0.f;
    for (int c = 0; c < F0c; c++) { float v = xr[c]; s1 += v*ws[c]; s2 += v*wd[c]; }
    als[i] = s1; ald[i] = s2;
}

// ---------------- layer-1 aggregation in x-space: xagg[n,hh,80] = sum alpha * x[src] ----------------
// gather source xpad is 9.6 MB (L2/L3-resident). One wave per dst node.
__global__ void k_agg1x(const unsigned* __restrict__ xpu, const float* __restrict__ als,
                        const float* __restrict__ ald, const int* __restrict__ offs,
                        const int* __restrict__ csrc, unsigned* __restrict__ xaggu) {
    constexpr int H = H1c;
    int dn = blockIdx.x, lane = threadIdx.x;   // 64
    int s = offs[dn], e = offs[dn+1], deg = e - s;
    __shared__ float wexp[64*H];               // 2560 B
    __shared__ int   ssrc[64];
    __shared__ float ms[H], dinv_s[H];

    if (deg <= 64) {
        if (lane < deg) ssrc[lane] = csrc[s + lane];
        __syncthreads();
        for (int idx = lane; idx < deg*H; idx += 64) {
            int j = idx / H, hh = idx - j*H;
            float al = als[(size_t)ssrc[j]*H + hh] + ald[(size_t)dn*H + hh];
            wexp[idx] = (al >= 0.f) ? al : 0.2f*al;
        }
        __syncthreads();
        if (lane < H) {
            float m = -1e30f;
            for (int j = 0; j < deg; j++) m = fmaxf(m, wexp[j*H + lane]);
            float den = 0.f;
            for (int j = 0; j < deg; j++) den += __expf(wexp[j*H + lane] - m);
            ms[lane] = m; dinv_s[lane] = 1.f/(den + 1e-16f);
        }
        __syncthreads();
        for (int idx = lane; idx < deg*H; idx += 64) {
            int hh = idx % H;
            wexp[idx] = __expf(wexp[idx] - ms[hh]) * dinv_s[hh];
        }
        __syncthreads();
        if (lane < 40) {                       // uint c covers x cols 2c,2c+1 (cols 0..79)
            float accL[H], accH[H];
            #pragma unroll
            for (int hh = 0; hh < H; hh++) { accL[hh] = 0.f; accH[hh] = 0.f; }
            int j = 0;
            for (; j + 1 < deg; j += 2) {
                unsigned ua = xpu[(size_t)ssrc[j]*48 + lane];
                unsigned ub = xpu[(size_t)ssrc[j+1]*48 + lane];
                float a0 = bflo(ua), a1 = bfhi(ua), b0 = bflo(ub), b1 = bfhi(ub);
                #pragma unroll
                for (int hh = 0; hh < H; hh++) {
                    float wA = wexp[j*H + hh], wB = wexp[(j+1)*H + hh];
                    accL[hh] += wA*a0 + wB*b0;
                    accH[hh] += wA*a1 + wB*b1;
                }
            }
            if (j < deg) {
                unsigned ua = xpu[(size_t)ssrc[j]*48 + lane];
                float a0 = bflo(ua), a1 = bfhi(ua);
                #pragma unroll
                for (int hh = 0; hh < H; hh++) {
                    float wA = wexp[j*H + hh];
                    accL[hh] += wA*a0;
                    accH[hh] += wA*a1;
                }
            }
            #pragma unroll
            for (int hh = 0; hh < H; hh++) {
                unsigned p = (unsigned)f2bf(accL[hh]) | ((unsigned)f2bf(accH[hh]) << 16);
                xaggu[((size_t)dn*H + hh)*40 + lane] = p;
            }
        }
    } else {
        // fallback deg>64 (practically never): recompute alpha inline, guaranteed correct
        if (lane < H) {
            float adv = ald[(size_t)dn*H + lane];
            float m = -1e30f;
            for (int j = s; j < e; j++) {
                float al = als[(size_t)csrc[j]*H + lane] + adv;
                al = (al >= 0.f) ? al : 0.2f*al;
                m = fmaxf(m, al);
            }
            float den = 0.f;
            for (int j = s; j < e; j++) {
                float al = als[(size_t)csrc[j]*H + lane] + adv;
                al = (al >= 0.f) ? al : 0.2f*al;
                den += __expf(al - m);
            }
            ms[lane] = m; dinv_s[lane] = 1.f/(den + 1e-16f);
        }
        __syncthreads();
        if (lane < 40) {
            float accL[H], accH[H];
            #pragma unroll
            for (int hh = 0; hh < H; hh++) { accL[hh] = 0.f; accH[hh] = 0.f; }
            for (int j = s; j < e; j++) {
                int sj = csrc[j];
                unsigned ua = xpu[(size_t)sj*48 + lane];
                float a0 = bflo(ua), a1 = bfhi(ua);
                #pragma unroll
                for (int hh = 0; hh < H; hh++) {
                    float al = als[(size_t)sj*H + hh] + ald[(size_t)dn*H + hh];
                    al = (al >= 0.f) ? al : 0.2f*al;
                    float a = __expf(al - ms[hh]) * dinv_s[hh];
                    accL[hh] += a*a0;
                    accH[hh] += a*a1;
                }
            }
            #pragma unroll
            for (int hh = 0; hh < H; hh++) {
                unsigned p = (unsigned)f2bf(accL[hh]) | ((unsigned)f2bf(accH[hh]) << 16);
                xaggu[((size_t)dn*H + hh)*40 + lane] = p;
            }
        }
    }
}

// ---------------- per-head GEMM: xagg[n,hh,80] @ W1_hh[80x80] -> out1 (elu+bias fused) ----------------
// K handled as 3x32 MFMA steps; A overreads k>=80 into next row but B rows are zero there.
__global__ void k_gemm1h(const short* __restrict__ xagg, const short* __restrict__ w1hp,
                         const float* __restrict__ bpad, u16* __restrict__ out1) {
    int wave = threadIdx.x >> 6, lane = threadIdx.x & 63;
    int m16 = lane & 15, quad = lane >> 4;
    int hh = blockIdx.y;
    int r0 = blockIdx.x*64 + wave*16;
    int rowc = min(r0 + m16, N_NODES-1);
    const short8* arow = (const short8*)(xagg + ((size_t)rowc*H1c + hh)*80);
    f32x4 acc[5];
    #pragma unroll
    for (int ct = 0; ct < 5; ct++) acc[ct] = (f32x4){0.f,0.f,0.f,0.f};
    #pragma unroll
    for (int kt = 0; kt < 3; kt++) {
        short8 af = arow[kt*4 + quad];    // kt=2,quad>=2 overreads: B zeros neutralize
        #pragma unroll
        for (int ct = 0; ct < 5; ct++) {
            const short8* brow = (const short8*)(w1hp + (size_t)(hh*80 + ct*16 + m16)*96);
            short8 bf = brow[kt*4 + quad];
            acc[ct] = __builtin_amdgcn_mfma_f32_16x16x32_bf16(af, bf, acc[ct], 0, 0, 0);
        }
    }
    #pragma unroll
    for (int ct = 0; ct < 5; ct++) {
        int col = ct*16 + m16;
        float bv = bpad[hh*80 + col];
        #pragma unroll
        for (int r = 0; r < 4; r++) {
            int orow = r0 + quad*4 + r;
            if (orow < N_NODES) {
                float v = acc[ct][r] + bv;
                v = (v > 0.f) ? v : (__expf(v) - 1.f);
                out1[(size_t)orow*HSTR + hh*80 + col] = f2bf(v);
            }
        }
    }
}

// ---------------- GEMM2 (MFMA) + att2 fold: out1 @ W2t^T -> h2, als2, ald2 ----------------
__global__ void k_gemm2_mfma(const short* __restrict__ A, const short* __restrict__ Bt,
                             const float* __restrict__ a_src2, const float* __restrict__ a_dst2,
                             float* __restrict__ Cout, float* __restrict__ als2,
                             float* __restrict__ ald2) {
    int wave = threadIdx.x >> 6, lane = threadIdx.x & 63;
    int m16 = lane & 15, quad = lane >> 4;
    int r0 = blockIdx.x*64 + wave*16;
    int rowc = min(r0 + m16, N_NODES-1);
    const short8* arow = (const short8*)(A + (size_t)rowc*HSTR);
    f32x4 acc[8];
    #pragma unroll
    for (int ct = 0; ct < 8; ct++) acc[ct] = (f32x4){0.f,0.f,0.f,0.f};
    for (int kt = 0; kt < 25; kt++) {
        short8 af = arow[kt*4 + quad];
        #pragma unroll
        for (int ct = 0; ct < 8; ct++) {
            const short8* brow = (const short8*)(Bt + (size_t)(ct*16 + m16)*HSTR);
            short8 bf = brow[kt*4 + quad];
            acc[ct] = __builtin_amdgcn_mfma_f32_16x16x32_bf16(af, bf, acc[ct], 0, 0, 0);
        }
    }
    #pragma unroll
    for (int ct = 0; ct < 8; ct++) {
        #pragma unroll
        for (int r = 0; r < 4; r++) {
            int orow = r0 + quad*4 + r;
            if (orow < N_NODES) Cout[(size_t)orow*C2c + ct*16 + m16] = acc[ct][r];
        }
    }
    float asv[8], adv[8];
    #pragma unroll
    for (int ct = 0; ct < 8; ct++) { asv[ct] = a_src2[ct*16 + m16]; adv[ct] = a_dst2[ct*16 + m16]; }
    #pragma unroll
    for (int r = 0; r < 4; r++) {
        float s1 = 0.f, s2 = 0.f;
        #pragma unroll
        for (int ct = 0; ct < 8; ct++) { s1 += acc[ct][r]*asv[ct]; s2 += acc[ct][r]*adv[ct]; }
        #pragma unroll
        for (int d = 1; d < 16; d <<= 1) { s1 += __shfl_xor(s1, d, 64); s2 += __shfl_xor(s2, d, 64); }
        int orow = r0 + quad*4 + r;
        if (m16 == 0 && orow < N_NODES) { als2[orow] = s1; ald2[orow] = s2; }
    }
}

// ---------------- GAT layer-2 aggregation (H=1, C=128 f32) ----------------
__global__ void k_agg2(const float* __restrict__ h2, const float* __restrict__ als,
                       const float* __restrict__ ald, const int* __restrict__ offs,
                       const int* __restrict__ csrc, const float* __restrict__ b2,
                       float* __restrict__ out) {
    int dn = blockIdx.x, lane = threadIdx.x;   // 64
    int s = offs[dn], e = offs[dn+1], deg = e - s;
    __shared__ float wexp[128];
    __shared__ int ssrc[128];

    if (deg <= 128) {
        float adv = ald[dn];
        for (int j = lane; j < deg; j += 64) {
            int sj = csrc[s + j];
            ssrc[j] = sj;
            float al = als[sj] + adv;
            wexp[j] = (al >= 0.f) ? al : 0.2f*al;
        }
        __syncthreads();
        float m = -1e30f;
        for (int j = lane; j < deg; j += 64) m = fmaxf(m, wexp[j]);
        #pragma unroll
        for (int d = 32; d > 0; d >>= 1) m = fmaxf(m, __shfl_xor(m, d, 64));
        __syncthreads();
        float den = 0.f;
        for (int j = lane; j < deg; j += 64) {
            float ex = __expf(wexp[j] - m);
            wexp[j] = ex;
            den += ex;
        }
        #pragma unroll
        for (int d = 32; d > 0; d >>= 1) den += __shfl_xor(den, d, 64);
        float dinv = 1.f/(den + 1e-16f);
        __syncthreads();
        float2 acc = {0.f, 0.f};
        for (int j = 0; j < deg; j++) {
            float alpha = wexp[j] * dinv;
            float2 v = ((const float2*)(h2 + (size_t)ssrc[j]*C2c))[lane];
            acc.x += alpha*v.x; acc.y += alpha*v.y;
        }
        float2 o;
        o.x = fmaxf(acc.x + b2[2*lane], 0.f);
        o.y = fmaxf(acc.y + b2[2*lane+1], 0.f);
        ((float2*)(out + (size_t)dn*C2c))[lane] = o;
    } else {
        __shared__ float sm[2];
        if (lane == 0) {
            float adv = ald[dn];
            float m = -1e30f;
            for (int j = s; j < e; j++) {
                float al = als[csrc[j]] + adv;
                al = (al >= 0.f) ? al : 0.2f*al;
                m = fmaxf(m, al);
            }
            float den = 0.f;
            for (int j = s; j < e; j++) {
                float al = als[csrc[j]] + adv;
                al = (al >= 0.f) ? al : 0.2f*al;
                den += __expf(al - m);
            }
            sm[0] = m; sm[1] = 1.f/(den + 1e-16f);
        }
        __syncthreads();
        float m = sm[0], dinv = sm[1], adv = ald[dn];
        float2 acc = {0.f, 0.f};
        for (int j = s; j < e; j++) {
            int sj = csrc[j];
            float al = als[sj] + adv;
            al = (al >= 0.f) ? al : 0.2f*al;
            float alpha = __expf(al - m) * dinv;
            float2 v = ((const float2*)(h2 + (size_t)sj*C2c))[lane];
            acc.x += alpha*v.x; acc.y += alpha*v.y;
        }
        float2 o;
        o.x = fmaxf(acc.x + b2[2*lane], 0.f);
        o.y = fmaxf(acc.y + b2[2*lane+1], 0.f);
        ((float2*)(out + (size_t)dn*C2c))[lane] = o;
    }
}

// ---------------- pool + fc_g1 merged (g stays in LDS) ----------------
__global__ void k_poolfcg(const float* __restrict__ hf, const int* __restrict__ batch,
                          const float* __restrict__ W, const float* __restrict__ bias,
                          float* __restrict__ xc) {
    int b = blockIdx.x, tid = threadIdx.x;    // 128
    __shared__ int se[2];
    __shared__ float gs[C2c];
    if (tid < 2) {
        int key = b + tid;
        int lo = 0, hi = N_NODES;
        while (lo < hi) { int mid = (lo+hi) >> 1; if (batch[mid] < key) lo = mid+1; else hi = mid; }
        se[tid] = lo;
    }
    __syncthreads();
    int s = se[0], e = se[1];
    float m = -1e30f;
    for (int n = s; n < e; n++) m = fmaxf(m, hf[(size_t)n*C2c + tid]);
    gs[tid] = m;
    __syncthreads();
    float acc = bias[tid];
    for (int k = 0; k < C2c; k++) acc += gs[k] * W[k*C2c + tid];
    xc[b*256 + tid] = fmaxf(acc, 0.f);
}

// ---------------- conv path ----------------
__global__ void k_bucket(const int* __restrict__ target, int* __restrict__ ordered,
                         int* __restrict__ boff) {
    int b = blockIdx.x, tid = threadIdx.x;    // 256
    __shared__ unsigned char tg[SEQc];
    __shared__ u16 cnt[VOCABc][256];          // 13.3 KB, [v][chunk]
    __shared__ int offs_s[VOCABc+1];
    __shared__ int tot[VOCABc];
    for (int i = tid; i < VOCABc*256; i += 256) ((u16*)cnt)[i] = 0;
    __syncthreads();
    int i0 = tid*4;
    #pragma unroll
    for (int k = 0; k < 4; k++) {
        int i = i0 + k;
        if (i < SEQc) {
            int t = target[(size_t)b*SEQc + i];
            tg[i] = (unsigned char)t;
            cnt[t][tid]++;
        }
    }
    __syncthreads();
    if (tid < VOCABc) {
        int run = 0;
        for (int c = 0; c < 256; c++) {
            int v = cnt[tid][c];
            cnt[tid][c] = (u16)run;
            run += v;
        }
        tot[tid] = run;
    }
    __syncthreads();
    if (tid == 0) {
        offs_s[0] = 0;
        for (int v = 0; v < VOCABc; v++) offs_s[v+1] = offs_s[v] + tot[v];
    }
    __syncthreads();
    if (tid < VOCABc+1) boff[b*(VOCABc+1) + tid] = offs_s[tid];
    #pragma unroll
    for (int k = 0; k < 4; k++) {
        int i = i0 + k;
        if (i < SEQc) {
            int t = tg[i];
            int r = cnt[t][tid]++;
            ordered[(size_t)b*SEQc + offs_s[t] + r] = i;
        }
    }
}
__global__ void k_buildA(const float* __restrict__ convw, const int* __restrict__ ordered,
                         const int* __restrict__ boff, float* __restrict__ Amat) {
    int t = blockIdx.x, b = blockIdx.y;
    int tid = threadIdx.x;                // 256 = 32 o * 8 k
    int o = tid >> 3, k = tid & 7;
    int s = boff[b*(VOCABc+1) + t], e = boff[b*(VOCABc+1) + t + 1];
    const int* ord = ordered + (size_t)b*SEQc;
    float acc = 0.f;
    for (int j = s; j < e; j++) {
        int i = ord[j];
        acc += convw[((size_t)o*SEQc + i)*KWc + k];
    }
    Amat[(((size_t)b*NFc + o)*VOCABc + t)*KWc + k] = acc;
}
__global__ void __launch_bounds__(128, 4)
k_conv(const float* __restrict__ Amat, const float* __restrict__ emb,
       const float* __restrict__ convb, u16* __restrict__ convout) {
    int b = blockIdx.x, og = blockIdx.y;      // og in 0..7 -> o base og*4
    int tid = threadIdx.x;                    // 128
    __shared__ float embs[VOCABc*EMBc];       // 13.3 KB
    __shared__ float arow[4*VOCABc*KWc];      // 3.3 KB
    for (int i = tid; i < VOCABc*EMBc; i += 128) embs[i] = emb[i];
    for (int i = tid; i < 4*VOCABc*KWc; i += 128)
        arow[i] = Amat[((size_t)b*NFc + og*4)*(VOCABc*KWc) + i];
    __syncthreads();
    if (tid < LOUTc) {
        float a0 = convb[og*4+0], a1 = convb[og*4+1], a2 = convb[og*4+2], a3 = convb[og*4+3];
        for (int t = 0; t < VOCABc; t++) {
            #pragma unroll
            for (int k = 0; k < KWc; k++) {
                float ev = embs[t*EMBc + tid + k];
                a0 += arow[0*(VOCABc*KWc) + t*KWc + k] * ev;
                a1 += arow[1*(VOCABc*KWc) + t*KWc + k] * ev;
                a2 += arow[2*(VOCABc*KWc) + t*KWc + k] * ev;
                a3 += arow[3*(VOCABc*KWc) + t*KWc + k] * ev;
            }
        }
        size_t base = (size_t)b*KXT + (og*4)*LOUTc + tid;
        convout[base            ] = f2bf(fmaxf(a0, 0.f));
        convout[base +   LOUTc  ] = f2bf(fmaxf(a1, 0.f));
        convout[base + 2*LOUTc  ] = f2bf(fmaxf(a2, 0.f));
        convout[base + 3*LOUTc  ] = f2bf(fmaxf(a3, 0.f));
    }
}
__global__ void k_fcxt_mfma(const short* __restrict__ cvo, const short* __restrict__ wxt,
                            float* __restrict__ fxp) {
    int wave = threadIdx.x >> 6, lane = threadIdx.x & 63;
    int m16 = lane & 15, quad = lane >> 4;
    int r0 = blockIdx.x*64 + wave*16;      // 512 rows = 8 blocks * 64
    int kt0 = blockIdx.y*11;               // 121 k-steps = 11 chunks * 11
    const short8* arow = (const short8*)(cvo + (size_t)(r0 + m16)*KXT);
    f32x4 acc[8];
    #pragma unroll
    for (int ct = 0; ct < 8; ct++) acc[ct] = (f32x4){0.f,0.f,0.f,0.f};
    for (int kt = kt0; kt < kt0 + 11; kt++) {
        short8 af = arow[kt*4 + quad];
        #pragma unroll
        for (int ct = 0; ct < 8; ct++) {
            const short8* brow = (const short8*)(wxt + (size_t)(ct*16 + m16)*KXT);
            short8 bf = brow[kt*4 + quad];
            acc[ct] = __builtin_amdgcn_mfma_f32_16x16x32_bf16(af, bf, acc[ct], 0, 0, 0);
        }
    }
    #pragma unroll
    for (int ct = 0; ct < 8; ct++) {
        int col = ct*16 + m16;
        #pragma unroll
        for (int r = 0; r < 4; r++) {
            int row = r0 + quad*4 + r;
            fxp[((size_t)blockIdx.y*BGRAPHS + row)*C2c + col] = acc[ct][r];
        }
    }
}

// ---------------- head MLP ----------------
__global__ void k_fc1(const float* __restrict__ xc, const float* __restrict__ fxp,
                      const float* __restrict__ fcxt_b, const float* __restrict__ W,
                      const float* __restrict__ bias, float* __restrict__ y1) {
    int b = blockIdx.x, tid = threadIdx.x;    // 256
    __shared__ float xs[256];
    if (tid < 128) {
        xs[tid] = xc[b*256 + tid];
    } else {
        int col = tid - 128;
        float s = fcxt_b[col];
        #pragma unroll
        for (int q = 0; q < 11; q++) s += fxp[((size_t)q*BGRAPHS + b)*C2c + col];
        xs[tid] = s;
    }
    __syncthreads();
    float a0 = bias[tid], a1 = bias[tid+256], a2 = bias[tid+512], a3 = bias[tid+768];
    for (int k = 0; k < 256; k++) {
        float xk = xs[k];
        const float* wr = W + (size_t)k*1024;
        a0 += xk*wr[tid]; a1 += xk*wr[tid+256]; a2 += xk*wr[tid+512]; a3 += xk*wr[tid+768];
    }
    y1[(size_t)b*1024 + tid      ] = fmaxf(a0, 0.f);
    y1[(size_t)b*1024 + tid + 256] = fmaxf(a1, 0.f);
    y1[(size_t)b*1024 + tid + 512] = fmaxf(a2, 0.f);
    y1[(size_t)b*1024 + tid + 768] = fmaxf(a3, 0.f);
}
__global__ void k_fc2out(const float* __restrict__ y1, const float* __restrict__ W,
                         const float* __restrict__ bias, const float* __restrict__ ow,
                         const float* __restrict__ ob, float* __restrict__ out) {
    int b = blockIdx.x, tid = threadIdx.x;    // 256
    int lane = tid & 63, wid = tid >> 6;
    __shared__ float ys[1024];
    __shared__ float wsum[4];
    for (int i = tid; i < 1024; i += 256) ys[i] = y1[(size_t)b*1024 + i];
    __syncthreads();
    float acc = bias[tid];
    for (int k = 0; k < 1024; k++) acc += ys[k] * W[(size_t)k*256 + tid];
    float v = fmaxf(acc, 0.f) * ow[tid];
    #pragma unroll
    for (int d = 32; d > 0; d >>= 1) v += __shfl_xor(v, d, 64);
    if (lane == 0) wsum[wid] = v;
    __syncthreads();
    if (tid == 0) out[b] = wsum[0] + wsum[1] + wsum[2] + wsum[3] + ob[0];
}

extern "C" void kernel_launch(void* const* d_in, const int* in_sizes, int n_in,
                              void* d_out, int out_size, void* d_ws, size_t ws_size,
                              hipStream_t stream) {
    (void)in_sizes; (void)n_in; (void)out_size;
    if (ws_size < A_END) return;   // guard: clean numeric-fail if ws too small

    const float* x       = (const float*)d_in[0];
    const int*   ei      = (const int*)  d_in[1];
    const int*   batch   = (const int*)  d_in[2];
    const int*   target  = (const int*)  d_in[3];
    const float* W1      = (const float*)d_in[4];
    const float* a_src1  = (const float*)d_in[5];
    const float* a_dst1  = (const float*)d_in[6];
    const float* b1      = (const float*)d_in[7];
    const float* W2      = (const float*)d_in[8];
    const float* a_src2  = (const float*)d_in[9];
    const float* a_dst2  = (const float*)d_in[10];
    const float* b2      = (const float*)d_in[11];
    const float* fcg_w   = (const float*)d_in[12];
    const float* fcg_b   = (const float*)d_in[13];
    const float* emb     = (const float*)d_in[14];
    const float* conv_w  = (const float*)d_in[15];
    const float* conv_b  = (const float*)d_in[16];
    const float* fcxt_w  = (const float*)d_in[17];
    const float* fcxt_b  = (const float*)d_in[18];
    const float* fc1_w   = (const float*)d_in[19];
    const float* fc1_b   = (const float*)d_in[20];
    const float* fc2_w   = (const float*)d_in[21];
    const float* fc2_b   = (const float*)d_in[22];
    const float* out_w   = (const float*)d_in[23];
    const float* out_b   = (const float*)d_in[24];

    char* wsb = (char*)d_ws;
    u16*   xagg  = (u16*)  (wsb + A_HBUF);
    u16*   out1  = (u16*)  (wsb + A_OUT1);
    float* h2    = (float*)(wsb + A_H2);
    __hip_bfloat16* w2t = (__hip_bfloat16*)(wsb + A_W2T);
    float* als1  = (float*)(wsb + A_ALS1);
    float* ald1  = (float*)(wsb + A_ALD1);
    float* als2  = (float*)(wsb + A_ALS2);
    float* ald2  = (float*)(wsb + A_ALD2);
    int*   deg   = (int*)  (wsb + A_DEG);
    int*   offs  = (int*)  (wsb + A_OFFS);
    int*   cur   = (int*)  (wsb + A_CUR);
    int*   csrc  = (int*)  (wsb + A_CSRC);
    float* xc    = (float*)(wsb + A_XC);
    float* y1    = (float*)(wsb + A_Y1);
    int*   boff  = (int*)  (wsb + A_BOFF);
    float* bpad  = (float*)(wsb + A_BPAD);
    __hip_bfloat16* wxt  = (__hip_bfloat16*)(wsb + A_WXT);
    float* fxp   = (float*)(wsb + A_FXP);
    __hip_bfloat16* w1hp = (__hip_bfloat16*)(wsb + A_W1HP);
    float* wsd   = (float*)(wsb + A_WSD);
    // aliases:
    float* hfin  = (float*)(wsb + A_HFIN);
    int*   ord   = (int*)  (wsb + A_ORD);
    float* Amat  = (float*)(wsb + A_AMAT);
    u16*   cvo   = (u16*)  (wsb + A_CVO);
    __hip_bfloat16* xpad = (__hip_bfloat16*)(wsb + A_XPAD);

    // prep
    k_prep<<<(PREP_TOTAL+255)/256, 256, 0, stream>>>(x, W1, W2, b1, fcxt_w, a_src1, a_dst1,
                                                     xpad, w1hp, w2t, bpad, wxt, wsd, deg);
    // CSR build (+ deterministic segment sort)
    k_count  <<<(N_EDGES+255)/256, 256, 0, stream>>>(ei, deg);
    k_scan   <<<1, 1024, 0, stream>>>(deg, offs, cur, N_NODES);
    k_fill   <<<(N_EDGES+N_NODES+255)/256, 256, 0, stream>>>(ei, cur, csrc);
    k_sortcsr<<<(N_NODES+255)/256, 256, 0, stream>>>(offs, csrc);

    // GAT layer 1 in x-space (no h materialization)
    k_att1x<<<(N_NODES*H1c+255)/256, 256, 0, stream>>>(x, wsd, als1, ald1);
    k_agg1x<<<N_NODES, 64, 0, stream>>>((const unsigned*)xpad, als1, ald1, offs, csrc,
                                        (unsigned*)xagg);
    k_gemm1h<<<dim3((N_NODES+63)/64, H1c), 256, 0, stream>>>((const short*)xagg,
                                                             (const short*)w1hp, bpad, out1);
    // ---- xagg dead; xpad dead (out1 region live) ----

    // GAT layer 2 (gemm2 also emits als2/ald2)
    k_gemm2_mfma<<<(N_NODES+63)/64, 256, 0, stream>>>((const short*)out1, (const short*)w2t,
                                                      a_src2, a_dst2, h2, als2, ald2);
    k_agg2<<<N_NODES, 64, 0, stream>>>(h2, als2, ald2, offs, csrc, b2, hfin);

    // pool + fc_g1 -> xc[:, 0:128]
    k_poolfcg<<<BGRAPHS, 128, 0, stream>>>(hfin, batch, fcg_w, fcg_b, xc);

    // conv path -> fxp partials
    k_bucket<<<BGRAPHS, 256, 0, stream>>>(target, ord, boff);
    k_buildA<<<dim3(VOCABc, BGRAPHS), 256, 0, stream>>>(conv_w, ord, boff, Amat);
    k_conv  <<<dim3(BGRAPHS, 8), 128, 0, stream>>>(Amat, emb, conv_b, cvo);
    k_fcxt_mfma<<<dim3(BGRAPHS/64, 11), 256, 0, stream>>>((const short*)cvo, (const short*)wxt, fxp);

    // head MLP
    k_fc1<<<BGRAPHS, 256, 0, stream>>>(xc, fxp, fcxt_b, fc1_w, fc1_b, y1);
    k_fc2out<<<BGRAPHS, 256, 0, stream>>>(y1, fc2_w, fc2_b, out_w, out_b, (float*)d_out);
}

// Round 15
// 643.375 us; speedup vs baseline: 1.6627x; 1.0100x over previous
//
#include <hip/hip_runtime.h>
#include <hip/hip_bf16.h>

// Problem constants (from reference)
#define N_NODES 50000
#define N_EDGES 200000
#define BGRAPHS 512
#define F0c 78
#define H1c 10
#define HC1 780     // H1*F0 (logical)
#define HSTR 800    // padded row stride: 10 head blocks of 80 (78 data + 2 pad)
#define C2c 128
#define SEQc 1000
#define VOCABc 26
#define NFc 32
#define KWc 8
#define LOUTc 121
#define EMBc 128
#define KX 96       // padded cols for xpad (78 -> 96)
#define KXT 3872    // NF*LOUT = 32*121 -> 121 MFMA k-steps, split 11 x 11

typedef __attribute__((ext_vector_type(8))) short short8;
typedef __attribute__((ext_vector_type(4))) float f32x4;
typedef unsigned short u16;

static constexpr size_t alignup(size_t x) { return (x + 255) & ~size_t(255); }

// -------- workspace layout (bytes) --------
// A_HBUF region holds xagg bf16 [N][10][80] = 80,000,000 B.
static constexpr size_t A_HBUF = 0;
static constexpr size_t A_OUT1 = alignup(A_HBUF + size_t(N_NODES)*HSTR*2);   // bf16 [N,800] = 80 MB
static constexpr size_t A_H2   = alignup(A_OUT1 + size_t(N_NODES)*HSTR*2);   // f32  [N,128]
static constexpr size_t A_W2T  = alignup(A_H2   + size_t(N_NODES)*C2c*4);    // bf16 [128,800] padded-80 layout
static constexpr size_t A_ALS1 = alignup(A_W2T  + size_t(C2c)*HSTR*2);
static constexpr size_t A_ALD1 = alignup(A_ALS1 + size_t(N_NODES)*H1c*4);
static constexpr size_t A_ALS2 = alignup(A_ALD1 + size_t(N_NODES)*H1c*4);
static constexpr size_t A_ALD2 = alignup(A_ALS2 + size_t(N_NODES)*4);
static constexpr size_t A_DEG  = alignup(A_ALD2 + size_t(N_NODES)*4);
static constexpr size_t A_OFFS = alignup(A_DEG  + size_t(N_NODES)*4);
static constexpr size_t A_CUR  = alignup(A_OFFS + size_t(N_NODES+1)*4);
static constexpr size_t A_CSRC = alignup(A_CUR  + size_t(N_NODES)*4);
static constexpr size_t A_XC   = alignup(A_CSRC + size_t(N_EDGES+N_NODES)*4);
static constexpr size_t A_Y1   = alignup(A_XC   + size_t(BGRAPHS)*256*4);
static constexpr size_t A_BOFF = alignup(A_Y1   + size_t(BGRAPHS)*1024*4);
static constexpr size_t A_BPAD = alignup(A_BOFF + size_t(BGRAPHS)*(VOCABc+1)*4);
static constexpr size_t A_WXT  = alignup(A_BPAD + size_t(HSTR)*4);           // bf16 [128][3872]
static constexpr size_t A_FXP  = alignup(A_WXT  + size_t(C2c)*KXT*2);        // f32 [11][512][128]
static constexpr size_t A_W1HP = alignup(A_FXP  + size_t(11)*BGRAPHS*C2c*4); // bf16 [10][80][96]
static constexpr size_t A_WSD  = alignup(A_W1HP + size_t(10)*80*96*2);       // f32 [2][10][78]
static constexpr size_t A_END  = alignup(A_WSD  + size_t(2)*H1c*F0c*4);

// aliases inside xagg region (valid after k_gemm1h retires; xagg dead then):
static constexpr size_t A_HFIN = A_HBUF;                                        // f32 [N,128]
static constexpr size_t A_ORD  = alignup(A_HFIN + size_t(N_NODES)*C2c*4);
static constexpr size_t A_AMAT = alignup(A_ORD  + size_t(BGRAPHS)*SEQc*4);
static constexpr size_t A_CVO  = alignup(A_AMAT + size_t(BGRAPHS)*NFc*VOCABc*KWc*4);  // bf16 [512][3872]
static_assert(A_CVO + size_t(BGRAPHS)*KXT*2 <= size_t(N_NODES)*HSTR*2, "alias A overflow");
// alias inside out1 region (xpad dead before gemm1h writes out1):
static constexpr size_t A_XPAD = A_OUT1;                                        // bf16 [N,96]
static_assert(size_t(N_NODES)*KX*2 <= size_t(N_NODES)*HSTR*2, "alias B overflow");

// -------- helpers --------
__device__ __forceinline__ float bflo(unsigned u) { return __uint_as_float(u << 16); }
__device__ __forceinline__ float bfhi(unsigned u) { return __uint_as_float(u & 0xffff0000u); }
__device__ __forceinline__ u16 f2bf(float v) {
    __hip_bfloat16 b = __float2bfloat16(v);
    return *(u16*)&b;
}

// ---------------- prep: deg init + conversions + folded attention vectors ----------------
__global__ void k_prep(const float* __restrict__ x, const float* __restrict__ W1,
                       const float* __restrict__ W2, const float* __restrict__ b1,
                       const float* __restrict__ fcxt_w,
                       const float* __restrict__ a_src1, const float* __restrict__ a_dst1,
                       __hip_bfloat16* __restrict__ xpad, __hip_bfloat16* __restrict__ w1hp,
                       __hip_bfloat16* __restrict__ w2t, float* __restrict__ bpad,
                       __hip_bfloat16* __restrict__ wxt, float* __restrict__ wsd,
                       int* __restrict__ deg) {
    int i = blockIdx.x*256 + threadIdx.x;
    const int R0 = N_NODES;
    const int R1 = R0 + N_NODES*KX;
    const int R2 = R1 + 10*80*96;
    const int R3 = R2 + C2c*HSTR;
    const int R4 = R3 + HSTR;
    const int R5 = R4 + C2c*KXT;
    const int R6 = R5 + 2*H1c*F0c;
    if (i < R0) {
        deg[i] = 1;   // self loop
    } else if (i < R1) {
        int t = i - R0; int n = t / KX, c = t - n*KX;
        xpad[t] = __float2bfloat16(c < F0c ? x[(size_t)n*F0c + c] : 0.f);
    } else if (i < R2) {
        int t = i - R1; int hh = t / 7680, rem = t - hh*7680;
        int j = rem / 96, k = rem - j*96;
        w1hp[t] = __float2bfloat16((j < F0c && k < F0c) ? W1[(size_t)k*HC1 + hh*F0c + j] : 0.f);
    } else if (i < R3) {
        int t = i - R2; int c = t / HSTR, p = t - c*HSTR;
        int hh = p / 80, cc = p - hh*80;
        w2t[t] = __float2bfloat16(cc < F0c ? W2[(size_t)(hh*F0c + cc)*C2c + c] : 0.f);
    } else if (i < R4) {
        int p = i - R3; int hh = p / 80, cc = p - hh*80;
        bpad[p] = (cc < F0c) ? b1[hh*F0c + cc] : 0.f;
    } else if (i < R5) {
        int t = i - R4; int c = t / KXT, j = t - c*KXT;
        wxt[t] = __float2bfloat16(fcxt_w[(size_t)j*C2c + c]);
    } else if (i < R6) {
        int t = i - R5; int sd = t / (H1c*F0c), rem = t - sd*(H1c*F0c);
        int hh = rem / F0c, c = rem - hh*F0c;
        const float* a = sd ? a_dst1 : a_src1;
        float v = 0.f;
        for (int j = 0; j < F0c; j++) v += W1[(size_t)c*HC1 + hh*F0c + j] * a[hh*F0c + j];
        wsd[t] = v;
    }
}
#define PREP_TOTAL (N_NODES + N_NODES*KX + 10*80*96 + C2c*HSTR + HSTR + C2c*KXT + 2*H1c*F0c)

// ---------------- CSR build ----------------
__global__ void k_count(const int* __restrict__ ei, int* deg) {
    int i = blockIdx.x*256 + threadIdx.x;
    if (i < N_EDGES) atomicAdd(&deg[ei[N_EDGES + i]], 1);
}
__global__ void k_scan(const int* __restrict__ deg, int* __restrict__ off,
                       int* __restrict__ cur, int n) {
    __shared__ int wsum[16];
    __shared__ int s_carry;
    int tid = threadIdx.x, lane = tid & 63, wid = tid >> 6;
    if (tid == 0) s_carry = 0;
    __syncthreads();
    for (int base = 0; base < n; base += 1024) {
        int i = base + tid;
        int v0 = (i < n) ? deg[i] : 0;
        int v = v0;
        for (int d = 1; d < 64; d <<= 1) { int t = __shfl_up(v, d, 64); if (lane >= d) v += t; }
        if (lane == 63) wsum[wid] = v;
        __syncthreads();
        if (wid == 0) {
            int w = (lane < 16) ? wsum[lane] : 0;
            for (int d = 1; d < 16; d <<= 1) { int t = __shfl_up(w, d, 64); if (lane >= d) w += t; }
            if (lane < 16) wsum[lane] = w;
        }
        __syncthreads();
        int wprev = (wid > 0) ? wsum[wid-1] : 0;
        int carry = s_carry;
        if (i < n) { int o = carry + wprev + (v - v0); off[i] = o; cur[i] = o; }
        __syncthreads();
        if (tid == 0) s_carry = carry + wsum[15];
        __syncthreads();
    }
    if (tid == 0) off[n] = s_carry;
}
__global__ void k_fill(const int* __restrict__ ei, int* cur, int* __restrict__ csrc) {
    int i = blockIdx.x*256 + threadIdx.x;
    if (i < N_EDGES) {
        int s = ei[i], d = ei[N_EDGES + i];
        int p = atomicAdd(&cur[d], 1);
        csrc[p] = s;
    } else if (i < N_EDGES + N_NODES) {
        int n = i - N_EDGES;
        int p = atomicAdd(&cur[n], 1);
        csrc[p] = n;
    }
}
// determinize: sort each CSR segment (atomic fill order varies run-to-run)
__global__ void k_sortcsr(const int* __restrict__ offs, int* __restrict__ csrc) {
    int n = blockIdx.x*256 + threadIdx.x;
    if (n >= N_NODES) return;
    int s = offs[n], e = offs[n+1];
    for (int i = s + 1; i < e; i++) {
        int v = csrc[i];
        int j = i - 1;
        while (j >= s && csrc[j] > v) { csrc[j+1] = csrc[j]; j--; }
        csrc[j+1] = v;
    }
}

// ---------------- layer-1 attention logits, direct from x: als = x @ (W1_h a_h) ----------------
__global__ void k_att1x(const float* __restrict__ x, const float* __restrict__ wsd,
                        float* __restrict__ als, float* __restrict__ ald) {
    int i = blockIdx.x*256 + threadIdx.x;
    if (i >= N_NODES*H1c) return;
    int n = i / H1c, hh = i - n*H1c;
    const float* xr = x + (size_t)n*F0c;
    const float* ws = wsd + hh*F0c;
    const float* wd = wsd + H1c*F0c + hh*F0c;
    float s1 = 0.f, s2 = 0.f;
    for (int c = 0; c < F0c; c++) { float v = xr[c]; s1 += v*ws[c]; s2 += v*wd[c]; }
    als[i] = s1; ald[i] = s2;
}

// ---------------- layer-1 aggregation in x-space: xagg[n,hh,80] = sum alpha * x[src] ----------------
__global__ void k_agg1x(const unsigned* __restrict__ xpu, const float* __restrict__ als,
                        const float* __restrict__ ald, const int* __restrict__ offs,
                        const int* __restrict__ csrc, unsigned* __restrict__ xaggu) {
    constexpr int H = H1c;
    int dn = blockIdx.x, lane = threadIdx.x;   // 64
    int s = offs[dn], e = offs[dn+1], deg = e - s;
    __shared__ float wexp[64*H];               // 2560 B
    __shared__ int   ssrc[64];
    __shared__ float ms[H], dinv_s[H];

    if (deg <= 64) {
        if (lane < deg) ssrc[lane] = csrc[s + lane];
        __syncthreads();
        for (int idx = lane; idx < deg*H; idx += 64) {
            int j = idx / H, hh = idx - j*H;
            float al = als[(size_t)ssrc[j]*H + hh] + ald[(size_t)dn*H + hh];
            wexp[idx] = (al >= 0.f) ? al : 0.2f*al;
        }
        __syncthreads();
        if (lane < H) {
            float m = -1e30f;
            for (int j = 0; j < deg; j++) m = fmaxf(m, wexp[j*H + lane]);
            float den = 0.f;
            for (int j = 0; j < deg; j++) den += __expf(wexp[j*H + lane] - m);
            ms[lane] = m; dinv_s[lane] = 1.f/(den + 1e-16f);
        }
        __syncthreads();
        for (int idx = lane; idx < deg*H; idx += 64) {
            int hh = idx % H;
            wexp[idx] = __expf(wexp[idx] - ms[hh]) * dinv_s[hh];
        }
        __syncthreads();
        if (lane < 40) {                       // uint c covers x cols 2c,2c+1 (cols 0..79)
            float accL[H], accH[H];
            #pragma unroll
            for (int hh = 0; hh < H; hh++) { accL[hh] = 0.f; accH[hh] = 0.f; }
            int j = 0;
            for (; j + 1 < deg; j += 2) {
                unsigned ua = xpu[(size_t)ssrc[j]*48 + lane];
                unsigned ub = xpu[(size_t)ssrc[j+1]*48 + lane];
                float a0 = bflo(ua), a1 = bfhi(ua), b0 = bflo(ub), b1 = bfhi(ub);
                #pragma unroll
                for (int hh = 0; hh < H; hh++) {
                    float wA = wexp[j*H + hh], wB = wexp[(j+1)*H + hh];
                    accL[hh] += wA*a0 + wB*b0;
                    accH[hh] += wA*a1 + wB*b1;
                }
            }
            if (j < deg) {
                unsigned ua = xpu[(size_t)ssrc[j]*48 + lane];
                float a0 = bflo(ua), a1 = bfhi(ua);
                #pragma unroll
                for (int hh = 0; hh < H; hh++) {
                    float wA = wexp[j*H + hh];
                    accL[hh] += wA*a0;
                    accH[hh] += wA*a1;
                }
            }
            #pragma unroll
            for (int hh = 0; hh < H; hh++) {
                unsigned p = (unsigned)f2bf(accL[hh]) | ((unsigned)f2bf(accH[hh]) << 16);
                xaggu[((size_t)dn*H + hh)*40 + lane] = p;
            }
        }
    } else {
        // fallback deg>64 (practically never): recompute alpha inline, guaranteed correct
        if (lane < H) {
            float adv = ald[(size_t)dn*H + lane];
            float m = -1e30f;
            for (int j = s; j < e; j++) {
                float al = als[(size_t)csrc[j]*H + lane] + adv;
                al = (al >= 0.f) ? al : 0.2f*al;
                m = fmaxf(m, al);
            }
            float den = 0.f;
            for (int j = s; j < e; j++) {
                float al = als[(size_t)csrc[j]*H + lane] + adv;
                al = (al >= 0.f) ? al : 0.2f*al;
                den += __expf(al - m);
            }
            ms[lane] = m; dinv_s[lane] = 1.f/(den + 1e-16f);
        }
        __syncthreads();
        if (lane < 40) {
            float accL[H], accH[H];
            #pragma unroll
            for (int hh = 0; hh < H; hh++) { accL[hh] = 0.f; accH[hh] = 0.f; }
            for (int j = s; j < e; j++) {
                int sj = csrc[j];
                unsigned ua = xpu[(size_t)sj*48 + lane];
                float a0 = bflo(ua), a1 = bfhi(ua);
                #pragma unroll
                for (int hh = 0; hh < H; hh++) {
                    float al = als[(size_t)sj*H + hh] + ald[(size_t)dn*H + hh];
                    al = (al >= 0.f) ? al : 0.2f*al;
                    float a = __expf(al - ms[hh]) * dinv_s[hh];
                    accL[hh] += a*a0;
                    accH[hh] += a*a1;
                }
            }
            #pragma unroll
            for (int hh = 0; hh < H; hh++) {
                unsigned p = (unsigned)f2bf(accL[hh]) | ((unsigned)f2bf(accH[hh]) << 16);
                xaggu[((size_t)dn*H + hh)*40 + lane] = p;
            }
        }
    }
}

// ---------------- per-head GEMM: xagg[n,hh,80] @ W1_hh[80x80] -> out1 (elu+bias fused) ----------------
__global__ void k_gemm1h(const short* __restrict__ xagg, const short* __restrict__ w1hp,
                         const float* __restrict__ bpad, u16* __restrict__ out1) {
    int wave = threadIdx.x >> 6, lane = threadIdx.x & 63;
    int m16 = lane & 15, quad = lane >> 4;
    int hh = blockIdx.y;
    int r0 = blockIdx.x*64 + wave*16;
    int rowc = min(r0 + m16, N_NODES-1);
    const short8* arow = (const short8*)(xagg + ((size_t)rowc*H1c + hh)*80);
    f32x4 acc[5];
    #pragma unroll
    for (int ct = 0; ct < 5; ct++) acc[ct] = (f32x4){0.f,0.f,0.f,0.f};
    #pragma unroll
    for (int kt = 0; kt < 3; kt++) {
        short8 af = arow[kt*4 + quad];    // kt=2,quad>=2 overreads: B zeros neutralize
        #pragma unroll
        for (int ct = 0; ct < 5; ct++) {
            const short8* brow = (const short8*)(w1hp + (size_t)(hh*80 + ct*16 + m16)*96);
            short8 bf = brow[kt*4 + quad];
            acc[ct] = __builtin_amdgcn_mfma_f32_16x16x32_bf16(af, bf, acc[ct], 0, 0, 0);
        }
    }
    #pragma unroll
    for (int ct = 0; ct < 5; ct++) {
        int col = ct*16 + m16;
        float bv = bpad[hh*80 + col];
        #pragma unroll
        for (int r = 0; r < 4; r++) {
            int orow = r0 + quad*4 + r;
            if (orow < N_NODES) {
                float v = acc[ct][r] + bv;
                v = (v > 0.f) ? v : (__expf(v) - 1.f);
                out1[(size_t)orow*HSTR + hh*80 + col] = f2bf(v);
            }
        }
    }
}

// ---------------- GEMM2 (MFMA) + att2 fold: out1 @ W2t^T -> h2, als2, ald2 ----------------
__global__ void k_gemm2_mfma(const short* __restrict__ A, const short* __restrict__ Bt,
                             const float* __restrict__ a_src2, const float* __restrict__ a_dst2,
                             float* __restrict__ Cout, float* __restrict__ als2,
                             float* __restrict__ ald2) {
    int wave = threadIdx.x >> 6, lane = threadIdx.x & 63;
    int m16 = lane & 15, quad = lane >> 4;
    int r0 = blockIdx.x*64 + wave*16;
    int rowc = min(r0 + m16, N_NODES-1);
    const short8* arow = (const short8*)(A + (size_t)rowc*HSTR);
    f32x4 acc[8];
    #pragma unroll
    for (int ct = 0; ct < 8; ct++) acc[ct] = (f32x4){0.f,0.f,0.f,0.f};
    for (int kt = 0; kt < 25; kt++) {
        short8 af = arow[kt*4 + quad];
        #pragma unroll
        for (int ct = 0; ct < 8; ct++) {
            const short8* brow = (const short8*)(Bt + (size_t)(ct*16 + m16)*HSTR);
            short8 bf = brow[kt*4 + quad];
            acc[ct] = __builtin_amdgcn_mfma_f32_16x16x32_bf16(af, bf, acc[ct], 0, 0, 0);
        }
    }
    #pragma unroll
    for (int ct = 0; ct < 8; ct++) {
        #pragma unroll
        for (int r = 0; r < 4; r++) {
            int orow = r0 + quad*4 + r;
            if (orow < N_NODES) Cout[(size_t)orow*C2c + ct*16 + m16] = acc[ct][r];
        }
    }
    float asv[8], adv[8];
    #pragma unroll
    for (int ct = 0; ct < 8; ct++) { asv[ct] = a_src2[ct*16 + m16]; adv[ct] = a_dst2[ct*16 + m16]; }
    #pragma unroll
    for (int r = 0; r < 4; r++) {
        float s1 = 0.f, s2 = 0.f;
        #pragma unroll
        for (int ct = 0; ct < 8; ct++) { s1 += acc[ct][r]*asv[ct]; s2 += acc[ct][r]*adv[ct]; }
        #pragma unroll
        for (int d = 1; d < 16; d <<= 1) { s1 += __shfl_xor(s1, d, 64); s2 += __shfl_xor(s2, d, 64); }
        int orow = r0 + quad*4 + r;
        if (m16 == 0 && orow < N_NODES) { als2[orow] = s1; ald2[orow] = s2; }
    }
}

// ---------------- GAT layer-2 aggregation (H=1, C=128 f32) ----------------
__global__ void k_agg2(const float* __restrict__ h2, const float* __restrict__ als,
                       const float* __restrict__ ald, const int* __restrict__ offs,
                       const int* __restrict__ csrc, const float* __restrict__ b2,
                       float* __restrict__ out) {
    int dn = blockIdx.x, lane = threadIdx.x;   // 64
    int s = offs[dn], e = offs[dn+1], deg = e - s;
    __shared__ float wexp[128];
    __shared__ int ssrc[128];

    if (deg <= 128) {
        float adv = ald[dn];
        for (int j = lane; j < deg; j += 64) {
            int sj = csrc[s + j];
            ssrc[j] = sj;
            float al = als[sj] + adv;
            wexp[j] = (al >= 0.f) ? al : 0.2f*al;
        }
        __syncthreads();
        float m = -1e30f;
        for (int j = lane; j < deg; j += 64) m = fmaxf(m, wexp[j]);
        #pragma unroll
        for (int d = 32; d > 0; d >>= 1) m = fmaxf(m, __shfl_xor(m, d, 64));
        __syncthreads();
        float den = 0.f;
        for (int j = lane; j < deg; j += 64) {
            float ex = __expf(wexp[j] - m);
            wexp[j] = ex;
            den += ex;
        }
        #pragma unroll
        for (int d = 32; d > 0; d >>= 1) den += __shfl_xor(den, d, 64);
        float dinv = 1.f/(den + 1e-16f);
        __syncthreads();
        float2 acc = {0.f, 0.f};
        for (int j = 0; j < deg; j++) {
            float alpha = wexp[j] * dinv;
            float2 v = ((const float2*)(h2 + (size_t)ssrc[j]*C2c))[lane];
            acc.x += alpha*v.x; acc.y += alpha*v.y;
        }
        float2 o;
        o.x = fmaxf(acc.x + b2[2*lane], 0.f);
        o.y = fmaxf(acc.y + b2[2*lane+1], 0.f);
        ((float2*)(out + (size_t)dn*C2c))[lane] = o;
    } else {
        __shared__ float sm[2];
        if (lane == 0) {
            float adv = ald[dn];
            float m = -1e30f;
            for (int j = s; j < e; j++) {
                float al = als[csrc[j]] + adv;
                al = (al >= 0.f) ? al : 0.2f*al;
                m = fmaxf(m, al);
            }
            float den = 0.f;
            for (int j = s; j < e; j++) {
                float al = als[csrc[j]] + adv;
                al = (al >= 0.f) ? al : 0.2f*al;
                den += __expf(al - m);
            }
            sm[0] = m; sm[1] = 1.f/(den + 1e-16f);
        }
        __syncthreads();
        float m = sm[0], dinv = sm[1], adv = ald[dn];
        float2 acc = {0.f, 0.f};
        for (int j = s; j < e; j++) {
            int sj = csrc[j];
            float al = als[sj] + adv;
            al = (al >= 0.f) ? al : 0.2f*al;
            float alpha = __expf(al - m) * dinv;
            float2 v = ((const float2*)(h2 + (size_t)sj*C2c))[lane];
            acc.x += alpha*v.x; acc.y += alpha*v.y;
        }
        float2 o;
        o.x = fmaxf(acc.x + b2[2*lane], 0.f);
        o.y = fmaxf(acc.y + b2[2*lane+1], 0.f);
        ((float2*)(out + (size_t)dn*C2c))[lane] = o;
    }
}

// ---------------- pool + fc_g1 merged (g stays in LDS) ----------------
__global__ void k_poolfcg(const float* __restrict__ hf, const int* __restrict__ batch,
                          const float* __restrict__ W, const float* __restrict__ bias,
                          float* __restrict__ xc) {
    int b = blockIdx.x, tid = threadIdx.x;    // 128
    __shared__ int se[2];
    __shared__ float gs[C2c];
    if (tid < 2) {
        int key = b + tid;
        int lo = 0, hi = N_NODES;
        while (lo < hi) { int mid = (lo+hi) >> 1; if (batch[mid] < key) lo = mid+1; else hi = mid; }
        se[tid] = lo;
    }
    __syncthreads();
    int s = se[0], e = se[1];
    float m = -1e30f;
    for (int n = s; n < e; n++) m = fmaxf(m, hf[(size_t)n*C2c + tid]);
    gs[tid] = m;
    __syncthreads();
    float acc = bias[tid];
    for (int k = 0; k < C2c; k++) acc += gs[k] * W[k*C2c + tid];
    xc[b*256 + tid] = fmaxf(acc, 0.f);
}

// ---------------- conv path ----------------
__global__ void k_bucket(const int* __restrict__ target, int* __restrict__ ordered,
                         int* __restrict__ boff) {
    int b = blockIdx.x, tid = threadIdx.x;    // 256
    __shared__ unsigned char tg[SEQc];
    __shared__ u16 cnt[VOCABc][256];          // 13.3 KB, [v][chunk]
    __shared__ int offs_s[VOCABc+1];
    __shared__ int tot[VOCABc];
    for (int i = tid; i < VOCABc*256; i += 256) ((u16*)cnt)[i] = 0;
    __syncthreads();
    int i0 = tid*4;
    #pragma unroll
    for (int k = 0; k < 4; k++) {
        int i = i0 + k;
        if (i < SEQc) {
            int t = target[(size_t)b*SEQc + i];
            tg[i] = (unsigned char)t;
            cnt[t][tid]++;
        }
    }
    __syncthreads();
    if (tid < VOCABc) {
        int run = 0;
        for (int c = 0; c < 256; c++) {
            int v = cnt[tid][c];
            cnt[tid][c] = (u16)run;
            run += v;
        }
        tot[tid] = run;
    }
    __syncthreads();
    if (tid == 0) {
        offs_s[0] = 0;
        for (int v = 0; v < VOCABc; v++) offs_s[v+1] = offs_s[v] + tot[v];
    }
    __syncthreads();
    if (tid < VOCABc+1) boff[b*(VOCABc+1) + tid] = offs_s[tid];
    #pragma unroll
    for (int k = 0; k < 4; k++) {
        int i = i0 + k;
        if (i < SEQc) {
            int t = tg[i];
            int r = cnt[t][tid]++;
            ordered[(size_t)b*SEQc + offs_s[t] + r] = i;
        }
    }
}
// buildA: LDS-staged bucket indices break the ord->convw dependent chain.
// Same per-thread summation order as before -> bit-identical output.
__global__ void k_buildA(const float* __restrict__ convw, const int* __restrict__ ordered,
                         const int* __restrict__ boff, float* __restrict__ Amat) {
    int t = blockIdx.x, b = blockIdx.y;
    int tid = threadIdx.x;                // 256 = 32 o * 8 k
    int o = tid >> 3, k = tid & 7;
    int s = boff[b*(VOCABc+1) + t], e = boff[b*(VOCABc+1) + t + 1];
    __shared__ int sidx[256];
    float acc = 0.f;
    for (int base = s; base < e; base += 256) {
        int m = min(256, e - base);
        __syncthreads();
        if (tid < m) sidx[tid] = ordered[(size_t)b*SEQc + base + tid];
        __syncthreads();
        #pragma unroll 4
        for (int j = 0; j < m; j++) {
            acc += convw[((size_t)o*SEQc + sidx[j])*KWc + k];
        }
    }
    Amat[(((size_t)b*NFc + o)*VOCABc + t)*KWc + k] = acc;
}
__global__ void __launch_bounds__(128, 4)
k_conv(const float* __restrict__ Amat, const float* __restrict__ emb,
       const float* __restrict__ convb, u16* __restrict__ convout) {
    int b = blockIdx.x, og = blockIdx.y;      // og in 0..7 -> o base og*4
    int tid = threadIdx.x;                    // 128
    __shared__ float embs[VOCABc*EMBc];       // 13.3 KB
    __shared__ float arow[4*VOCABc*KWc];      // 3.3 KB
    for (int i = tid; i < VOCABc*EMBc; i += 128) embs[i] = emb[i];
    for (int i = tid; i < 4*VOCABc*KWc; i += 128)
        arow[i] = Amat[((size_t)b*NFc + og*4)*(VOCABc*KWc) + i];
    __syncthreads();
    if (tid < LOUTc) {
        float a0 = convb[og*4+0], a1 = convb[og*4+1], a2 = convb[og*4+2], a3 = convb[og*4+3];
        for (int t = 0; t < VOCABc; t++) {
            #pragma unroll
            for (int k = 0; k < KWc; k++) {
                float ev = embs[t*EMBc + tid + k];
                a0 += arow[0*(VOCABc*KWc) + t*KWc + k] * ev;
                a1 += arow[1*(VOCABc*KWc) + t*KWc + k] * ev;
                a2 += arow[2*(VOCABc*KWc) + t*KWc + k] * ev;
                a3 += arow[3*(VOCABc*KWc) + t*KWc + k] * ev;
            }
        }
        size_t base = (size_t)b*KXT + (og*4)*LOUTc + tid;
        convout[base            ] = f2bf(fmaxf(a0, 0.f));
        convout[base +   LOUTc  ] = f2bf(fmaxf(a1, 0.f));
        convout[base + 2*LOUTc  ] = f2bf(fmaxf(a2, 0.f));
        convout[base + 3*LOUTc  ] = f2bf(fmaxf(a3, 0.f));
    }
}
__global__ void k_fcxt_mfma(const short* __restrict__ cvo, const short* __restrict__ wxt,
                            float* __restrict__ fxp) {
    int wave = threadIdx.x >> 6, lane = threadIdx.x & 63;
    int m16 = lane & 15, quad = lane >> 4;
    int r0 = blockIdx.x*64 + wave*16;      // 512 rows = 8 blocks * 64
    int kt0 = blockIdx.y*11;               // 121 k-steps = 11 chunks * 11
    const short8* arow = (const short8*)(cvo + (size_t)(r0 + m16)*KXT);
    f32x4 acc[8];
    #pragma unroll
    for (int ct = 0; ct < 8; ct++) acc[ct] = (f32x4){0.f,0.f,0.f,0.f};
    for (int kt = kt0; kt < kt0 + 11; kt++) {
        short8 af = arow[kt*4 + quad];
        #pragma unroll
        for (int ct = 0; ct < 8; ct++) {
            const short8* brow = (const short8*)(wxt + (size_t)(ct*16 + m16)*KXT);
            short8 bf = brow[kt*4 + quad];
            acc[ct] = __builtin_amdgcn_mfma_f32_16x16x32_bf16(af, bf, acc[ct], 0, 0, 0);
        }
    }
    #pragma unroll
    for (int ct = 0; ct < 8; ct++) {
        int col = ct*16 + m16;
        #pragma unroll
        for (int r = 0; r < 4; r++) {
            int row = r0 + quad*4 + r;
            fxp[((size_t)blockIdx.y*BGRAPHS + row)*C2c + col] = acc[ct][r];
        }
    }
}

// ---------------- head MLP ----------------
__global__ void k_fc1(const float* __restrict__ xc, const float* __restrict__ fxp,
                      const float* __restrict__ fcxt_b, const float* __restrict__ W,
                      const float* __restrict__ bias, float* __restrict__ y1) {
    int b = blockIdx.x, tid = threadIdx.x;    // 256
    __shared__ float xs[256];
    if (tid < 128) {
        xs[tid] = xc[b*256 + tid];
    } else {
        int col = tid - 128;
        float s = fcxt_b[col];
        #pragma unroll
        for (int q = 0; q < 11; q++) s += fxp[((size_t)q*BGRAPHS + b)*C2c + col];
        xs[tid] = s;
    }
    __syncthreads();
    float a0 = bias[tid], a1 = bias[tid+256], a2 = bias[tid+512], a3 = bias[tid+768];
    for (int k = 0; k < 256; k++) {
        float xk = xs[k];
        const float* wr = W + (size_t)k*1024;
        a0 += xk*wr[tid]; a1 += xk*wr[tid+256]; a2 += xk*wr[tid+512]; a3 += xk*wr[tid+768];
    }
    y1[(size_t)b*1024 + tid      ] = fmaxf(a0, 0.f);
    y1[(size_t)b*1024 + tid + 256] = fmaxf(a1, 0.f);
    y1[(size_t)b*1024 + tid + 512] = fmaxf(a2, 0.f);
    y1[(size_t)b*1024 + tid + 768] = fmaxf(a3, 0.f);
}
__global__ void k_fc2out(const float* __restrict__ y1, const float* __restrict__ W,
                         const float* __restrict__ bias, const float* __restrict__ ow,
                         const float* __restrict__ ob, float* __restrict__ out) {
    int b = blockIdx.x, tid = threadIdx.x;    // 256
    int lane = tid & 63, wid = tid >> 6;
    __shared__ float ys[1024];
    __shared__ float wsum[4];
    for (int i = tid; i < 1024; i += 256) ys[i] = y1[(size_t)b*1024 + i];
    __syncthreads();
    float acc = bias[tid];
    for (int k = 0; k < 1024; k++) acc += ys[k] * W[(size_t)k*256 + tid];
    float v = fmaxf(acc, 0.f) * ow[tid];
    #pragma unroll
    for (int d = 32; d > 0; d >>= 1) v += __shfl_xor(v, d, 64);
    if (lane == 0) wsum[wid] = v;
    __syncthreads();
    if (tid == 0) out[b] = wsum[0] + wsum[1] + wsum[2] + wsum[3] + ob[0];
}

extern "C" void kernel_launch(void* const* d_in, const int* in_sizes, int n_in,
                              void* d_out, int out_size, void* d_ws, size_t ws_size,
                              hipStream_t stream) {
    (void)in_sizes; (void)n_in; (void)out_size;
    if (ws_size < A_END) return;   // guard: clean numeric-fail if ws too small

    const float* x       = (const float*)d_in[0];
    const int*   ei      = (const int*)  d_in[1];
    const int*   batch   = (const int*)  d_in[2];
    const int*   target  = (const int*)  d_in[3];
    const float* W1      = (const float*)d_in[4];
    const float* a_src1  = (const float*)d_in[5];
    const float* a_dst1  = (const float*)d_in[6];
    const float* b1      = (const float*)d_in[7];
    const float* W2      = (const float*)d_in[8];
    const float* a_src2  = (const float*)d_in[9];
    const float* a_dst2  = (const float*)d_in[10];
    const float* b2      = (const float*)d_in[11];
    const float* fcg_w   = (const float*)d_in[12];
    const float* fcg_b   = (const float*)d_in[13];
    const float* emb     = (const float*)d_in[14];
    const float* conv_w  = (const float*)d_in[15];
    const float* conv_b  = (const float*)d_in[16];
    const float* fcxt_w  = (const float*)d_in[17];
    const float* fcxt_b  = (const float*)d_in[18];
    const float* fc1_w   = (const float*)d_in[19];
    const float* fc1_b   = (const float*)d_in[20];
    const float* fc2_w   = (const float*)d_in[21];
    const float* fc2_b   = (const float*)d_in[22];
    const float* out_w   = (const float*)d_in[23];
    const float* out_b   = (const float*)d_in[24];

    char* wsb = (char*)d_ws;
    u16*   xagg  = (u16*)  (wsb + A_HBUF);
    u16*   out1  = (u16*)  (wsb + A_OUT1);
    float* h2    = (float*)(wsb + A_H2);
    __hip_bfloat16* w2t = (__hip_bfloat16*)(wsb + A_W2T);
    float* als1  = (float*)(wsb + A_ALS1);
    float* ald1  = (float*)(wsb + A_ALD1);
    float* als2  = (float*)(wsb + A_ALS2);
    float* ald2  = (float*)(wsb + A_ALD2);
    int*   deg   = (int*)  (wsb + A_DEG);
    int*   offs  = (int*)  (wsb + A_OFFS);
    int*   cur   = (int*)  (wsb + A_CUR);
    int*   csrc  = (int*)  (wsb + A_CSRC);
    float* xc    = (float*)(wsb + A_XC);
    float* y1    = (float*)(wsb + A_Y1);
    int*   boff  = (int*)  (wsb + A_BOFF);
    float* bpad  = (float*)(wsb + A_BPAD);
    __hip_bfloat16* wxt  = (__hip_bfloat16*)(wsb + A_WXT);
    float* fxp   = (float*)(wsb + A_FXP);
    __hip_bfloat16* w1hp = (__hip_bfloat16*)(wsb + A_W1HP);
    float* wsd   = (float*)(wsb + A_WSD);
    // aliases:
    float* hfin  = (float*)(wsb + A_HFIN);
    int*   ord   = (int*)  (wsb + A_ORD);
    float* Amat  = (float*)(wsb + A_AMAT);
    u16*   cvo   = (u16*)  (wsb + A_CVO);
    __hip_bfloat16* xpad = (__hip_bfloat16*)(wsb + A_XPAD);

    // prep
    k_prep<<<(PREP_TOTAL+255)/256, 256, 0, stream>>>(x, W1, W2, b1, fcxt_w, a_src1, a_dst1,
                                                     xpad, w1hp, w2t, bpad, wxt, wsd, deg);
    // CSR build (+ deterministic segment sort)
    k_count  <<<(N_EDGES+255)/256, 256, 0, stream>>>(ei, deg);
    k_scan   <<<1, 1024, 0, stream>>>(deg, offs, cur, N_NODES);
    k_fill   <<<(N_EDGES+N_NODES+255)/256, 256, 0, stream>>>(ei, cur, csrc);
    k_sortcsr<<<(N_NODES+255)/256, 256, 0, stream>>>(offs, csrc);

    // GAT layer 1 in x-space (no h materialization)
    k_att1x<<<(N_NODES*H1c+255)/256, 256, 0, stream>>>(x, wsd, als1, ald1);
    k_agg1x<<<N_NODES, 64, 0, stream>>>((const unsigned*)xpad, als1, ald1, offs, csrc,
                                        (unsigned*)xagg);
    k_gemm1h<<<dim3((N_NODES+63)/64, H1c), 256, 0, stream>>>((const short*)xagg,
                                                             (const short*)w1hp, bpad, out1);
    // ---- xagg dead; xpad dead (out1 region live) ----

    // GAT layer 2 (gemm2 also emits als2/ald2)
    k_gemm2_mfma<<<(N_NODES+63)/64, 256, 0, stream>>>((const short*)out1, (const short*)w2t,
                                                      a_src2, a_dst2, h2, als2, ald2);
    k_agg2<<<N_NODES, 64, 0, stream>>>(h2, als2, ald2, offs, csrc, b2, hfin);

    // pool + fc_g1 -> xc[:, 0:128]
    k_poolfcg<<<BGRAPHS, 128, 0, stream>>>(hfin, batch, fcg_w, fcg_b, xc);

    // conv path -> fxp partials
    k_bucket<<<BGRAPHS, 256, 0, stream>>>(target, ord, boff);
    k_buildA<<<dim3(VOCABc, BGRAPHS), 256, 0, stream>>>(conv_w, ord, boff, Amat);
    k_conv  <<<dim3(BGRAPHS, 8), 128, 0, stream>>>(Amat, emb, conv_b, cvo);
    k_fcxt_mfma<<<dim3(BGRAPHS/64, 11), 256, 0, stream>>>((const short*)cvo, (const short*)wxt, fxp);

    // head MLP
    k_fc1<<<BGRAPHS, 256, 0, stream>>>(xc, fxp, fcxt_b, fc1_w, fc1_b, y1);
    k_fc2out<<<BGRAPHS, 256, 0, stream>>>(y1, fc2_w, fc2_b, out_w, out_b, (float*)d_out);
}